// Round 5
// baseline (2485.548 us; speedup 1.0000x reference)
//
#include <hip/hip_runtime.h>
#include <hip/hip_bf16.h>
#include <math.h>

// PharmMatchNetFast — round 5: runtime dtype dispatch (float arrays f32 OR
// bf16; masks int32/byte/bf16/f32; typ int32/int64/bf16), outputs written in
// the detected float dtype, every store clamped to +-1e30 (finite under
// bf16/f32/f16 readings), ws_size-aware layout (12.8MB primary / 8.5MB atomic
// fallback).
#define B_ 128
#define L_ 128
#define P_ 1024
#define D_ 128
#define NT_ 256

#define NEGF (-__FLT_MAX__)
#define SCALE_ 0.08838834764831845f
#define CLAMPV 1e30f

// output offsets (elements)
#define OUT_SHARP  16793600
#define OUT_NEGENT 16793728
#define OUT_LZ     16793856
#define OUT_PZ     16810240
#define OUT_SIG    16826624

// ws offsets (floats)
#define WS_HL     0
#define WS_DUST   2097152
#define WS_SHARPP 2113536
#define WS_ENTP   2114560
#define WS_PG     2115584
#define WS_PCNTB  2131968
#define WS_FLAG   2132096
#define WS_PPART  2132112
#define WS_PCNT   3180688
#define WS_END_A  3188880

__device__ __forceinline__ float gelu_(float x) {
    return 0.5f * x * (1.0f + erff(x * 0.7071067811865476f));
}
__device__ __forceinline__ float bf2f(unsigned short u) {
    return __uint_as_float(((unsigned)u) << 16);
}
__device__ __forceinline__ float sanz(float x) {
    return fminf(fmaxf(x, -CLAMPV), CLAMPV);   // NaN -> -CLAMPV
}
template<int BF> __device__ __forceinline__ float ldf(const void* p, int i) {
    if constexpr (BF) return bf2f(((const unsigned short*)p)[i]);
    else return ((const float*)p)[i];
}
template<int BF> __device__ __forceinline__ void stf(void* p, size_t i, float x) {
    x = sanz(x);
    if constexpr (BF) ((__hip_bfloat16*)p)[i] = __float2bfloat16(x);
    else ((float*)p)[i] = x;
}
__device__ __forceinline__ float maskf(const void* m, int mm, int idx) {
    if (mm == 3) return ((const float*)m)[idx] != 0.f ? 1.f : 0.f;
    if (mm == 2) return ((const unsigned short*)m)[idx] ? 1.f : 0.f;
    if (mm == 1) return ((const unsigned char*)m)[idx] ? 1.f : 0.f;
    return ((const int*)m)[idx] ? 1.f : 0.f;
}
__device__ __forceinline__ int typf(const void* p, int tm, int idx) {
    int v;
    if (tm == 2) v = (int)bf2f(((const unsigned short*)p)[idx]);
    else if (tm == 1) v = (int)((const long long*)p)[idx];
    else v = ((const int*)p)[idx];
    return v < 0 ? 0 : (v > NT_ - 1 ? NT_ - 1 : v);
}

// flags[0]=mask mode (0 i32/1 byte/2 bf16/3 f32); flags[1]=float (0 f32/1 bf16);
// flags[2]=typ (0 i32/1 i64/2 bf16)
__global__ __launch_bounds__(64) void detect_k(const unsigned int* __restrict__ px,
                                               const unsigned int* __restrict__ pm,
                                               const unsigned int* __restrict__ pt,
                                               int* __restrict__ flags)
{
    const int t = threadIdx.x;
    int hit = 0;
    for (int i = t; i < 4096; i += 64) {
        unsigned e = (px[i] >> 7) & 0xFFu;
        hit += (e >= 110 && e <= 132) ? 1 : 0;
    }
    for (int s = 1; s < 64; s <<= 1) hit += __shfl_xor(hit, s);

    unsigned big = 0, lo3f = 0, hi3f = 0;
    for (int i = t; i < 1024; i += 64) {
        unsigned w = pm[i];
        big  |= (w > 1u) ? 1u : 0u;
        lo3f |= ((w & 0xFFFFu) == 0x3F80u) ? 1u : 0u;
        hi3f |= ((w >> 16) == 0x3F80u) ? 1u : 0u;
    }
    unsigned long long aBig = __ballot(big != 0), aLo = __ballot(lo3f != 0), aHi = __ballot(hi3f != 0);

    unsigned tbig = 0, oddnz = 0;
    for (int i = t; i < 512; i += 64) {
        unsigned we = pt[2 * i], wo = pt[2 * i + 1];
        tbig  |= (we > 0xFFFFu || wo > 0xFFFFu) ? 1u : 0u;
        oddnz |= (wo != 0u) ? 1u : 0u;
    }
    unsigned long long aTb = __ballot(tbig != 0), aOdd = __ballot(oddnz != 0);

    if (t == 0) {
        flags[1] = (hit > 2048) ? 1 : 0;
        flags[0] = aLo ? 2 : (aHi ? 3 : (aBig ? 1 : 0));
        flags[2] = aTb ? 2 : (!aOdd ? 1 : 0);
    }
}

__global__ __launch_bounds__(256) void zero_k(float* __restrict__ pg, float* __restrict__ pcntB)
{
    const int t = blockIdx.x * 256 + threadIdx.x;
    if (t < B_ * D_) pg[t] = 0.f;
    if (t < B_) pcntB[t] = 0.f;
}

// ---------------- encode L ----------------
#define RL 8
template<int BF> __device__ __forceinline__ void enc_l_body(
    const void* l_x, const void* l_typ, int tm,
    const void* w1, const void* b1, const void* w2, const void* b2,
    const void* lng, const void* lnb, const void* emb, const void* proj,
    const void* dustv, float* hL, float* dust)
{
    __shared__ __align__(16) float X[RL * 8];
    __shared__ __align__(16) float H[RL][D_];
    __shared__ __align__(16) float Y[RL][D_];
    __shared__ float mus[RL], rss[RL];
    const int o = threadIdx.x;
    const int base = blockIdx.x * RL;

    if (o < RL * 8) X[o] = ldf<BF>(l_x, base * 8 + o);
    __syncthreads();

    float acc[RL];
    const float b1o = ldf<BF>(b1, o);
#pragma unroll
    for (int r = 0; r < RL; r++) acc[r] = b1o;
#pragma unroll
    for (int i = 0; i < 8; i += 4) {
        float wa = ldf<BF>(w1, (i + 0) * D_ + o), wb = ldf<BF>(w1, (i + 1) * D_ + o);
        float wc = ldf<BF>(w1, (i + 2) * D_ + o), wd = ldf<BF>(w1, (i + 3) * D_ + o);
#pragma unroll
        for (int r = 0; r < RL; r++) {
            const float4 x4 = *(const float4*)&X[r * 8 + i];
            acc[r] = fmaf(x4.x, wa, fmaf(x4.y, wb, fmaf(x4.z, wc, fmaf(x4.w, wd, acc[r]))));
        }
    }
#pragma unroll
    for (int r = 0; r < RL; r++) H[r][o] = gelu_(acc[r]);
    __syncthreads();

#pragma unroll
    for (int r = 0; r < RL; r++) {
        int tt = typf(l_typ, tm, base + r);
        acc[r] = ldf<BF>(b2, o) + ldf<BF>(emb, tt * D_ + o);
    }
    for (int i = 0; i < D_; i += 4) {
        float wa = ldf<BF>(w2, (i + 0) * D_ + o), wb = ldf<BF>(w2, (i + 1) * D_ + o);
        float wc = ldf<BF>(w2, (i + 2) * D_ + o), wd = ldf<BF>(w2, (i + 3) * D_ + o);
#pragma unroll
        for (int r = 0; r < RL; r++) {
            const float4 h4 = *(const float4*)&H[r][i];
            acc[r] = fmaf(h4.x, wa, fmaf(h4.y, wb, fmaf(h4.z, wc, fmaf(h4.w, wd, acc[r]))));
        }
    }
#pragma unroll
    for (int r = 0; r < RL; r++) Y[r][o] = acc[r];
    __syncthreads();

    {
        const int r = o >> 4, j = o & 15;
        float s = 0.f;
#pragma unroll
        for (int i = 0; i < 8; i++) s += Y[r][j * 8 + i];
        s += __shfl_xor(s, 1); s += __shfl_xor(s, 2); s += __shfl_xor(s, 4); s += __shfl_xor(s, 8);
        const float mu = s * (1.f / 128.f);
        float v = 0.f;
#pragma unroll
        for (int i = 0; i < 8; i++) { float d = Y[r][j * 8 + i] - mu; v = fmaf(d, d, v); }
        v += __shfl_xor(v, 1); v += __shfl_xor(v, 2); v += __shfl_xor(v, 4); v += __shfl_xor(v, 8);
        if (j == 0) { mus[r] = mu; rss[r] = rsqrtf(v * (1.f / 128.f) + 1e-5f); }
    }
    __syncthreads();
    {
        const float g = ldf<BF>(lng, o), bl = ldf<BF>(lnb, o);
#pragma unroll
        for (int r = 0; r < RL; r++) Y[r][o] = fmaf((Y[r][o] - mus[r]) * rss[r], g, bl);
    }
    __syncthreads();

#pragma unroll
    for (int r = 0; r < RL; r++) acc[r] = 0.f;
    for (int i = 0; i < D_; i += 4) {
        float wa = ldf<BF>(proj, (i + 0) * D_ + o), wb = ldf<BF>(proj, (i + 1) * D_ + o);
        float wc = ldf<BF>(proj, (i + 2) * D_ + o), wd = ldf<BF>(proj, (i + 3) * D_ + o);
#pragma unroll
        for (int r = 0; r < RL; r++) {
            const float4 y4 = *(const float4*)&Y[r][i];
            acc[r] = fmaf(y4.x, wa, fmaf(y4.y, wb, fmaf(y4.z, wc, fmaf(y4.w, wd, acc[r]))));
        }
    }
    const float dvo = ldf<BF>(dustv, o);
#pragma unroll
    for (int r = 0; r < RL; r++) {
        hL[(size_t)(base + r) * D_ + o] = acc[r];
        H[r][o] = acc[r] * dvo;
    }
    __syncthreads();
    {
        const int r = o >> 4, j = o & 15;
        float s = 0.f;
#pragma unroll
        for (int i = 0; i < 8; i++) s += H[r][j * 8 + i];
        s += __shfl_xor(s, 1); s += __shfl_xor(s, 2); s += __shfl_xor(s, 4); s += __shfl_xor(s, 8);
        if (j == 0) dust[base + r] = s * SCALE_;
    }
}

__global__ __launch_bounds__(128) void enc_l_k(
    const void* l_x, const void* l_typ,
    const void* w1, const void* b1, const void* w2, const void* b2,
    const void* lng, const void* lnb, const void* emb, const void* proj,
    const void* dustv, float* hL, float* dust, const int* flags)
{
    const int tm = flags[2];
    if (flags[1]) enc_l_body<1>(l_x, l_typ, tm, w1, b1, w2, b2, lng, lnb, emb, proj, dustv, hL, dust);
    else          enc_l_body<0>(l_x, l_typ, tm, w1, b1, w2, b2, lng, lnb, emb, proj, dustv, hL, dust);
}

// ---------------- encode P + sigma + pool-partials + raw logits ----------------
#define RP 16
template<int BF> __device__ __forceinline__ void enc_pl_body(
    const void* p_x, const void* p_typ, int tm,
    const void* p_score, const void* p_rad,
    const void* w1, const void* b1, const void* w2, const void* b2,
    const void* sw1, const void* sb1, const void* sw2, const void* sb2,
    const void* lng, const void* lnb, const void* emb, const void* proj,
    const void* gw1, const void* gb1, const void* gw2, const void* gb2,
    const float* hL, const void* p_mask, int mm, int layoutA,
    void* out, float* ppart, float* pcnt, float* pg, float* pcntB)
{
    __shared__ __align__(16) float A[RP * 192];
    __shared__ __align__(16) float Bb[RP][D_];
    __shared__ __align__(16) float Cc[RP][D_];
    __shared__ __align__(16) float Lh[D_ * 33];
    __shared__ float mus[RP], rss[RP], pm_s[RP];
    const int o = threadIdx.x;
    const int b = blockIdx.x >> 6;
    const int tile = blockIdx.x & 63;
    const int p0 = tile * RP;
    const int base = b * P_ + p0;

    for (int idx = o; idx < RP * 192; idx += 128) A[idx] = ldf<BF>(p_x, base * 192 + idx);
    if (o < RP) pm_s[o] = maskf(p_mask, mm, base + o);
    __syncthreads();

    float acc[RP];
    const float b1o = ldf<BF>(b1, o);
#pragma unroll
    for (int r = 0; r < RP; r++) acc[r] = b1o;
    for (int i = 0; i < 192; i += 4) {
        float wa = ldf<BF>(w1, (i + 0) * D_ + o), wb = ldf<BF>(w1, (i + 1) * D_ + o);
        float wc = ldf<BF>(w1, (i + 2) * D_ + o), wd = ldf<BF>(w1, (i + 3) * D_ + o);
#pragma unroll
        for (int r = 0; r < RP; r++) {
            const float4 x4 = *(const float4*)&A[r * 192 + i];
            acc[r] = fmaf(x4.x, wa, fmaf(x4.y, wb, fmaf(x4.z, wc, fmaf(x4.w, wd, acc[r]))));
        }
    }
#pragma unroll
    for (int r = 0; r < RP; r++) Bb[r][o] = gelu_(acc[r]);
    {
        const float a1 = ldf<BF>(sw1, o), a0 = ldf<BF>(sb1, o);
#pragma unroll
        for (int r = 0; r < RP; r++) Cc[r][o] = gelu_(fmaf(ldf<BF>(p_score, base + r), a1, a0));
    }
    __syncthreads();

#pragma unroll
    for (int r = 0; r < RP; r++) {
        int tt = typf(p_typ, tm, base + r);
        acc[r] = ldf<BF>(b2, o) + ldf<BF>(sb2, o) + ldf<BF>(emb, tt * D_ + o);
    }
    for (int i = 0; i < D_; i += 4) {
        float wa = ldf<BF>(w2, (i + 0) * D_ + o), wb = ldf<BF>(w2, (i + 1) * D_ + o);
        float wc = ldf<BF>(w2, (i + 2) * D_ + o), wd = ldf<BF>(w2, (i + 3) * D_ + o);
        float va = ldf<BF>(sw2, (i + 0) * D_ + o), vb = ldf<BF>(sw2, (i + 1) * D_ + o);
        float vc = ldf<BF>(sw2, (i + 2) * D_ + o), vd = ldf<BF>(sw2, (i + 3) * D_ + o);
#pragma unroll
        for (int r = 0; r < RP; r++) {
            const float4 h4 = *(const float4*)&Bb[r][i];
            const float4 s4 = *(const float4*)&Cc[r][i];
            float t0 = fmaf(h4.x, wa, fmaf(s4.x, va, acc[r]));
            float t1 = fmaf(h4.y, wb, fmaf(s4.y, vb, t0));
            float t2 = fmaf(h4.z, wc, fmaf(s4.z, vc, t1));
            acc[r]   = fmaf(h4.w, wd, fmaf(s4.w, vd, t2));
        }
    }
    __syncthreads();
#pragma unroll
    for (int r = 0; r < RP; r++) Bb[r][o] = acc[r];
    __syncthreads();

    {
        const int r = o >> 3, j = o & 7;
        float s = 0.f;
#pragma unroll
        for (int i = 0; i < 16; i++) s += Bb[r][j * 16 + i];
        s += __shfl_xor(s, 1); s += __shfl_xor(s, 2); s += __shfl_xor(s, 4);
        const float mu = s * (1.f / 128.f);
        float v = 0.f;
#pragma unroll
        for (int i = 0; i < 16; i++) { float d = Bb[r][j * 16 + i] - mu; v = fmaf(d, d, v); }
        v += __shfl_xor(v, 1); v += __shfl_xor(v, 2); v += __shfl_xor(v, 4);
        if (j == 0) { mus[r] = mu; rss[r] = rsqrtf(v * (1.f / 128.f) + 1e-5f); }
    }
    __syncthreads();
    {
        const float g = ldf<BF>(lng, o), bl = ldf<BF>(lnb, o);
#pragma unroll
        for (int r = 0; r < RP; r++) Bb[r][o] = fmaf((Bb[r][o] - mus[r]) * rss[r], g, bl);
    }
    __syncthreads();

#pragma unroll
    for (int r = 0; r < RP; r++) acc[r] = 0.f;
    for (int i = 0; i < D_; i += 4) {
        float wa = ldf<BF>(proj, (i + 0) * D_ + o), wb = ldf<BF>(proj, (i + 1) * D_ + o);
        float wc = ldf<BF>(proj, (i + 2) * D_ + o), wd = ldf<BF>(proj, (i + 3) * D_ + o);
#pragma unroll
        for (int r = 0; r < RP; r++) {
            const float4 y4 = *(const float4*)&Bb[r][i];
            acc[r] = fmaf(y4.x, wa, fmaf(y4.y, wb, fmaf(y4.z, wc, fmaf(y4.w, wd, acc[r]))));
        }
    }
#pragma unroll
    for (int r = 0; r < RP; r++) A[r * D_ + o] = acc[r];
    __syncthreads();

    {
        float s = 0.f;
#pragma unroll
        for (int r = 0; r < RP; r++) s = fmaf(A[r * D_ + o], pm_s[r], s);
        if (layoutA) {
            ppart[(size_t)blockIdx.x * D_ + o] = s;
            if (o == 0) {
                float c = 0.f;
#pragma unroll
                for (int r = 0; r < RP; r++) c += pm_s[r];
                pcnt[blockIdx.x] = c;
            }
        } else {
            atomicAdd(&pg[b * D_ + o], s);
            if (o == 0) {
                float c = 0.f;
#pragma unroll
                for (int r = 0; r < RP; r++) c += pm_s[r];
                atomicAdd(&pcntB[b], c);
            }
        }
    }

#pragma unroll
    for (int r = 0; r < RP; r++) acc[r] = ldf<BF>(gb1, o);
    for (int i = 0; i < D_; i += 4) {
        float wa = ldf<BF>(gw1, (i + 0) * D_ + o), wb = ldf<BF>(gw1, (i + 1) * D_ + o);
        float wc = ldf<BF>(gw1, (i + 2) * D_ + o), wd = ldf<BF>(gw1, (i + 3) * D_ + o);
#pragma unroll
        for (int r = 0; r < RP; r++) {
            const float4 h4 = *(const float4*)&A[r * D_ + i];
            acc[r] = fmaf(h4.x, wa, fmaf(h4.y, wb, fmaf(h4.z, wc, fmaf(h4.w, wd, acc[r]))));
        }
    }
#pragma unroll
    for (int r = 0; r < RP; r++) Cc[r][o] = gelu_(acc[r]);
    __syncthreads();
    {
        const int r = o >> 3, j = o & 7;
        float s = 0.f;
#pragma unroll
        for (int i = 0; i < 16; i++) s = fmaf(Cc[r][j * 16 + i], ldf<BF>(gw2, j * 16 + i), s);
        s += __shfl_xor(s, 1); s += __shfl_xor(s, 2); s += __shfl_xor(s, 4);
        if (j == 0) {
            float v = s + ldf<BF>(gb2, 0);
            float sp = fmaxf(v, 0.f) + log1pf(expf(-fabsf(v)));
            stf<BF>(out, (size_t)OUT_SIG + base + r, sp + 1e-3f + fmaxf(ldf<BF>(p_rad, base + r), 0.f));
        }
    }

    float lg[RP];
#pragma unroll
    for (int r = 0; r < RP; r++) lg[r] = 0.f;
    for (int kc = 0; kc < 4; kc++) {
        __syncthreads();
        for (int idx = o; idx < D_ * 32; idx += 128) {
            const int l = idx >> 5, kk = idx & 31;
            Lh[l * 33 + kk] = hL[((size_t)b * L_ + l) * D_ + kc * 32 + kk];
        }
        __syncthreads();
        for (int kk = 0; kk < 32; kk++) {
            const float al = Lh[o * 33 + kk];
            const int hb = kc * 32 + kk;
#pragma unroll
            for (int r = 0; r < RP; r++)
                lg[r] = fmaf(al, A[r * D_ + hb], lg[r]);
        }
    }
#pragma unroll
    for (int r = 0; r < RP; r++)
        stf<BF>(out, ((size_t)(b * L_ + o)) * (P_ + 1) + p0 + r, lg[r]);
}

__global__ __launch_bounds__(128) void enc_pl_k(
    const void* p_x, const void* p_typ, const void* p_score, const void* p_rad,
    const void* w1, const void* b1, const void* w2, const void* b2,
    const void* sw1, const void* sb1, const void* sw2, const void* sb2,
    const void* lng, const void* lnb, const void* emb, const void* proj,
    const void* gw1, const void* gb1, const void* gw2, const void* gb2,
    const float* hL, const void* p_mask, const int* flags, int layoutA,
    void* out, float* ppart, float* pcnt, float* pg, float* pcntB)
{
    const int tm = flags[2], mm = flags[0];
    if (flags[1]) enc_pl_body<1>(p_x, p_typ, tm, p_score, p_rad, w1, b1, w2, b2, sw1, sb1, sw2, sb2,
                                 lng, lnb, emb, proj, gw1, gb1, gw2, gb2, hL, p_mask, mm, layoutA,
                                 out, ppart, pcnt, pg, pcntB);
    else          enc_pl_body<0>(p_x, p_typ, tm, p_score, p_rad, w1, b1, w2, b2, sw1, sb1, sw2, sb2,
                                 lng, lnb, emb, proj, gw1, gb1, gw2, gb2, hL, p_mask, mm, layoutA,
                                 out, ppart, pcnt, pg, pcntB);
}

// ---------------- softmax over logW rows (in place) + sharp/ent partials ----------------
template<int BF> __device__ __forceinline__ void softmax_body(
    const float* dust, const void* l_mask, const void* p_mask, int mm,
    void* out, float* sharp_parts, float* ent_parts)
{
    __shared__ float dv_s[16], lm_s[16];
    __shared__ float redA[64], redB[64], redC[64], redD[64];
    const int t = threadIdx.x;
    const int b = blockIdx.x >> 3;
    const int l0 = (blockIdx.x & 7) * 16;

    if (t < 16) {
        dv_s[t] = dust[b * L_ + l0 + t];
        lm_s[t] = maskf(l_mask, mm, b * L_ + l0 + t);
    }
    __syncthreads();

    float pmv[4];
#pragma unroll
    for (int j = 0; j < 4; j++) pmv[j] = maskf(p_mask, mm, b * P_ + t + 256 * j);

    const int lane = t & 63, wid = t >> 6;
    float acc[16][4], mrow[16], lse[16];

#pragma unroll
    for (int r = 0; r < 16; r++) {
        const size_t row = ((size_t)(b * L_ + l0 + r)) * (P_ + 1);
        const bool lmr = lm_s[r] != 0.f;
        float m = NEGF;
#pragma unroll
        for (int j = 0; j < 4; j++) {
            float raw = ldf<BF>(out, (int)(row + t + 256 * j));
            float v = (lmr && pmv[j] != 0.f) ? raw * SCALE_ : NEGF;
            acc[r][j] = v;
            m = fmaxf(m, v);
        }
        m = fmaxf(m, __shfl_xor(m, 1));  m = fmaxf(m, __shfl_xor(m, 2));
        m = fmaxf(m, __shfl_xor(m, 4));  m = fmaxf(m, __shfl_xor(m, 8));
        m = fmaxf(m, __shfl_xor(m, 16)); m = fmaxf(m, __shfl_xor(m, 32));
        if (lane == 0) redA[r * 4 + wid] = m;
    }
    __syncthreads();
#pragma unroll
    for (int r = 0; r < 16; r++) {
        float m = fmaxf(fmaxf(redA[r * 4 + 0], redA[r * 4 + 1]), fmaxf(redA[r * 4 + 2], redA[r * 4 + 3]));
        float dvr = (lm_s[r] != 0.f) ? dv_s[r] : NEGF;
        mrow[r] = fmaxf(m, dvr);
    }
#pragma unroll
    for (int r = 0; r < 16; r++) {
        float s = expf(acc[r][0] - mrow[r]) + expf(acc[r][1] - mrow[r])
                + expf(acc[r][2] - mrow[r]) + expf(acc[r][3] - mrow[r]);
        s += __shfl_xor(s, 1);  s += __shfl_xor(s, 2);  s += __shfl_xor(s, 4);
        s += __shfl_xor(s, 8);  s += __shfl_xor(s, 16); s += __shfl_xor(s, 32);
        if (lane == 0) redB[r * 4 + wid] = s;
    }
    __syncthreads();
#pragma unroll
    for (int r = 0; r < 16; r++) {
        float dvr = (lm_s[r] != 0.f) ? dv_s[r] : NEGF;
        float s = (redB[r * 4 + 0] + redB[r * 4 + 1]) + (redB[r * 4 + 2] + redB[r * 4 + 3]);
        s += expf(dvr - mrow[r]);
        lse[r] = logf(s);
    }
#pragma unroll
    for (int r = 0; r < 16; r++) {
        const size_t row = ((size_t)(b * L_ + l0 + r)) * (P_ + 1);
        float mw = 0.f, es = 0.f;
#pragma unroll
        for (int j = 0; j < 4; j++) {
            float lw = acc[r][j] - mrow[r] - lse[r];
            stf<BF>(out, row + t + 256 * j, lw);
            float lwc = fmaxf(lw, -CLAMPV);
            float wm = expf(lwc) * pmv[j];
            mw = fmaxf(mw, wm);
            if (wm > 0.f) es = fmaf(-wm, lwc, es);
        }
        mw = fmaxf(mw, __shfl_xor(mw, 1));  mw = fmaxf(mw, __shfl_xor(mw, 2));
        mw = fmaxf(mw, __shfl_xor(mw, 4));  mw = fmaxf(mw, __shfl_xor(mw, 8));
        mw = fmaxf(mw, __shfl_xor(mw, 16)); mw = fmaxf(mw, __shfl_xor(mw, 32));
        es += __shfl_xor(es, 1);  es += __shfl_xor(es, 2);  es += __shfl_xor(es, 4);
        es += __shfl_xor(es, 8);  es += __shfl_xor(es, 16); es += __shfl_xor(es, 32);
        if (lane == 0) { redC[r * 4 + wid] = mw; redD[r * 4 + wid] = es; }
    }
    __syncthreads();
    if (t < 16) {
        float dvr = (lm_s[t] != 0.f) ? dv_s[t] : NEGF;
        stf<BF>(out, ((size_t)(b * L_ + l0 + t)) * (P_ + 1) + P_, dvr - mrow[t] - lse[t]);
    }
    if (t == 0) {
        float sp = 0.f, en = 0.f;
        for (int r = 0; r < 16; r++) {
            float dvr = (lm_s[r] != 0.f) ? dv_s[r] : NEGF;
            float lwd = fmaxf(dvr - mrow[r] - lse[r], -CLAMPV);
            float wd = expf(lwd);
            float mw = fmaxf(fmaxf(redC[r * 4 + 0], redC[r * 4 + 1]), fmaxf(redC[r * 4 + 2], redC[r * 4 + 3]));
            mw = fmaxf(mw, wd);
            float es = (redD[r * 4 + 0] + redD[r * 4 + 1]) + (redD[r * 4 + 2] + redD[r * 4 + 3]);
            if (wd > 0.f) es = fmaf(-wd, lwd, es);
            sp = fmaf(mw, lm_s[r], sp);
            en = fmaf(es, lm_s[r], en);
        }
        sharp_parts[blockIdx.x] = sp;
        ent_parts[blockIdx.x] = en;
    }
}

__global__ __launch_bounds__(256) void softmax_k(
    const float* dust, const void* l_mask, const void* p_mask, const int* flags,
    void* out, float* sharp_parts, float* ent_parts)
{
    const int mm = flags[0];
    if (flags[1]) softmax_body<1>(dust, l_mask, p_mask, mm, out, sharp_parts, ent_parts);
    else          softmax_body<0>(dust, l_mask, p_mask, mm, out, sharp_parts, ent_parts);
}

// ---------------- pooled L -> retr -> l2norm ----------------
template<int BF> __device__ __forceinline__ void pool_l_body(
    const float* hL, const void* l_mask, int mm, const void* retr, void* out)
{
    __shared__ float lmv[L_];
    __shared__ __align__(16) float lg[D_];
    __shared__ float red[2];
    const int o = threadIdx.x, b = blockIdx.x;
    lmv[o] = maskf(l_mask, mm, b * L_ + o);
    __syncthreads();
    float cnt = 0.f;
    for (int l = 0; l < L_; l++) cnt += lmv[l];
    float s0 = 0, s1 = 0, s2 = 0, s3 = 0;
    const float* hb = hL + (size_t)b * L_ * D_;
    for (int l = 0; l < L_; l += 4) {
        s0 = fmaf(hb[(l + 0) * D_ + o], lmv[l + 0], s0);
        s1 = fmaf(hb[(l + 1) * D_ + o], lmv[l + 1], s1);
        s2 = fmaf(hb[(l + 2) * D_ + o], lmv[l + 2], s2);
        s3 = fmaf(hb[(l + 3) * D_ + o], lmv[l + 3], s3);
    }
    lg[o] = ((s0 + s1) + (s2 + s3)) / fmaxf(cnt, 1.f);
    __syncthreads();
    float r = 0.f;
    for (int i = 0; i < D_; i += 4) {
        const float4 g4 = *(const float4*)&lg[i];
        r = fmaf(g4.x, ldf<BF>(retr, (i + 0) * D_ + o), r);
        r = fmaf(g4.y, ldf<BF>(retr, (i + 1) * D_ + o), r);
        r = fmaf(g4.z, ldf<BF>(retr, (i + 2) * D_ + o), r);
        r = fmaf(g4.w, ldf<BF>(retr, (i + 3) * D_ + o), r);
    }
    float n = r * r;
    n += __shfl_xor(n, 1); n += __shfl_xor(n, 2); n += __shfl_xor(n, 4);
    n += __shfl_xor(n, 8); n += __shfl_xor(n, 16); n += __shfl_xor(n, 32);
    if ((o & 63) == 0) red[o >> 6] = n;
    __syncthreads();
    float nrm = fmaxf(sqrtf(red[0] + red[1]), 1e-12f);
    stf<BF>(out, (size_t)OUT_LZ + b * D_ + o, r / nrm);
}

__global__ __launch_bounds__(128) void pool_l_k(
    const float* hL, const void* l_mask, const int* flags, const void* retr, void* out)
{
    const int mm = flags[0];
    if (flags[1]) pool_l_body<1>(hL, l_mask, mm, retr, out);
    else          pool_l_body<0>(hL, l_mask, mm, retr, out);
}

// ---------------- pooled P -> retr -> l2norm ----------------
template<int BF> __device__ __forceinline__ void pool_p_body(
    const float* ppart, const float* pcnt, const float* pg, const float* pcntB,
    int layoutA, const void* retr, void* out)
{
    __shared__ __align__(16) float pgs[D_];
    __shared__ float red[2];
    const int o = threadIdx.x, b = blockIdx.x;
    float s = 0.f, c = 0.f;
    if (layoutA) {
        for (int k = 0; k < 64; k++) s += ppart[(size_t)(b * 64 + k) * D_ + o];
        for (int k = 0; k < 64; k++) c += pcnt[b * 64 + k];
    } else {
        s = pg[b * D_ + o];
        c = pcntB[b];
    }
    pgs[o] = s / fmaxf(c, 1.f);
    __syncthreads();
    float r = 0.f;
    for (int i = 0; i < D_; i += 4) {
        const float4 g4 = *(const float4*)&pgs[i];
        r = fmaf(g4.x, ldf<BF>(retr, (i + 0) * D_ + o), r);
        r = fmaf(g4.y, ldf<BF>(retr, (i + 1) * D_ + o), r);
        r = fmaf(g4.z, ldf<BF>(retr, (i + 2) * D_ + o), r);
        r = fmaf(g4.w, ldf<BF>(retr, (i + 3) * D_ + o), r);
    }
    float n = r * r;
    n += __shfl_xor(n, 1); n += __shfl_xor(n, 2); n += __shfl_xor(n, 4);
    n += __shfl_xor(n, 8); n += __shfl_xor(n, 16); n += __shfl_xor(n, 32);
    if ((o & 63) == 0) red[o >> 6] = n;
    __syncthreads();
    float nrm = fmaxf(sqrtf(red[0] + red[1]), 1e-12f);
    stf<BF>(out, (size_t)OUT_PZ + b * D_ + o, r / nrm);
}

__global__ __launch_bounds__(128) void pool_p_k(
    const float* ppart, const float* pcnt, const float* pg, const float* pcntB,
    const int* flags, int layoutA, const void* retr, void* out)
{
    if (flags[1]) pool_p_body<1>(ppart, pcnt, pg, pcntB, layoutA, retr, out);
    else          pool_p_body<0>(ppart, pcnt, pg, pcntB, layoutA, retr, out);
}

// ---------------- finalize sharp / neg_ent ----------------
template<int BF> __device__ __forceinline__ void finalize_body(
    const void* l_mask, int mm, const float* sharp_parts, const float* ent_parts, void* out)
{
    const int b = threadIdx.x;
    float cnt = 0.f;
    for (int l = 0; l < L_; l++) cnt += maskf(l_mask, mm, b * L_ + l);
    const float den = fmaxf(cnt, 1.f);
    float sp = 0.f, en = 0.f;
    for (int k = 0; k < 8; k++) { sp += sharp_parts[b * 8 + k]; en += ent_parts[b * 8 + k]; }
    stf<BF>(out, (size_t)OUT_SHARP + b, sp / den);
    stf<BF>(out, (size_t)OUT_NEGENT + b, -(en / den));
}

__global__ __launch_bounds__(128) void finalize_k(
    const void* l_mask, const int* flags,
    const float* sharp_parts, const float* ent_parts, void* out)
{
    const int mm = flags[0];
    if (flags[1]) finalize_body<1>(l_mask, mm, sharp_parts, ent_parts, out);
    else          finalize_body<0>(l_mask, mm, sharp_parts, ent_parts, out);
}

extern "C" void kernel_launch(void* const* d_in, const int* in_sizes, int n_in,
                              void* d_out, int out_size, void* d_ws, size_t ws_size,
                              hipStream_t stream)
{
    const void* l_x     = d_in[0];
    const void* l_typ   = d_in[1];
    const void* p_x     = d_in[2];
    const void* p_typ   = d_in[3];
    const void* p_score = d_in[4];
    const void* p_rad   = d_in[5];
    const void* l_mask  = d_in[6];
    const void* p_mask  = d_in[7];
    const void* lt_emb  = d_in[8];
    const void* lx_w1   = d_in[9];
    const void* lx_b1   = d_in[10];
    const void* lx_w2   = d_in[11];
    const void* lx_b2   = d_in[12];
    const void* l_ln_g  = d_in[13];
    const void* l_ln_b  = d_in[14];
    const void* pt_emb  = d_in[15];
    const void* px_w1   = d_in[16];
    const void* px_b1   = d_in[17];
    const void* px_w2   = d_in[18];
    const void* px_b2   = d_in[19];
    const void* ps_w1   = d_in[20];
    const void* ps_b1   = d_in[21];
    const void* ps_w2   = d_in[22];
    const void* ps_b2   = d_in[23];
    const void* p_ln_g  = d_in[24];
    const void* p_ln_b  = d_in[25];
    const void* proj_l  = d_in[26];
    const void* proj_p  = d_in[27];
    const void* dustv   = d_in[28];
    const void* sg_w1   = d_in[29];
    const void* sg_b1   = d_in[30];
    const void* sg_w2   = d_in[31];
    const void* sg_b2   = d_in[32];
    const void* retr_l  = d_in[33];
    const void* retr_p  = d_in[34];

    float* ws     = (float*)d_ws;
    float* hL     = ws + WS_HL;
    float* dust   = ws + WS_DUST;
    float* sharpp = ws + WS_SHARPP;
    float* entp   = ws + WS_ENTP;
    float* pg     = ws + WS_PG;
    float* pcntB  = ws + WS_PCNTB;
    int*   flags  = (int*)(ws + WS_FLAG);
    float* ppart  = ws + WS_PPART;
    float* pcnt   = ws + WS_PCNT;

    const int layoutA = (ws_size >= (size_t)WS_END_A * 4) ? 1 : 0;

    detect_k<<<1, 64, 0, stream>>>((const unsigned int*)p_x, (const unsigned int*)p_mask,
                                   (const unsigned int*)p_typ, flags);
    zero_k<<<(B_ * D_ + 255) / 256, 256, 0, stream>>>(pg, pcntB);
    enc_l_k<<<(B_ * L_) / RL, 128, 0, stream>>>(l_x, l_typ, lx_w1, lx_b1, lx_w2, lx_b2,
                                                l_ln_g, l_ln_b, lt_emb, proj_l, dustv,
                                                hL, dust, flags);
    enc_pl_k<<<B_ * (P_ / RP), 128, 0, stream>>>(p_x, p_typ, p_score, p_rad,
                                                 px_w1, px_b1, px_w2, px_b2,
                                                 ps_w1, ps_b1, ps_w2, ps_b2,
                                                 p_ln_g, p_ln_b, pt_emb, proj_p,
                                                 sg_w1, sg_b1, sg_w2, sg_b2,
                                                 hL, p_mask, flags, layoutA,
                                                 d_out, ppart, pcnt, pg, pcntB);
    softmax_k<<<B_ * 8, 256, 0, stream>>>(dust, l_mask, p_mask, flags, d_out, sharpp, entp);
    pool_l_k<<<B_, 128, 0, stream>>>(hL, l_mask, flags, retr_l, d_out);
    pool_p_k<<<B_, 128, 0, stream>>>(ppart, pcnt, pg, pcntB, flags, layoutA, retr_p, d_out);
    finalize_k<<<1, 128, 0, stream>>>(l_mask, flags, sharpp, entp, d_out);
}

// Round 6
// 850.185 us; speedup vs baseline: 2.9235x; 2.9235x over previous
//
#include <hip/hip_runtime.h>
#include <hip/hip_bf16.h>
#include <math.h>

// PharmMatchNetFast — round 6: enc_pl rewritten for occupancy.
// R5 post-mortem: template<0/1> bodies each allocated their own __shared__
// arrays -> 91.6KB LDS -> 1 block/CU -> 6.1% occupancy -> 22% VALUBusy.
// Fix: dynamic LDS (single allocation, carved), 256-thread blocks (8 rows/
// thread), hL streamed to registers instead of LDS staging.
// All other kernels verbatim from the passing R5 build.
#define B_ 128
#define L_ 128
#define P_ 1024
#define D_ 128
#define NT_ 256

#define NEGF (-__FLT_MAX__)
#define SCALE_ 0.08838834764831845f
#define CLAMPV 1e30f

// output offsets (elements)
#define OUT_SHARP  16793600
#define OUT_NEGENT 16793728
#define OUT_LZ     16793856
#define OUT_PZ     16810240
#define OUT_SIG    16826624

// ws offsets (floats)
#define WS_HL     0
#define WS_DUST   2097152
#define WS_SHARPP 2113536
#define WS_ENTP   2114560
#define WS_PG     2115584
#define WS_PCNTB  2131968
#define WS_FLAG   2132096
#define WS_PPART  2132112
#define WS_PCNT   3180688
#define WS_END_A  3188880

__device__ __forceinline__ float gelu_(float x) {
    return 0.5f * x * (1.0f + erff(x * 0.7071067811865476f));
}
__device__ __forceinline__ float bf2f(unsigned short u) {
    return __uint_as_float(((unsigned)u) << 16);
}
__device__ __forceinline__ float sanz(float x) {
    return fminf(fmaxf(x, -CLAMPV), CLAMPV);   // NaN -> -CLAMPV
}
template<int BF> __device__ __forceinline__ float ldf(const void* p, int i) {
    if constexpr (BF) return bf2f(((const unsigned short*)p)[i]);
    else return ((const float*)p)[i];
}
template<int BF> __device__ __forceinline__ void stf(void* p, size_t i, float x) {
    x = sanz(x);
    if constexpr (BF) ((__hip_bfloat16*)p)[i] = __float2bfloat16(x);
    else ((float*)p)[i] = x;
}
__device__ __forceinline__ float maskf(const void* m, int mm, int idx) {
    if (mm == 3) return ((const float*)m)[idx] != 0.f ? 1.f : 0.f;
    if (mm == 2) return ((const unsigned short*)m)[idx] ? 1.f : 0.f;
    if (mm == 1) return ((const unsigned char*)m)[idx] ? 1.f : 0.f;
    return ((const int*)m)[idx] ? 1.f : 0.f;
}
__device__ __forceinline__ int typf(const void* p, int tm, int idx) {
    int v;
    if (tm == 2) v = (int)bf2f(((const unsigned short*)p)[idx]);
    else if (tm == 1) v = (int)((const long long*)p)[idx];
    else v = ((const int*)p)[idx];
    return v < 0 ? 0 : (v > NT_ - 1 ? NT_ - 1 : v);
}

// flags[0]=mask mode (0 i32/1 byte/2 bf16/3 f32); flags[1]=float (0 f32/1 bf16);
// flags[2]=typ (0 i32/1 i64/2 bf16)
__global__ __launch_bounds__(64) void detect_k(const unsigned int* __restrict__ px,
                                               const unsigned int* __restrict__ pm,
                                               const unsigned int* __restrict__ pt,
                                               int* __restrict__ flags)
{
    const int t = threadIdx.x;
    int hit = 0;
    for (int i = t; i < 4096; i += 64) {
        unsigned e = (px[i] >> 7) & 0xFFu;
        hit += (e >= 110 && e <= 132) ? 1 : 0;
    }
    for (int s = 1; s < 64; s <<= 1) hit += __shfl_xor(hit, s);

    unsigned big = 0, lo3f = 0, hi3f = 0;
    for (int i = t; i < 1024; i += 64) {
        unsigned w = pm[i];
        big  |= (w > 1u) ? 1u : 0u;
        lo3f |= ((w & 0xFFFFu) == 0x3F80u) ? 1u : 0u;
        hi3f |= ((w >> 16) == 0x3F80u) ? 1u : 0u;
    }
    unsigned long long aBig = __ballot(big != 0), aLo = __ballot(lo3f != 0), aHi = __ballot(hi3f != 0);

    unsigned tbig = 0, oddnz = 0;
    for (int i = t; i < 512; i += 64) {
        unsigned we = pt[2 * i], wo = pt[2 * i + 1];
        tbig  |= (we > 0xFFFFu || wo > 0xFFFFu) ? 1u : 0u;
        oddnz |= (wo != 0u) ? 1u : 0u;
    }
    unsigned long long aTb = __ballot(tbig != 0), aOdd = __ballot(oddnz != 0);

    if (t == 0) {
        flags[1] = (hit > 2048) ? 1 : 0;
        flags[0] = aLo ? 2 : (aHi ? 3 : (aBig ? 1 : 0));
        flags[2] = aTb ? 2 : (!aOdd ? 1 : 0);
    }
}

__global__ __launch_bounds__(256) void zero_k(float* __restrict__ pg, float* __restrict__ pcntB)
{
    const int t = blockIdx.x * 256 + threadIdx.x;
    if (t < B_ * D_) pg[t] = 0.f;
    if (t < B_) pcntB[t] = 0.f;
}

// ---------------- encode L (unchanged from R5) ----------------
#define RL 8
template<int BF> __device__ __forceinline__ void enc_l_body(
    const void* l_x, const void* l_typ, int tm,
    const void* w1, const void* b1, const void* w2, const void* b2,
    const void* lng, const void* lnb, const void* emb, const void* proj,
    const void* dustv, float* hL, float* dust)
{
    __shared__ __align__(16) float X[RL * 8];
    __shared__ __align__(16) float H[RL][D_];
    __shared__ __align__(16) float Y[RL][D_];
    __shared__ float mus[RL], rss[RL];
    const int o = threadIdx.x;
    const int base = blockIdx.x * RL;

    if (o < RL * 8) X[o] = ldf<BF>(l_x, base * 8 + o);
    __syncthreads();

    float acc[RL];
    const float b1o = ldf<BF>(b1, o);
#pragma unroll
    for (int r = 0; r < RL; r++) acc[r] = b1o;
#pragma unroll
    for (int i = 0; i < 8; i += 4) {
        float wa = ldf<BF>(w1, (i + 0) * D_ + o), wb = ldf<BF>(w1, (i + 1) * D_ + o);
        float wc = ldf<BF>(w1, (i + 2) * D_ + o), wd = ldf<BF>(w1, (i + 3) * D_ + o);
#pragma unroll
        for (int r = 0; r < RL; r++) {
            const float4 x4 = *(const float4*)&X[r * 8 + i];
            acc[r] = fmaf(x4.x, wa, fmaf(x4.y, wb, fmaf(x4.z, wc, fmaf(x4.w, wd, acc[r]))));
        }
    }
#pragma unroll
    for (int r = 0; r < RL; r++) H[r][o] = gelu_(acc[r]);
    __syncthreads();

#pragma unroll
    for (int r = 0; r < RL; r++) {
        int tt = typf(l_typ, tm, base + r);
        acc[r] = ldf<BF>(b2, o) + ldf<BF>(emb, tt * D_ + o);
    }
    for (int i = 0; i < D_; i += 4) {
        float wa = ldf<BF>(w2, (i + 0) * D_ + o), wb = ldf<BF>(w2, (i + 1) * D_ + o);
        float wc = ldf<BF>(w2, (i + 2) * D_ + o), wd = ldf<BF>(w2, (i + 3) * D_ + o);
#pragma unroll
        for (int r = 0; r < RL; r++) {
            const float4 h4 = *(const float4*)&H[r][i];
            acc[r] = fmaf(h4.x, wa, fmaf(h4.y, wb, fmaf(h4.z, wc, fmaf(h4.w, wd, acc[r]))));
        }
    }
#pragma unroll
    for (int r = 0; r < RL; r++) Y[r][o] = acc[r];
    __syncthreads();

    {
        const int r = o >> 4, j = o & 15;
        float s = 0.f;
#pragma unroll
        for (int i = 0; i < 8; i++) s += Y[r][j * 8 + i];
        s += __shfl_xor(s, 1); s += __shfl_xor(s, 2); s += __shfl_xor(s, 4); s += __shfl_xor(s, 8);
        const float mu = s * (1.f / 128.f);
        float v = 0.f;
#pragma unroll
        for (int i = 0; i < 8; i++) { float d = Y[r][j * 8 + i] - mu; v = fmaf(d, d, v); }
        v += __shfl_xor(v, 1); v += __shfl_xor(v, 2); v += __shfl_xor(v, 4); v += __shfl_xor(v, 8);
        if (j == 0) { mus[r] = mu; rss[r] = rsqrtf(v * (1.f / 128.f) + 1e-5f); }
    }
    __syncthreads();
    {
        const float g = ldf<BF>(lng, o), bl = ldf<BF>(lnb, o);
#pragma unroll
        for (int r = 0; r < RL; r++) Y[r][o] = fmaf((Y[r][o] - mus[r]) * rss[r], g, bl);
    }
    __syncthreads();

#pragma unroll
    for (int r = 0; r < RL; r++) acc[r] = 0.f;
    for (int i = 0; i < D_; i += 4) {
        float wa = ldf<BF>(proj, (i + 0) * D_ + o), wb = ldf<BF>(proj, (i + 1) * D_ + o);
        float wc = ldf<BF>(proj, (i + 2) * D_ + o), wd = ldf<BF>(proj, (i + 3) * D_ + o);
#pragma unroll
        for (int r = 0; r < RL; r++) {
            const float4 y4 = *(const float4*)&Y[r][i];
            acc[r] = fmaf(y4.x, wa, fmaf(y4.y, wb, fmaf(y4.z, wc, fmaf(y4.w, wd, acc[r]))));
        }
    }
    const float dvo = ldf<BF>(dustv, o);
#pragma unroll
    for (int r = 0; r < RL; r++) {
        hL[(size_t)(base + r) * D_ + o] = acc[r];
        H[r][o] = acc[r] * dvo;
    }
    __syncthreads();
    {
        const int r = o >> 4, j = o & 15;
        float s = 0.f;
#pragma unroll
        for (int i = 0; i < 8; i++) s += H[r][j * 8 + i];
        s += __shfl_xor(s, 1); s += __shfl_xor(s, 2); s += __shfl_xor(s, 4); s += __shfl_xor(s, 8);
        if (j == 0) dust[base + r] = s * SCALE_;
    }
}

__global__ __launch_bounds__(128) void enc_l_k(
    const void* l_x, const void* l_typ,
    const void* w1, const void* b1, const void* w2, const void* b2,
    const void* lng, const void* lnb, const void* emb, const void* proj,
    const void* dustv, float* hL, float* dust, const int* flags)
{
    const int tm = flags[2];
    if (flags[1]) enc_l_body<1>(l_x, l_typ, tm, w1, b1, w2, b2, lng, lnb, emb, proj, dustv, hL, dust);
    else          enc_l_body<0>(l_x, l_typ, tm, w1, b1, w2, b2, lng, lnb, emb, proj, dustv, hL, dust);
}

// ---------------- encode P + sigma + pool-partials + raw logits ----------------
// 256 threads: o = t&127 (channel), rh = t>>7 (row half, 8 rows each).
// Dynamic LDS, single allocation: A[16*192] (p_x tile, later hp[16][128]),
// Bb[16*128], Cc[16*128], mus/rss/pm_s[48]. Total 7216 floats = 28.9KB.
#define RP 16
#define ENC_PL_SMEM (7216 * 4)
template<int BF> __device__ __forceinline__ void enc_pl_body(
    float* __restrict__ A, float* __restrict__ Bb, float* __restrict__ Cc,
    float* __restrict__ mus, float* __restrict__ rss, float* __restrict__ pm_s,
    const void* p_x, const void* p_typ, int tm,
    const void* p_score, const void* p_rad,
    const void* w1, const void* b1, const void* w2, const void* b2,
    const void* sw1, const void* sb1, const void* sw2, const void* sb2,
    const void* lng, const void* lnb, const void* emb, const void* proj,
    const void* gw1, const void* gb1, const void* gw2, const void* gb2,
    const float* hL, const void* p_mask, int mm, int layoutA,
    void* out, float* ppart, float* pcnt, float* pg, float* pcntB)
{
    const int t = threadIdx.x;
    const int o = t & 127;
    const int rh = t >> 7;           // 0/1: rows rh*8 .. rh*8+7
    const int b = blockIdx.x >> 6;
    const int tile = blockIdx.x & 63;
    const int p0 = tile * RP;
    const int base = b * P_ + p0;

    // stage p_x tile
    for (int idx = t; idx < RP * 192; idx += 256) A[idx] = ldf<BF>(p_x, base * 192 + idx);
    if (t < RP) pm_s[t] = maskf(p_mask, mm, base + t);
    __syncthreads();

    float acc[8];
    // ---- MLP1: h1 = gelu(x @ w1 + b1)
    {
        const float b1o = ldf<BF>(b1, o);
#pragma unroll
        for (int r = 0; r < 8; r++) acc[r] = b1o;
    }
    for (int i = 0; i < 192; i += 4) {
        float wa = ldf<BF>(w1, (i + 0) * D_ + o), wb = ldf<BF>(w1, (i + 1) * D_ + o);
        float wc = ldf<BF>(w1, (i + 2) * D_ + o), wd = ldf<BF>(w1, (i + 3) * D_ + o);
#pragma unroll
        for (int r = 0; r < 8; r++) {
            const float4 x4 = *(const float4*)&A[(rh * 8 + r) * 192 + i];
            acc[r] = fmaf(x4.x, wa, fmaf(x4.y, wb, fmaf(x4.z, wc, fmaf(x4.w, wd, acc[r]))));
        }
    }
#pragma unroll
    for (int r = 0; r < 8; r++) Bb[(rh * 8 + r) * D_ + o] = gelu_(acc[r]);
    // hs = gelu(score * sw1 + sb1)
    {
        const float a1 = ldf<BF>(sw1, o), a0 = ldf<BF>(sb1, o);
#pragma unroll
        for (int r = 0; r < 8; r++)
            Cc[(rh * 8 + r) * D_ + o] = gelu_(fmaf(ldf<BF>(p_score, base + rh * 8 + r), a1, a0));
    }
    __syncthreads();

    // ---- MLP2 + score-MLP2 + emb: h2 = h1@w2 + hs@sw2 + b2 + sb2 + emb[typ]
    {
        const float bo = ldf<BF>(b2, o) + ldf<BF>(sb2, o);
#pragma unroll
        for (int r = 0; r < 8; r++) {
            int tt = typf(p_typ, tm, base + rh * 8 + r);
            acc[r] = bo + ldf<BF>(emb, tt * D_ + o);
        }
    }
    for (int i = 0; i < D_; i += 4) {
        float wa = ldf<BF>(w2, (i + 0) * D_ + o), wb = ldf<BF>(w2, (i + 1) * D_ + o);
        float wc = ldf<BF>(w2, (i + 2) * D_ + o), wd = ldf<BF>(w2, (i + 3) * D_ + o);
        float va = ldf<BF>(sw2, (i + 0) * D_ + o), vb = ldf<BF>(sw2, (i + 1) * D_ + o);
        float vc = ldf<BF>(sw2, (i + 2) * D_ + o), vd = ldf<BF>(sw2, (i + 3) * D_ + o);
#pragma unroll
        for (int r = 0; r < 8; r++) {
            const int row = rh * 8 + r;
            const float4 h4 = *(const float4*)&Bb[row * D_ + i];
            const float4 s4 = *(const float4*)&Cc[row * D_ + i];
            float t0 = fmaf(h4.x, wa, fmaf(s4.x, va, acc[r]));
            float t1 = fmaf(h4.y, wb, fmaf(s4.y, vb, t0));
            float t2 = fmaf(h4.z, wc, fmaf(s4.z, vc, t1));
            acc[r]   = fmaf(h4.w, wd, fmaf(s4.w, vd, t2));
        }
    }
    __syncthreads();              // all Bb/Cc reads done
#pragma unroll
    for (int r = 0; r < 8; r++) Bb[(rh * 8 + r) * D_ + o] = acc[r];   // h2
    __syncthreads();

    // ---- LN stats: 16 rows x 16 threads/row (t 0..255), two-pass
    {
        const int r = t >> 4, j = t & 15;
        float s = 0.f;
#pragma unroll
        for (int i = 0; i < 8; i++) s += Bb[r * D_ + j * 8 + i];
        s += __shfl_xor(s, 1); s += __shfl_xor(s, 2); s += __shfl_xor(s, 4); s += __shfl_xor(s, 8);
        const float mu = s * (1.f / 128.f);
        float v = 0.f;
#pragma unroll
        for (int i = 0; i < 8; i++) { float d = Bb[r * D_ + j * 8 + i] - mu; v = fmaf(d, d, v); }
        v += __shfl_xor(v, 1); v += __shfl_xor(v, 2); v += __shfl_xor(v, 4); v += __shfl_xor(v, 8);
        if (j == 0) { mus[r] = mu; rss[r] = rsqrtf(v * (1.f / 128.f) + 1e-5f); }
    }
    __syncthreads();
    {
        const float g = ldf<BF>(lng, o), bl = ldf<BF>(lnb, o);
#pragma unroll
        for (int r = 0; r < 8; r++) {
            const int row = rh * 8 + r;
            Bb[row * D_ + o] = fmaf((Bb[row * D_ + o] - mus[row]) * rss[row], g, bl);
        }
    }
    __syncthreads();

    // ---- proj: hp = y @ proj
#pragma unroll
    for (int r = 0; r < 8; r++) acc[r] = 0.f;
    for (int i = 0; i < D_; i += 4) {
        float wa = ldf<BF>(proj, (i + 0) * D_ + o), wb = ldf<BF>(proj, (i + 1) * D_ + o);
        float wc = ldf<BF>(proj, (i + 2) * D_ + o), wd = ldf<BF>(proj, (i + 3) * D_ + o);
#pragma unroll
        for (int r = 0; r < 8; r++) {
            const float4 y4 = *(const float4*)&Bb[(rh * 8 + r) * D_ + i];
            acc[r] = fmaf(y4.x, wa, fmaf(y4.y, wb, fmaf(y4.z, wc, fmaf(y4.w, wd, acc[r]))));
        }
    }
#pragma unroll
    for (int r = 0; r < 8; r++) A[(rh * 8 + r) * D_ + o] = acc[r];   // hp tile (A dead)
    __syncthreads();

    // ---- pool-P partials (rh==0 half only; identical values either way)
    if (rh == 0) {
        float s = 0.f;
#pragma unroll
        for (int r = 0; r < RP; r++) s = fmaf(A[r * D_ + o], pm_s[r], s);
        if (layoutA) {
            ppart[(size_t)blockIdx.x * D_ + o] = s;
            if (t == 0) {
                float c = 0.f;
#pragma unroll
                for (int r = 0; r < RP; r++) c += pm_s[r];
                pcnt[blockIdx.x] = c;
            }
        } else {
            atomicAdd(&pg[b * D_ + o], s);
            if (t == 0) {
                float c = 0.f;
#pragma unroll
                for (int r = 0; r < RP; r++) c += pm_s[r];
                atomicAdd(&pcntB[b], c);
            }
        }
    }

    // ---- sigma head: g1 = gelu(hp @ gw1 + gb1); sig = softplus(g1@gw2+gb2)+...
#pragma unroll
    for (int r = 0; r < 8; r++) acc[r] = ldf<BF>(gb1, o);
    for (int i = 0; i < D_; i += 4) {
        float wa = ldf<BF>(gw1, (i + 0) * D_ + o), wb = ldf<BF>(gw1, (i + 1) * D_ + o);
        float wc = ldf<BF>(gw1, (i + 2) * D_ + o), wd = ldf<BF>(gw1, (i + 3) * D_ + o);
#pragma unroll
        for (int r = 0; r < 8; r++) {
            const float4 h4 = *(const float4*)&A[(rh * 8 + r) * D_ + i];
            acc[r] = fmaf(h4.x, wa, fmaf(h4.y, wb, fmaf(h4.z, wc, fmaf(h4.w, wd, acc[r]))));
        }
    }
#pragma unroll
    for (int r = 0; r < 8; r++) Cc[(rh * 8 + r) * D_ + o] = gelu_(acc[r]);
    __syncthreads();
    {   // 16 rows x 16 threads/row, 8 channels each
        const int r = t >> 4, j = t & 15;
        float s = 0.f;
#pragma unroll
        for (int i = 0; i < 8; i++) s = fmaf(Cc[r * D_ + j * 8 + i], ldf<BF>(gw2, j * 8 + i), s);
        s += __shfl_xor(s, 1); s += __shfl_xor(s, 2); s += __shfl_xor(s, 4); s += __shfl_xor(s, 8);
        if (j == 0) {
            float v = s + ldf<BF>(gb2, 0);
            float sp = fmaxf(v, 0.f) + log1pf(expf(-fabsf(v)));
            stf<BF>(out, (size_t)OUT_SIG + base + r, sp + 1e-3f + fmaxf(ldf<BF>(p_rad, base + r), 0.f));
        }
    }

    // ---- raw logits: thread = (l-row o, col-half rh). hL row streamed to regs,
    // hp tile read via wave-broadcast float4 from LDS.
    float lg[8];
#pragma unroll
    for (int c = 0; c < 8; c++) lg[c] = 0.f;
    {
        const float* hrow = hL + ((size_t)b * L_ + o) * D_;
        for (int kc = 0; kc < 8; kc++) {
            float4 h0 = *(const float4*)&hrow[kc * 16 + 0];
            float4 h1 = *(const float4*)&hrow[kc * 16 + 4];
            float4 h2 = *(const float4*)&hrow[kc * 16 + 8];
            float4 h3 = *(const float4*)&hrow[kc * 16 + 12];
#pragma unroll
            for (int c = 0; c < 8; c++) {
                const float* ap = &A[(rh * 8 + c) * D_ + kc * 16];
                const float4 a0 = *(const float4*)&ap[0];
                const float4 a1 = *(const float4*)&ap[4];
                const float4 a2 = *(const float4*)&ap[8];
                const float4 a3 = *(const float4*)&ap[12];
                float s = lg[c];
                s = fmaf(h0.x, a0.x, fmaf(h0.y, a0.y, fmaf(h0.z, a0.z, fmaf(h0.w, a0.w, s))));
                s = fmaf(h1.x, a1.x, fmaf(h1.y, a1.y, fmaf(h1.z, a1.z, fmaf(h1.w, a1.w, s))));
                s = fmaf(h2.x, a2.x, fmaf(h2.y, a2.y, fmaf(h2.z, a2.z, fmaf(h2.w, a2.w, s))));
                s = fmaf(h3.x, a3.x, fmaf(h3.y, a3.y, fmaf(h3.z, a3.z, fmaf(h3.w, a3.w, s))));
                lg[c] = s;
            }
        }
    }
    {
        const size_t rowoff = ((size_t)(b * L_ + o)) * (P_ + 1) + p0 + rh * 8;
#pragma unroll
        for (int c = 0; c < 8; c++)
            stf<BF>(out, rowoff + c, lg[c]);
    }
}

__global__ __launch_bounds__(256) void enc_pl_k(
    const void* p_x, const void* p_typ, const void* p_score, const void* p_rad,
    const void* w1, const void* b1, const void* w2, const void* b2,
    const void* sw1, const void* sb1, const void* sw2, const void* sb2,
    const void* lng, const void* lnb, const void* emb, const void* proj,
    const void* gw1, const void* gb1, const void* gw2, const void* gb2,
    const float* hL, const void* p_mask, const int* flags, int layoutA,
    void* out, float* ppart, float* pcnt, float* pg, float* pcntB)
{
    extern __shared__ __align__(16) float smem[];
    float* A    = smem;                 // [16*192] then hp [16][128]
    float* Bb   = smem + 3072;          // [16*128]
    float* Cc   = Bb + 2048;            // [16*128]
    float* mus  = Cc + 2048;            // [16]
    float* rss  = mus + 16;             // [16]
    float* pm_s = rss + 16;             // [16]
    const int tm = flags[2], mm = flags[0];
    if (flags[1]) enc_pl_body<1>(A, Bb, Cc, mus, rss, pm_s,
                                 p_x, p_typ, tm, p_score, p_rad, w1, b1, w2, b2, sw1, sb1, sw2, sb2,
                                 lng, lnb, emb, proj, gw1, gb1, gw2, gb2, hL, p_mask, mm, layoutA,
                                 out, ppart, pcnt, pg, pcntB);
    else          enc_pl_body<0>(A, Bb, Cc, mus, rss, pm_s,
                                 p_x, p_typ, tm, p_score, p_rad, w1, b1, w2, b2, sw1, sb1, sw2, sb2,
                                 lng, lnb, emb, proj, gw1, gb1, gw2, gb2, hL, p_mask, mm, layoutA,
                                 out, ppart, pcnt, pg, pcntB);
}

// ---------------- softmax over logW rows (in place) + sharp/ent partials ----------------
template<int BF> __device__ __forceinline__ void softmax_body(
    const float* dust, const void* l_mask, const void* p_mask, int mm,
    void* out, float* sharp_parts, float* ent_parts)
{
    __shared__ float dv_s[16], lm_s[16];
    __shared__ float redA[64], redB[64], redC[64], redD[64];
    const int t = threadIdx.x;
    const int b = blockIdx.x >> 3;
    const int l0 = (blockIdx.x & 7) * 16;

    if (t < 16) {
        dv_s[t] = dust[b * L_ + l0 + t];
        lm_s[t] = maskf(l_mask, mm, b * L_ + l0 + t);
    }
    __syncthreads();

    float pmv[4];
#pragma unroll
    for (int j = 0; j < 4; j++) pmv[j] = maskf(p_mask, mm, b * P_ + t + 256 * j);

    const int lane = t & 63, wid = t >> 6;
    float acc[16][4], mrow[16], lse[16];

#pragma unroll
    for (int r = 0; r < 16; r++) {
        const size_t row = ((size_t)(b * L_ + l0 + r)) * (P_ + 1);
        const bool lmr = lm_s[r] != 0.f;
        float m = NEGF;
#pragma unroll
        for (int j = 0; j < 4; j++) {
            float raw = ldf<BF>(out, (int)(row + t + 256 * j));
            float v = (lmr && pmv[j] != 0.f) ? raw * SCALE_ : NEGF;
            acc[r][j] = v;
            m = fmaxf(m, v);
        }
        m = fmaxf(m, __shfl_xor(m, 1));  m = fmaxf(m, __shfl_xor(m, 2));
        m = fmaxf(m, __shfl_xor(m, 4));  m = fmaxf(m, __shfl_xor(m, 8));
        m = fmaxf(m, __shfl_xor(m, 16)); m = fmaxf(m, __shfl_xor(m, 32));
        if (lane == 0) redA[r * 4 + wid] = m;
    }
    __syncthreads();
#pragma unroll
    for (int r = 0; r < 16; r++) {
        float m = fmaxf(fmaxf(redA[r * 4 + 0], redA[r * 4 + 1]), fmaxf(redA[r * 4 + 2], redA[r * 4 + 3]));
        float dvr = (lm_s[r] != 0.f) ? dv_s[r] : NEGF;
        mrow[r] = fmaxf(m, dvr);
    }
#pragma unroll
    for (int r = 0; r < 16; r++) {
        float s = expf(acc[r][0] - mrow[r]) + expf(acc[r][1] - mrow[r])
                + expf(acc[r][2] - mrow[r]) + expf(acc[r][3] - mrow[r]);
        s += __shfl_xor(s, 1);  s += __shfl_xor(s, 2);  s += __shfl_xor(s, 4);
        s += __shfl_xor(s, 8);  s += __shfl_xor(s, 16); s += __shfl_xor(s, 32);
        if (lane == 0) redB[r * 4 + wid] = s;
    }
    __syncthreads();
#pragma unroll
    for (int r = 0; r < 16; r++) {
        float dvr = (lm_s[r] != 0.f) ? dv_s[r] : NEGF;
        float s = (redB[r * 4 + 0] + redB[r * 4 + 1]) + (redB[r * 4 + 2] + redB[r * 4 + 3]);
        s += expf(dvr - mrow[r]);
        lse[r] = logf(s);
    }
#pragma unroll
    for (int r = 0; r < 16; r++) {
        const size_t row = ((size_t)(b * L_ + l0 + r)) * (P_ + 1);
        float mw = 0.f, es = 0.f;
#pragma unroll
        for (int j = 0; j < 4; j++) {
            float lw = acc[r][j] - mrow[r] - lse[r];
            stf<BF>(out, row + t + 256 * j, lw);
            float lwc = fmaxf(lw, -CLAMPV);
            float wm = expf(lwc) * pmv[j];
            mw = fmaxf(mw, wm);
            if (wm > 0.f) es = fmaf(-wm, lwc, es);
        }
        mw = fmaxf(mw, __shfl_xor(mw, 1));  mw = fmaxf(mw, __shfl_xor(mw, 2));
        mw = fmaxf(mw, __shfl_xor(mw, 4));  mw = fmaxf(mw, __shfl_xor(mw, 8));
        mw = fmaxf(mw, __shfl_xor(mw, 16)); mw = fmaxf(mw, __shfl_xor(mw, 32));
        es += __shfl_xor(es, 1);  es += __shfl_xor(es, 2);  es += __shfl_xor(es, 4);
        es += __shfl_xor(es, 8);  es += __shfl_xor(es, 16); es += __shfl_xor(es, 32);
        if (lane == 0) { redC[r * 4 + wid] = mw; redD[r * 4 + wid] = es; }
    }
    __syncthreads();
    if (t < 16) {
        float dvr = (lm_s[t] != 0.f) ? dv_s[t] : NEGF;
        stf<BF>(out, ((size_t)(b * L_ + l0 + t)) * (P_ + 1) + P_, dvr - mrow[t] - lse[t]);
    }
    if (t == 0) {
        float sp = 0.f, en = 0.f;
        for (int r = 0; r < 16; r++) {
            float dvr = (lm_s[r] != 0.f) ? dv_s[r] : NEGF;
            float lwd = fmaxf(dvr - mrow[r] - lse[r], -CLAMPV);
            float wd = expf(lwd);
            float mw = fmaxf(fmaxf(redC[r * 4 + 0], redC[r * 4 + 1]), fmaxf(redC[r * 4 + 2], redC[r * 4 + 3]));
            mw = fmaxf(mw, wd);
            float es = (redD[r * 4 + 0] + redD[r * 4 + 1]) + (redD[r * 4 + 2] + redD[r * 4 + 3]);
            if (wd > 0.f) es = fmaf(-wd, lwd, es);
            sp = fmaf(mw, lm_s[r], sp);
            en = fmaf(es, lm_s[r], en);
        }
        sharp_parts[blockIdx.x] = sp;
        ent_parts[blockIdx.x] = en;
    }
}

__global__ __launch_bounds__(256) void softmax_k(
    const float* dust, const void* l_mask, const void* p_mask, const int* flags,
    void* out, float* sharp_parts, float* ent_parts)
{
    const int mm = flags[0];
    if (flags[1]) softmax_body<1>(dust, l_mask, p_mask, mm, out, sharp_parts, ent_parts);
    else          softmax_body<0>(dust, l_mask, p_mask, mm, out, sharp_parts, ent_parts);
}

// ---------------- pooled L -> retr -> l2norm ----------------
template<int BF> __device__ __forceinline__ void pool_l_body(
    const float* hL, const void* l_mask, int mm, const void* retr, void* out)
{
    __shared__ float lmv[L_];
    __shared__ __align__(16) float lg[D_];
    __shared__ float red[2];
    const int o = threadIdx.x, b = blockIdx.x;
    lmv[o] = maskf(l_mask, mm, b * L_ + o);
    __syncthreads();
    float cnt = 0.f;
    for (int l = 0; l < L_; l++) cnt += lmv[l];
    float s0 = 0, s1 = 0, s2 = 0, s3 = 0;
    const float* hb = hL + (size_t)b * L_ * D_;
    for (int l = 0; l < L_; l += 4) {
        s0 = fmaf(hb[(l + 0) * D_ + o], lmv[l + 0], s0);
        s1 = fmaf(hb[(l + 1) * D_ + o], lmv[l + 1], s1);
        s2 = fmaf(hb[(l + 2) * D_ + o], lmv[l + 2], s2);
        s3 = fmaf(hb[(l + 3) * D_ + o], lmv[l + 3], s3);
    }
    lg[o] = ((s0 + s1) + (s2 + s3)) / fmaxf(cnt, 1.f);
    __syncthreads();
    float r = 0.f;
    for (int i = 0; i < D_; i += 4) {
        const float4 g4 = *(const float4*)&lg[i];
        r = fmaf(g4.x, ldf<BF>(retr, (i + 0) * D_ + o), r);
        r = fmaf(g4.y, ldf<BF>(retr, (i + 1) * D_ + o), r);
        r = fmaf(g4.z, ldf<BF>(retr, (i + 2) * D_ + o), r);
        r = fmaf(g4.w, ldf<BF>(retr, (i + 3) * D_ + o), r);
    }
    float n = r * r;
    n += __shfl_xor(n, 1); n += __shfl_xor(n, 2); n += __shfl_xor(n, 4);
    n += __shfl_xor(n, 8); n += __shfl_xor(n, 16); n += __shfl_xor(n, 32);
    if ((o & 63) == 0) red[o >> 6] = n;
    __syncthreads();
    float nrm = fmaxf(sqrtf(red[0] + red[1]), 1e-12f);
    stf<BF>(out, (size_t)OUT_LZ + b * D_ + o, r / nrm);
}

__global__ __launch_bounds__(128) void pool_l_k(
    const float* hL, const void* l_mask, const int* flags, const void* retr, void* out)
{
    const int mm = flags[0];
    if (flags[1]) pool_l_body<1>(hL, l_mask, mm, retr, out);
    else          pool_l_body<0>(hL, l_mask, mm, retr, out);
}

// ---------------- pooled P -> retr -> l2norm ----------------
template<int BF> __device__ __forceinline__ void pool_p_body(
    const float* ppart, const float* pcnt, const float* pg, const float* pcntB,
    int layoutA, const void* retr, void* out)
{
    __shared__ __align__(16) float pgs[D_];
    __shared__ float red[2];
    const int o = threadIdx.x, b = blockIdx.x;
    float s = 0.f, c = 0.f;
    if (layoutA) {
        for (int k = 0; k < 64; k++) s += ppart[(size_t)(b * 64 + k) * D_ + o];
        for (int k = 0; k < 64; k++) c += pcnt[b * 64 + k];
    } else {
        s = pg[b * D_ + o];
        c = pcntB[b];
    }
    pgs[o] = s / fmaxf(c, 1.f);
    __syncthreads();
    float r = 0.f;
    for (int i = 0; i < D_; i += 4) {
        const float4 g4 = *(const float4*)&pgs[i];
        r = fmaf(g4.x, ldf<BF>(retr, (i + 0) * D_ + o), r);
        r = fmaf(g4.y, ldf<BF>(retr, (i + 1) * D_ + o), r);
        r = fmaf(g4.z, ldf<BF>(retr, (i + 2) * D_ + o), r);
        r = fmaf(g4.w, ldf<BF>(retr, (i + 3) * D_ + o), r);
    }
    float n = r * r;
    n += __shfl_xor(n, 1); n += __shfl_xor(n, 2); n += __shfl_xor(n, 4);
    n += __shfl_xor(n, 8); n += __shfl_xor(n, 16); n += __shfl_xor(n, 32);
    if ((o & 63) == 0) red[o >> 6] = n;
    __syncthreads();
    float nrm = fmaxf(sqrtf(red[0] + red[1]), 1e-12f);
    stf<BF>(out, (size_t)OUT_PZ + b * D_ + o, r / nrm);
}

__global__ __launch_bounds__(128) void pool_p_k(
    const float* ppart, const float* pcnt, const float* pg, const float* pcntB,
    const int* flags, int layoutA, const void* retr, void* out)
{
    if (flags[1]) pool_p_body<1>(ppart, pcnt, pg, pcntB, layoutA, retr, out);
    else          pool_p_body<0>(ppart, pcnt, pg, pcntB, layoutA, retr, out);
}

// ---------------- finalize sharp / neg_ent ----------------
template<int BF> __device__ __forceinline__ void finalize_body(
    const void* l_mask, int mm, const float* sharp_parts, const float* ent_parts, void* out)
{
    const int b = threadIdx.x;
    float cnt = 0.f;
    for (int l = 0; l < L_; l++) cnt += maskf(l_mask, mm, b * L_ + l);
    const float den = fmaxf(cnt, 1.f);
    float sp = 0.f, en = 0.f;
    for (int k = 0; k < 8; k++) { sp += sharp_parts[b * 8 + k]; en += ent_parts[b * 8 + k]; }
    stf<BF>(out, (size_t)OUT_SHARP + b, sp / den);
    stf<BF>(out, (size_t)OUT_NEGENT + b, -(en / den));
}

__global__ __launch_bounds__(128) void finalize_k(
    const void* l_mask, const int* flags,
    const float* sharp_parts, const float* ent_parts, void* out)
{
    const int mm = flags[0];
    if (flags[1]) finalize_body<1>(l_mask, mm, sharp_parts, ent_parts, out);
    else          finalize_body<0>(l_mask, mm, sharp_parts, ent_parts, out);
}

extern "C" void kernel_launch(void* const* d_in, const int* in_sizes, int n_in,
                              void* d_out, int out_size, void* d_ws, size_t ws_size,
                              hipStream_t stream)
{
    const void* l_x     = d_in[0];
    const void* l_typ   = d_in[1];
    const void* p_x     = d_in[2];
    const void* p_typ   = d_in[3];
    const void* p_score = d_in[4];
    const void* p_rad   = d_in[5];
    const void* l_mask  = d_in[6];
    const void* p_mask  = d_in[7];
    const void* lt_emb  = d_in[8];
    const void* lx_w1   = d_in[9];
    const void* lx_b1   = d_in[10];
    const void* lx_w2   = d_in[11];
    const void* lx_b2   = d_in[12];
    const void* l_ln_g  = d_in[13];
    const void* l_ln_b  = d_in[14];
    const void* pt_emb  = d_in[15];
    const void* px_w1   = d_in[16];
    const void* px_b1   = d_in[17];
    const void* px_w2   = d_in[18];
    const void* px_b2   = d_in[19];
    const void* ps_w1   = d_in[20];
    const void* ps_b1   = d_in[21];
    const void* ps_w2   = d_in[22];
    const void* ps_b2   = d_in[23];
    const void* p_ln_g  = d_in[24];
    const void* p_ln_b  = d_in[25];
    const void* proj_l  = d_in[26];
    const void* proj_p  = d_in[27];
    const void* dustv   = d_in[28];
    const void* sg_w1   = d_in[29];
    const void* sg_b1   = d_in[30];
    const void* sg_w2   = d_in[31];
    const void* sg_b2   = d_in[32];
    const void* retr_l  = d_in[33];
    const void* retr_p  = d_in[34];

    float* ws     = (float*)d_ws;
    float* hL     = ws + WS_HL;
    float* dust   = ws + WS_DUST;
    float* sharpp = ws + WS_SHARPP;
    float* entp   = ws + WS_ENTP;
    float* pg     = ws + WS_PG;
    float* pcntB  = ws + WS_PCNTB;
    int*   flags  = (int*)(ws + WS_FLAG);
    float* ppart  = ws + WS_PPART;
    float* pcnt   = ws + WS_PCNT;

    const int layoutA = (ws_size >= (size_t)WS_END_A * 4) ? 1 : 0;

    detect_k<<<1, 64, 0, stream>>>((const unsigned int*)p_x, (const unsigned int*)p_mask,
                                   (const unsigned int*)p_typ, flags);
    zero_k<<<(B_ * D_ + 255) / 256, 256, 0, stream>>>(pg, pcntB);
    enc_l_k<<<(B_ * L_) / RL, 128, 0, stream>>>(l_x, l_typ, lx_w1, lx_b1, lx_w2, lx_b2,
                                                l_ln_g, l_ln_b, lt_emb, proj_l, dustv,
                                                hL, dust, flags);
    enc_pl_k<<<B_ * (P_ / RP), 256, ENC_PL_SMEM, stream>>>(p_x, p_typ, p_score, p_rad,
                                                 px_w1, px_b1, px_w2, px_b2,
                                                 ps_w1, ps_b1, ps_w2, ps_b2,
                                                 p_ln_g, p_ln_b, pt_emb, proj_p,
                                                 sg_w1, sg_b1, sg_w2, sg_b2,
                                                 hL, p_mask, flags, layoutA,
                                                 d_out, ppart, pcnt, pg, pcntB);
    softmax_k<<<B_ * 8, 256, 0, stream>>>(dust, l_mask, p_mask, flags, d_out, sharpp, entp);
    pool_l_k<<<B_, 128, 0, stream>>>(hL, l_mask, flags, retr_l, d_out);
    pool_p_k<<<B_, 128, 0, stream>>>(ppart, pcnt, pg, pcntB, flags, layoutA, retr_p, d_out);
    finalize_k<<<1, 128, 0, stream>>>(l_mask, flags, sharpp, entp, d_out);
}

// Round 7
// 407.717 us; speedup vs baseline: 6.0963x; 2.0852x over previous
//
#include <hip/hip_runtime.h>
#include <hip/hip_bf16.h>
#include <math.h>

// PharmMatchNetFast — round 7: MFMA rewrite of enc_pl.
// All GEMM-shaped stages (MLP1 K=192, MLP2 K=256 concat [h1|hs]@[w2;sw2],
// proj K=128, sigma gw1 K=128, logits 128x16x128) on mfma_f32_16x16x32_bf16.
// Weights pre-transposed to WT[n][k] bf16 in ws (B-frag = one 16B load/lane).
// Epilogues (gelu/LN/pool/sig) stay scalar f32 on LDS between GEMMs.
// enc_l now writes bf16 hLb (logits A + pool_l); f32 hL dropped.
#define B_ 128
#define L_ 128
#define P_ 1024
#define D_ 128
#define NT_ 256

#define NEGF (-__FLT_MAX__)
#define SCALE_ 0.08838834764831845f
#define CLAMPV 1e30f

// output offsets (elements)
#define OUT_SHARP  16793600
#define OUT_NEGENT 16793728
#define OUT_LZ     16793856
#define OUT_PZ     16810240
#define OUT_SIG    16826624

// ws offsets (floats)
#define WS_HLB    0            // bf16 hL [B*L*D] = 1,048,576 floats
#define WS_DUST   1048576
#define WS_SHARPP 1064960
#define WS_ENTP   1065984
#define WS_PG     1067008
#define WS_PCNTB  1083392
#define WS_FLAG   1083520
#define WS_WT     1083536      // bf16: w1T[128*192]@0, w2cT[128*256]@24576,
                               //       projT[128*128]@57344, gw1T[128*128]@73728
#define WS_PPART  1128592
#define WS_PCNT   2177168
#define WS_END_A  2185360

using bh8  = __attribute__((ext_vector_type(8))) short;   // 8 bf16 (4 VGPR)
using fx4  = __attribute__((ext_vector_type(4))) float;   // MFMA C/D

__device__ __forceinline__ float gelu_(float x) {
    return 0.5f * x * (1.0f + erff(x * 0.7071067811865476f));
}
__device__ __forceinline__ float bf2f(unsigned short u) {
    return __uint_as_float(((unsigned)u) << 16);
}
__device__ __forceinline__ float sanz(float x) {
    return fminf(fmaxf(x, -CLAMPV), CLAMPV);   // NaN -> -CLAMPV
}
template<int BF> __device__ __forceinline__ float ldf(const void* p, int i) {
    if constexpr (BF) return bf2f(((const unsigned short*)p)[i]);
    else return ((const float*)p)[i];
}
template<int BF> __device__ __forceinline__ void stf(void* p, size_t i, float x) {
    x = sanz(x);
    if constexpr (BF) ((__hip_bfloat16*)p)[i] = __float2bfloat16(x);
    else ((float*)p)[i] = x;
}
__device__ __forceinline__ float maskf(const void* m, int mm, int idx) {
    if (mm == 3) return ((const float*)m)[idx] != 0.f ? 1.f : 0.f;
    if (mm == 2) return ((const unsigned short*)m)[idx] ? 1.f : 0.f;
    if (mm == 1) return ((const unsigned char*)m)[idx] ? 1.f : 0.f;
    return ((const int*)m)[idx] ? 1.f : 0.f;
}
__device__ __forceinline__ int typf(const void* p, int tm, int idx) {
    int v;
    if (tm == 2) v = (int)bf2f(((const unsigned short*)p)[idx]);
    else if (tm == 1) v = (int)((const long long*)p)[idx];
    else v = ((const int*)p)[idx];
    return v < 0 ? 0 : (v > NT_ - 1 ? NT_ - 1 : v);
}

// flags[0]=mask mode (0 i32/1 byte/2 bf16/3 f32); flags[1]=float (0 f32/1 bf16);
// flags[2]=typ (0 i32/1 i64/2 bf16)
__global__ __launch_bounds__(64) void detect_k(const unsigned int* __restrict__ px,
                                               const unsigned int* __restrict__ pm,
                                               const unsigned int* __restrict__ pt,
                                               int* __restrict__ flags)
{
    const int t = threadIdx.x;
    int hit = 0;
    for (int i = t; i < 4096; i += 64) {
        unsigned e = (px[i] >> 7) & 0xFFu;
        hit += (e >= 110 && e <= 132) ? 1 : 0;
    }
    for (int s = 1; s < 64; s <<= 1) hit += __shfl_xor(hit, s);

    unsigned big = 0, lo3f = 0, hi3f = 0;
    for (int i = t; i < 1024; i += 64) {
        unsigned w = pm[i];
        big  |= (w > 1u) ? 1u : 0u;
        lo3f |= ((w & 0xFFFFu) == 0x3F80u) ? 1u : 0u;
        hi3f |= ((w >> 16) == 0x3F80u) ? 1u : 0u;
    }
    unsigned long long aBig = __ballot(big != 0), aLo = __ballot(lo3f != 0), aHi = __ballot(hi3f != 0);

    unsigned tbig = 0, oddnz = 0;
    for (int i = t; i < 512; i += 64) {
        unsigned we = pt[2 * i], wo = pt[2 * i + 1];
        tbig  |= (we > 0xFFFFu || wo > 0xFFFFu) ? 1u : 0u;
        oddnz |= (wo != 0u) ? 1u : 0u;
    }
    unsigned long long aTb = __ballot(tbig != 0), aOdd = __ballot(oddnz != 0);

    if (t == 0) {
        flags[1] = (hit > 2048) ? 1 : 0;
        flags[0] = aLo ? 2 : (aHi ? 3 : (aBig ? 1 : 0));
        flags[2] = aTb ? 2 : (!aOdd ? 1 : 0);
    }
}

__global__ __launch_bounds__(256) void zero_k(float* __restrict__ pg, float* __restrict__ pcntB)
{
    const int t = blockIdx.x * 256 + threadIdx.x;
    if (t < B_ * D_) pg[t] = 0.f;
    if (t < B_) pcntB[t] = 0.f;
}

// ---------------- weight transpose prep ----------------
template<int BF> __device__ __forceinline__ void wt_prep_body(
    const void* w1, const void* w2, const void* sw2,
    const void* proj, const void* gw1, __hip_bfloat16* wt)
{
    const int idx = blockIdx.x * 256 + threadIdx.x;
    const int stride = gridDim.x * 256;
    // w1T [128][192]
    for (int i = idx; i < 128 * 192; i += stride) {
        int n = i / 192, k = i - n * 192;
        wt[n * 192 + k] = __float2bfloat16(ldf<BF>(w1, k * 128 + n));
    }
    // w2cT [128][256]: cols 0..127 = w2, 128..255 = sw2
    __hip_bfloat16* w2c = wt + 24576;
    for (int i = idx; i < 128 * 256; i += stride) {
        int n = i >> 8, k = i & 255;
        float v = (k < 128) ? ldf<BF>(w2, k * 128 + n) : ldf<BF>(sw2, (k - 128) * 128 + n);
        w2c[n * 256 + k] = __float2bfloat16(v);
    }
    // projT [128][128]
    __hip_bfloat16* pjt = wt + 57344;
    for (int i = idx; i < 128 * 128; i += stride) {
        int n = i >> 7, k = i & 127;
        pjt[n * 128 + k] = __float2bfloat16(ldf<BF>(proj, k * 128 + n));
    }
    // gw1T [128][128]
    __hip_bfloat16* g1t = wt + 73728;
    for (int i = idx; i < 128 * 128; i += stride) {
        int n = i >> 7, k = i & 127;
        g1t[n * 128 + k] = __float2bfloat16(ldf<BF>(gw1, k * 128 + n));
    }
}

__global__ __launch_bounds__(256) void wt_prep_k(
    const void* w1, const void* w2, const void* sw2,
    const void* proj, const void* gw1, __hip_bfloat16* wt, const int* flags)
{
    if (flags[1]) wt_prep_body<1>(w1, w2, sw2, proj, gw1, wt);
    else          wt_prep_body<0>(w1, w2, sw2, proj, gw1, wt);
}

// ---------------- encode L (writes bf16 hLb + f32 dust) ----------------
#define RL 8
template<int BF> __device__ __forceinline__ void enc_l_body(
    const void* l_x, const void* l_typ, int tm,
    const void* w1, const void* b1, const void* w2, const void* b2,
    const void* lng, const void* lnb, const void* emb, const void* proj,
    const void* dustv, __hip_bfloat16* hLb, float* dust)
{
    __shared__ __align__(16) float X[RL * 8];
    __shared__ __align__(16) float H[RL][D_];
    __shared__ __align__(16) float Y[RL][D_];
    __shared__ float mus[RL], rss[RL];
    const int o = threadIdx.x;
    const int base = blockIdx.x * RL;

    if (o < RL * 8) X[o] = ldf<BF>(l_x, base * 8 + o);
    __syncthreads();

    float acc[RL];
    const float b1o = ldf<BF>(b1, o);
#pragma unroll
    for (int r = 0; r < RL; r++) acc[r] = b1o;
#pragma unroll
    for (int i = 0; i < 8; i += 4) {
        float wa = ldf<BF>(w1, (i + 0) * D_ + o), wb = ldf<BF>(w1, (i + 1) * D_ + o);
        float wc = ldf<BF>(w1, (i + 2) * D_ + o), wd = ldf<BF>(w1, (i + 3) * D_ + o);
#pragma unroll
        for (int r = 0; r < RL; r++) {
            const float4 x4 = *(const float4*)&X[r * 8 + i];
            acc[r] = fmaf(x4.x, wa, fmaf(x4.y, wb, fmaf(x4.z, wc, fmaf(x4.w, wd, acc[r]))));
        }
    }
#pragma unroll
    for (int r = 0; r < RL; r++) H[r][o] = gelu_(acc[r]);
    __syncthreads();

#pragma unroll
    for (int r = 0; r < RL; r++) {
        int tt = typf(l_typ, tm, base + r);
        acc[r] = ldf<BF>(b2, o) + ldf<BF>(emb, tt * D_ + o);
    }
    for (int i = 0; i < D_; i += 4) {
        float wa = ldf<BF>(w2, (i + 0) * D_ + o), wb = ldf<BF>(w2, (i + 1) * D_ + o);
        float wc = ldf<BF>(w2, (i + 2) * D_ + o), wd = ldf<BF>(w2, (i + 3) * D_ + o);
#pragma unroll
        for (int r = 0; r < RL; r++) {
            const float4 h4 = *(const float4*)&H[r][i];
            acc[r] = fmaf(h4.x, wa, fmaf(h4.y, wb, fmaf(h4.z, wc, fmaf(h4.w, wd, acc[r]))));
        }
    }
#pragma unroll
    for (int r = 0; r < RL; r++) Y[r][o] = acc[r];
    __syncthreads();

    {
        const int r = o >> 4, j = o & 15;
        float s = 0.f;
#pragma unroll
        for (int i = 0; i < 8; i++) s += Y[r][j * 8 + i];
        s += __shfl_xor(s, 1); s += __shfl_xor(s, 2); s += __shfl_xor(s, 4); s += __shfl_xor(s, 8);
        const float mu = s * (1.f / 128.f);
        float v = 0.f;
#pragma unroll
        for (int i = 0; i < 8; i++) { float d = Y[r][j * 8 + i] - mu; v = fmaf(d, d, v); }
        v += __shfl_xor(v, 1); v += __shfl_xor(v, 2); v += __shfl_xor(v, 4); v += __shfl_xor(v, 8);
        if (j == 0) { mus[r] = mu; rss[r] = rsqrtf(v * (1.f / 128.f) + 1e-5f); }
    }
    __syncthreads();
    {
        const float g = ldf<BF>(lng, o), bl = ldf<BF>(lnb, o);
#pragma unroll
        for (int r = 0; r < RL; r++) Y[r][o] = fmaf((Y[r][o] - mus[r]) * rss[r], g, bl);
    }
    __syncthreads();

#pragma unroll
    for (int r = 0; r < RL; r++) acc[r] = 0.f;
    for (int i = 0; i < D_; i += 4) {
        float wa = ldf<BF>(proj, (i + 0) * D_ + o), wb = ldf<BF>(proj, (i + 1) * D_ + o);
        float wc = ldf<BF>(proj, (i + 2) * D_ + o), wd = ldf<BF>(proj, (i + 3) * D_ + o);
#pragma unroll
        for (int r = 0; r < RL; r++) {
            const float4 y4 = *(const float4*)&Y[r][i];
            acc[r] = fmaf(y4.x, wa, fmaf(y4.y, wb, fmaf(y4.z, wc, fmaf(y4.w, wd, acc[r]))));
        }
    }
    const float dvo = ldf<BF>(dustv, o);
#pragma unroll
    for (int r = 0; r < RL; r++) {
        hLb[(size_t)(base + r) * D_ + o] = __float2bfloat16(acc[r]);
        H[r][o] = acc[r] * dvo;
    }
    __syncthreads();
    {
        const int r = o >> 4, j = o & 15;
        float s = 0.f;
#pragma unroll
        for (int i = 0; i < 8; i++) s += H[r][j * 8 + i];
        s += __shfl_xor(s, 1); s += __shfl_xor(s, 2); s += __shfl_xor(s, 4); s += __shfl_xor(s, 8);
        if (j == 0) dust[base + r] = s * SCALE_;
    }
}

__global__ __launch_bounds__(128) void enc_l_k(
    const void* l_x, const void* l_typ,
    const void* w1, const void* b1, const void* w2, const void* b2,
    const void* lng, const void* lnb, const void* emb, const void* proj,
    const void* dustv, __hip_bfloat16* hLb, float* dust, const int* flags)
{
    const int tm = flags[2];
    if (flags[1]) enc_l_body<1>(l_x, l_typ, tm, w1, b1, w2, b2, lng, lnb, emb, proj, dustv, hLb, dust);
    else          enc_l_body<0>(l_x, l_typ, tm, w1, b1, w2, b2, lng, lnb, emb, proj, dustv, hLb, dust);
}

// ---------------- encode P (MFMA) + sigma + pool + logits ----------------
// 256 thr = 4 waves. X: bf16 [16][264] LDS A-tile; Bb/Cc: f32 [16][128].
// MFMA 16x16x32 bf16: A lane: row=l&15, k=(l>>4)*8+i (8 contig k).
//                     B lane: col=l&15, k=(l>>4)*8+i.
//                     D lane: col=l&15, row=(l>>4)*4+j (f32 reg j).
#define XS 264
#define ENC_PL_SMEM 25024
template<int BF> __device__ __forceinline__ void enc_pl_body(
    unsigned short* X, float* Bb, float* Cc, float* mus, float* rss, float* pm_s,
    const void* p_x, const void* p_typ, int tm,
    const void* p_score, const void* p_rad,
    const void* b1, const void* b2, const void* sb2,
    const void* sw1, const void* sb1,
    const void* lng, const void* lnb, const void* emb,
    const void* gb1, const void* gw2, const void* gb2,
    const unsigned short* wt, const unsigned short* hLb,
    const void* p_mask, int mm, int layoutA,
    void* out, float* ppart, float* pcnt, float* pg, float* pcntB)
{
    const int t = threadIdx.x;
    const int o = t & 127, rh = t >> 7;
    const int lane = t & 63, w = t >> 6;
    const int m = lane & 15, g = lane >> 4;
    const int b = blockIdx.x >> 6, tile = blockIdx.x & 63;
    const int p0 = tile * 16, base = b * P_ + p0;
    __hip_bfloat16* Xb = (__hip_bfloat16*)X;

    // stage p_x tile -> X[16][192] bf16
    for (int i = t; i < 16 * 192; i += 256) {
        int r = i / 192, k = i - r * 192;
        Xb[r * XS + k] = __float2bfloat16(ldf<BF>(p_x, (base + r) * 192 + k));
    }
    if (t < 16) pm_s[t] = maskf(p_mask, mm, base + t);
    __syncthreads();

    // GEMM1: D = X[16x192] @ w1 -> Bb raw
    {
        const unsigned short* w1T = wt;   // [128][192]
        fx4 a0 = {0.f, 0.f, 0.f, 0.f}, a1 = {0.f, 0.f, 0.f, 0.f};
        const unsigned short* xr = X + m * XS + g * 8;
        const unsigned short* q0 = w1T + ((w * 2 + 0) * 16 + m) * 192 + g * 8;
        const unsigned short* q1 = w1T + ((w * 2 + 1) * 16 + m) * 192 + g * 8;
#pragma unroll
        for (int ks = 0; ks < 6; ks++) {
            bh8 a  = *(const bh8*)(xr + ks * 32);
            bh8 f0 = *(const bh8*)(q0 + ks * 32);
            bh8 f1 = *(const bh8*)(q1 + ks * 32);
            a0 = __builtin_amdgcn_mfma_f32_16x16x32_bf16(a, f0, a0, 0, 0, 0);
            a1 = __builtin_amdgcn_mfma_f32_16x16x32_bf16(a, f1, a1, 0, 0, 0);
        }
#pragma unroll
        for (int j = 0; j < 4; j++) {
            Bb[(g * 4 + j) * 128 + (w * 2 + 0) * 16 + m] = a0[j];
            Bb[(g * 4 + j) * 128 + (w * 2 + 1) * 16 + m] = a1[j];
        }
    }
    __syncthreads();

    // ep1: h1 = gelu(D+b1) -> X[:,0:128]; hs = gelu(score*sw1+sb1) -> X[:,128:256]
    {
        const float b1o = ldf<BF>(b1, o);
        const float a1v = ldf<BF>(sw1, o), a0v = ldf<BF>(sb1, o);
#pragma unroll
        for (int r = 0; r < 8; r++) {
            const int row = rh * 8 + r;
            Xb[row * XS + o] = __float2bfloat16(gelu_(Bb[row * 128 + o] + b1o));
            float hs = gelu_(fmaf(ldf<BF>(p_score, base + row), a1v, a0v));
            Xb[row * XS + 128 + o] = __float2bfloat16(hs);
        }
    }
    __syncthreads();

    // GEMM2: D = [h1|hs][16x256] @ w2c -> Bb raw
    {
        const unsigned short* w2cT = wt + 24576;   // [128][256]
        fx4 a0 = {0.f, 0.f, 0.f, 0.f}, a1 = {0.f, 0.f, 0.f, 0.f};
        const unsigned short* xr = X + m * XS + g * 8;
        const unsigned short* q0 = w2cT + ((w * 2 + 0) * 16 + m) * 256 + g * 8;
        const unsigned short* q1 = w2cT + ((w * 2 + 1) * 16 + m) * 256 + g * 8;
#pragma unroll
        for (int ks = 0; ks < 8; ks++) {
            bh8 a  = *(const bh8*)(xr + ks * 32);
            bh8 f0 = *(const bh8*)(q0 + ks * 32);
            bh8 f1 = *(const bh8*)(q1 + ks * 32);
            a0 = __builtin_amdgcn_mfma_f32_16x16x32_bf16(a, f0, a0, 0, 0, 0);
            a1 = __builtin_amdgcn_mfma_f32_16x16x32_bf16(a, f1, a1, 0, 0, 0);
        }
#pragma unroll
        for (int j = 0; j < 4; j++) {
            Bb[(g * 4 + j) * 128 + (w * 2 + 0) * 16 + m] = a0[j];
            Bb[(g * 4 + j) * 128 + (w * 2 + 1) * 16 + m] = a1[j];
        }
    }
    __syncthreads();

    // ep2: h2 = D + b2 + sb2 + emb[typ]  (f32, in place)
    {
        const float bo = ldf<BF>(b2, o) + ldf<BF>(sb2, o);
#pragma unroll
        for (int r = 0; r < 8; r++) {
            const int row = rh * 8 + r;
            int tt = typf(p_typ, tm, base + row);
            Bb[row * 128 + o] += bo + ldf<BF>(emb, tt * D_ + o);
        }
    }
    __syncthreads();

    // LN stats (16 rows x 16 thr, two-pass)
    {
        const int r = t >> 4, j = t & 15;
        float s = 0.f;
#pragma unroll
        for (int i = 0; i < 8; i++) s += Bb[r * 128 + j * 8 + i];
        s += __shfl_xor(s, 1); s += __shfl_xor(s, 2); s += __shfl_xor(s, 4); s += __shfl_xor(s, 8);
        const float mu = s * (1.f / 128.f);
        float v = 0.f;
#pragma unroll
        for (int i = 0; i < 8; i++) { float d = Bb[r * 128 + j * 8 + i] - mu; v = fmaf(d, d, v); }
        v += __shfl_xor(v, 1); v += __shfl_xor(v, 2); v += __shfl_xor(v, 4); v += __shfl_xor(v, 8);
        if (j == 0) { mus[r] = mu; rss[r] = rsqrtf(v * (1.f / 128.f) + 1e-5f); }
    }
    __syncthreads();
    // LN apply -> X bf16 [:,0:128]
    {
        const float gg = ldf<BF>(lng, o), bl = ldf<BF>(lnb, o);
#pragma unroll
        for (int r = 0; r < 8; r++) {
            const int row = rh * 8 + r;
            float y = fmaf((Bb[row * 128 + o] - mus[row]) * rss[row], gg, bl);
            Xb[row * XS + o] = __float2bfloat16(y);
        }
    }
    __syncthreads();

    // GEMM3: hp = y[16x128] @ proj -> Bb raw
    {
        const unsigned short* pjT = wt + 57344;   // [128][128]
        fx4 a0 = {0.f, 0.f, 0.f, 0.f}, a1 = {0.f, 0.f, 0.f, 0.f};
        const unsigned short* xr = X + m * XS + g * 8;
        const unsigned short* q0 = pjT + ((w * 2 + 0) * 16 + m) * 128 + g * 8;
        const unsigned short* q1 = pjT + ((w * 2 + 1) * 16 + m) * 128 + g * 8;
#pragma unroll
        for (int ks = 0; ks < 4; ks++) {
            bh8 a  = *(const bh8*)(xr + ks * 32);
            bh8 f0 = *(const bh8*)(q0 + ks * 32);
            bh8 f1 = *(const bh8*)(q1 + ks * 32);
            a0 = __builtin_amdgcn_mfma_f32_16x16x32_bf16(a, f0, a0, 0, 0, 0);
            a1 = __builtin_amdgcn_mfma_f32_16x16x32_bf16(a, f1, a1, 0, 0, 0);
        }
#pragma unroll
        for (int j = 0; j < 4; j++) {
            Bb[(g * 4 + j) * 128 + (w * 2 + 0) * 16 + m] = a0[j];
            Bb[(g * 4 + j) * 128 + (w * 2 + 1) * 16 + m] = a1[j];
        }
    }
    __syncthreads();

    // ep3: hp -> X bf16; pool-P partials from Bb f32
    {
#pragma unroll
        for (int r = 0; r < 8; r++) {
            const int row = rh * 8 + r;
            Xb[row * XS + o] = __float2bfloat16(Bb[row * 128 + o]);
        }
        if (rh == 0) {
            float s = 0.f;
#pragma unroll
            for (int r = 0; r < 16; r++) s = fmaf(Bb[r * 128 + o], pm_s[r], s);
            if (layoutA) {
                ppart[(size_t)blockIdx.x * D_ + o] = s;
                if (t == 0) {
                    float c = 0.f;
#pragma unroll
                    for (int r = 0; r < 16; r++) c += pm_s[r];
                    pcnt[blockIdx.x] = c;
                }
            } else {
                atomicAdd(&pg[b * D_ + o], s);
                if (t == 0) {
                    float c = 0.f;
#pragma unroll
                    for (int r = 0; r < 16; r++) c += pm_s[r];
                    atomicAdd(&pcntB[b], c);
                }
            }
        }
    }
    __syncthreads();

    // GEMM4: g1raw = hp[16x128] @ gw1 -> Cc
    {
        const unsigned short* g1T = wt + 73728;   // [128][128]
        fx4 a0 = {0.f, 0.f, 0.f, 0.f}, a1 = {0.f, 0.f, 0.f, 0.f};
        const unsigned short* xr = X + m * XS + g * 8;
        const unsigned short* q0 = g1T + ((w * 2 + 0) * 16 + m) * 128 + g * 8;
        const unsigned short* q1 = g1T + ((w * 2 + 1) * 16 + m) * 128 + g * 8;
#pragma unroll
        for (int ks = 0; ks < 4; ks++) {
            bh8 a  = *(const bh8*)(xr + ks * 32);
            bh8 f0 = *(const bh8*)(q0 + ks * 32);
            bh8 f1 = *(const bh8*)(q1 + ks * 32);
            a0 = __builtin_amdgcn_mfma_f32_16x16x32_bf16(a, f0, a0, 0, 0, 0);
            a1 = __builtin_amdgcn_mfma_f32_16x16x32_bf16(a, f1, a1, 0, 0, 0);
        }
#pragma unroll
        for (int j = 0; j < 4; j++) {
            Cc[(g * 4 + j) * 128 + (w * 2 + 0) * 16 + m] = a0[j];
            Cc[(g * 4 + j) * 128 + (w * 2 + 1) * 16 + m] = a1[j];
        }
    }
    __syncthreads();

    // ep4: g1 = gelu(Cc + gb1)
    {
        const float gb = ldf<BF>(gb1, o);
#pragma unroll
        for (int r = 0; r < 8; r++) {
            const int row = rh * 8 + r;
            Cc[row * 128 + o] = gelu_(Cc[row * 128 + o] + gb);
        }
    }
    __syncthreads();

    // sigma reduce (16 rows x 16 thr, 8 ch each)
    {
        const int r = t >> 4, j = t & 15;
        float s = 0.f;
#pragma unroll
        for (int i = 0; i < 8; i++) s = fmaf(Cc[r * 128 + j * 8 + i], ldf<BF>(gw2, j * 8 + i), s);
        s += __shfl_xor(s, 1); s += __shfl_xor(s, 2); s += __shfl_xor(s, 4); s += __shfl_xor(s, 8);
        if (j == 0) {
            float v = s + ldf<BF>(gb2, 0);
            float sp = fmaxf(v, 0.f) + log1pf(expf(-fabsf(v)));
            stf<BF>(out, (size_t)OUT_SIG + base + r, sp + 1e-3f + fmaxf(ldf<BF>(p_rad, base + r), 0.f));
        }
    }

    // logits: D[16l x 16p] per M-tile; A = hLb rows (global), B = hp (X LDS)
    {
        const unsigned short* hb = hLb + (size_t)b * L_ * D_;
        const unsigned short* br = X + m * XS + g * 8;
        fx4 a0 = {0.f, 0.f, 0.f, 0.f}, a1 = {0.f, 0.f, 0.f, 0.f};
        const unsigned short* ha0 = hb + ((w * 2 + 0) * 16 + m) * 128 + g * 8;
        const unsigned short* ha1 = hb + ((w * 2 + 1) * 16 + m) * 128 + g * 8;
#pragma unroll
        for (int ks = 0; ks < 4; ks++) {
            bh8 bf = *(const bh8*)(br + ks * 32);
            bh8 f0 = *(const bh8*)(ha0 + ks * 32);
            bh8 f1 = *(const bh8*)(ha1 + ks * 32);
            a0 = __builtin_amdgcn_mfma_f32_16x16x32_bf16(f0, bf, a0, 0, 0, 0);
            a1 = __builtin_amdgcn_mfma_f32_16x16x32_bf16(f1, bf, a1, 0, 0, 0);
        }
#pragma unroll
        for (int j = 0; j < 4; j++) {
            stf<BF>(out, (size_t)(b * L_ + (w * 2 + 0) * 16 + g * 4 + j) * (P_ + 1) + p0 + m, a0[j]);
            stf<BF>(out, (size_t)(b * L_ + (w * 2 + 1) * 16 + g * 4 + j) * (P_ + 1) + p0 + m, a1[j]);
        }
    }
}

__global__ __launch_bounds__(256) void enc_pl_k(
    const void* p_x, const void* p_typ, const void* p_score, const void* p_rad,
    const void* b1, const void* b2, const void* sb2,
    const void* sw1, const void* sb1,
    const void* lng, const void* lnb, const void* emb,
    const void* gb1, const void* gw2, const void* gb2,
    const unsigned short* wt, const unsigned short* hLb,
    const void* p_mask, const int* flags, int layoutA,
    void* out, float* ppart, float* pcnt, float* pg, float* pcntB)
{
    extern __shared__ __align__(16) char smem[];
    unsigned short* X = (unsigned short*)smem;              // 16*264*2 = 8448 B
    float* Bb   = (float*)(smem + 8448);                    // 8192 B
    float* Cc   = (float*)(smem + 8448 + 8192);             // 8192 B
    float* mus  = (float*)(smem + 8448 + 16384);            // 64 B
    float* rss  = mus + 16;
    float* pm_s = rss + 16;
    const int tm = flags[2], mm = flags[0];
    if (flags[1]) enc_pl_body<1>(X, Bb, Cc, mus, rss, pm_s,
                                 p_x, p_typ, tm, p_score, p_rad, b1, b2, sb2, sw1, sb1,
                                 lng, lnb, emb, gb1, gw2, gb2, wt, hLb, p_mask, mm, layoutA,
                                 out, ppart, pcnt, pg, pcntB);
    else          enc_pl_body<0>(X, Bb, Cc, mus, rss, pm_s,
                                 p_x, p_typ, tm, p_score, p_rad, b1, b2, sb2, sw1, sb1,
                                 lng, lnb, emb, gb1, gw2, gb2, wt, hLb, p_mask, mm, layoutA,
                                 out, ppart, pcnt, pg, pcntB);
}

// ---------------- softmax over logW rows (in place) + sharp/ent partials ----------------
template<int BF> __device__ __forceinline__ void softmax_body(
    const float* dust, const void* l_mask, const void* p_mask, int mm,
    void* out, float* sharp_parts, float* ent_parts)
{
    __shared__ float dv_s[16], lm_s[16];
    __shared__ float redA[64], redB[64], redC[64], redD[64];
    const int t = threadIdx.x;
    const int b = blockIdx.x >> 3;
    const int l0 = (blockIdx.x & 7) * 16;

    if (t < 16) {
        dv_s[t] = dust[b * L_ + l0 + t];
        lm_s[t] = maskf(l_mask, mm, b * L_ + l0 + t);
    }
    __syncthreads();

    float pmv[4];
#pragma unroll
    for (int j = 0; j < 4; j++) pmv[j] = maskf(p_mask, mm, b * P_ + t + 256 * j);

    const int lane = t & 63, wid = t >> 6;
    float acc[16][4], mrow[16], lse[16];

#pragma unroll
    for (int r = 0; r < 16; r++) {
        const size_t row = ((size_t)(b * L_ + l0 + r)) * (P_ + 1);
        const bool lmr = lm_s[r] != 0.f;
        float m = NEGF;
#pragma unroll
        for (int j = 0; j < 4; j++) {
            float raw = ldf<BF>(out, (int)(row + t + 256 * j));
            float v = (lmr && pmv[j] != 0.f) ? raw * SCALE_ : NEGF;
            acc[r][j] = v;
            m = fmaxf(m, v);
        }
        m = fmaxf(m, __shfl_xor(m, 1));  m = fmaxf(m, __shfl_xor(m, 2));
        m = fmaxf(m, __shfl_xor(m, 4));  m = fmaxf(m, __shfl_xor(m, 8));
        m = fmaxf(m, __shfl_xor(m, 16)); m = fmaxf(m, __shfl_xor(m, 32));
        if (lane == 0) redA[r * 4 + wid] = m;
    }
    __syncthreads();
#pragma unroll
    for (int r = 0; r < 16; r++) {
        float m = fmaxf(fmaxf(redA[r * 4 + 0], redA[r * 4 + 1]), fmaxf(redA[r * 4 + 2], redA[r * 4 + 3]));
        float dvr = (lm_s[r] != 0.f) ? dv_s[r] : NEGF;
        mrow[r] = fmaxf(m, dvr);
    }
#pragma unroll
    for (int r = 0; r < 16; r++) {
        float s = expf(acc[r][0] - mrow[r]) + expf(acc[r][1] - mrow[r])
                + expf(acc[r][2] - mrow[r]) + expf(acc[r][3] - mrow[r]);
        s += __shfl_xor(s, 1);  s += __shfl_xor(s, 2);  s += __shfl_xor(s, 4);
        s += __shfl_xor(s, 8);  s += __shfl_xor(s, 16); s += __shfl_xor(s, 32);
        if (lane == 0) redB[r * 4 + wid] = s;
    }
    __syncthreads();
#pragma unroll
    for (int r = 0; r < 16; r++) {
        float dvr = (lm_s[r] != 0.f) ? dv_s[r] : NEGF;
        float s = (redB[r * 4 + 0] + redB[r * 4 + 1]) + (redB[r * 4 + 2] + redB[r * 4 + 3]);
        s += expf(dvr - mrow[r]);
        lse[r] = logf(s);
    }
#pragma unroll
    for (int r = 0; r < 16; r++) {
        const size_t row = ((size_t)(b * L_ + l0 + r)) * (P_ + 1);
        float mw = 0.f, es = 0.f;
#pragma unroll
        for (int j = 0; j < 4; j++) {
            float lw = acc[r][j] - mrow[r] - lse[r];
            stf<BF>(out, row + t + 256 * j, lw);
            float lwc = fmaxf(lw, -CLAMPV);
            float wm = expf(lwc) * pmv[j];
            mw = fmaxf(mw, wm);
            if (wm > 0.f) es = fmaf(-wm, lwc, es);
        }
        mw = fmaxf(mw, __shfl_xor(mw, 1));  mw = fmaxf(mw, __shfl_xor(mw, 2));
        mw = fmaxf(mw, __shfl_xor(mw, 4));  mw = fmaxf(mw, __shfl_xor(mw, 8));
        mw = fmaxf(mw, __shfl_xor(mw, 16)); mw = fmaxf(mw, __shfl_xor(mw, 32));
        es += __shfl_xor(es, 1);  es += __shfl_xor(es, 2);  es += __shfl_xor(es, 4);
        es += __shfl_xor(es, 8);  es += __shfl_xor(es, 16); es += __shfl_xor(es, 32);
        if (lane == 0) { redC[r * 4 + wid] = mw; redD[r * 4 + wid] = es; }
    }
    __syncthreads();
    if (t < 16) {
        float dvr = (lm_s[t] != 0.f) ? dv_s[t] : NEGF;
        stf<BF>(out, ((size_t)(b * L_ + l0 + t)) * (P_ + 1) + P_, dvr - mrow[t] - lse[t]);
    }
    if (t == 0) {
        float sp = 0.f, en = 0.f;
        for (int r = 0; r < 16; r++) {
            float dvr = (lm_s[r] != 0.f) ? dv_s[r] : NEGF;
            float lwd = fmaxf(dvr - mrow[r] - lse[r], -CLAMPV);
            float wd = expf(lwd);
            float mw = fmaxf(fmaxf(redC[r * 4 + 0], redC[r * 4 + 1]), fmaxf(redC[r * 4 + 2], redC[r * 4 + 3]));
            mw = fmaxf(mw, wd);
            float es = (redD[r * 4 + 0] + redD[r * 4 + 1]) + (redD[r * 4 + 2] + redD[r * 4 + 3]);
            if (wd > 0.f) es = fmaf(-wd, lwd, es);
            sp = fmaf(mw, lm_s[r], sp);
            en = fmaf(es, lm_s[r], en);
        }
        sharp_parts[blockIdx.x] = sp;
        ent_parts[blockIdx.x] = en;
    }
}

__global__ __launch_bounds__(256) void softmax_k(
    const float* dust, const void* l_mask, const void* p_mask, const int* flags,
    void* out, float* sharp_parts, float* ent_parts)
{
    const int mm = flags[0];
    if (flags[1]) softmax_body<1>(dust, l_mask, p_mask, mm, out, sharp_parts, ent_parts);
    else          softmax_body<0>(dust, l_mask, p_mask, mm, out, sharp_parts, ent_parts);
}

// ---------------- pooled L -> retr -> l2norm (reads bf16 hLb) ----------------
template<int BF> __device__ __forceinline__ void pool_l_body(
    const unsigned short* hLb, const void* l_mask, int mm, const void* retr, void* out)
{
    __shared__ float lmv[L_];
    __shared__ __align__(16) float lg[D_];
    __shared__ float red[2];
    const int o = threadIdx.x, b = blockIdx.x;
    lmv[o] = maskf(l_mask, mm, b * L_ + o);
    __syncthreads();
    float cnt = 0.f;
    for (int l = 0; l < L_; l++) cnt += lmv[l];
    float s0 = 0, s1 = 0, s2 = 0, s3 = 0;
    const unsigned short* hb = hLb + (size_t)b * L_ * D_;
    for (int l = 0; l < L_; l += 4) {
        s0 = fmaf(bf2f(hb[(l + 0) * D_ + o]), lmv[l + 0], s0);
        s1 = fmaf(bf2f(hb[(l + 1) * D_ + o]), lmv[l + 1], s1);
        s2 = fmaf(bf2f(hb[(l + 2) * D_ + o]), lmv[l + 2], s2);
        s3 = fmaf(bf2f(hb[(l + 3) * D_ + o]), lmv[l + 3], s3);
    }
    lg[o] = ((s0 + s1) + (s2 + s3)) / fmaxf(cnt, 1.f);
    __syncthreads();
    float r = 0.f;
    for (int i = 0; i < D_; i += 4) {
        const float4 g4 = *(const float4*)&lg[i];
        r = fmaf(g4.x, ldf<BF>(retr, (i + 0) * D_ + o), r);
        r = fmaf(g4.y, ldf<BF>(retr, (i + 1) * D_ + o), r);
        r = fmaf(g4.z, ldf<BF>(retr, (i + 2) * D_ + o), r);
        r = fmaf(g4.w, ldf<BF>(retr, (i + 3) * D_ + o), r);
    }
    float n = r * r;
    n += __shfl_xor(n, 1); n += __shfl_xor(n, 2); n += __shfl_xor(n, 4);
    n += __shfl_xor(n, 8); n += __shfl_xor(n, 16); n += __shfl_xor(n, 32);
    if ((o & 63) == 0) red[o >> 6] = n;
    __syncthreads();
    float nrm = fmaxf(sqrtf(red[0] + red[1]), 1e-12f);
    stf<BF>(out, (size_t)OUT_LZ + b * D_ + o, r / nrm);
}

__global__ __launch_bounds__(128) void pool_l_k(
    const unsigned short* hLb, const void* l_mask, const int* flags, const void* retr, void* out)
{
    const int mm = flags[0];
    if (flags[1]) pool_l_body<1>(hLb, l_mask, mm, retr, out);
    else          pool_l_body<0>(hLb, l_mask, mm, retr, out);
}

// ---------------- pooled P -> retr -> l2norm ----------------
template<int BF> __device__ __forceinline__ void pool_p_body(
    const float* ppart, const float* pcnt, const float* pg, const float* pcntB,
    int layoutA, const void* retr, void* out)
{
    __shared__ __align__(16) float pgs[D_];
    __shared__ float red[2];
    const int o = threadIdx.x, b = blockIdx.x;
    float s = 0.f, c = 0.f;
    if (layoutA) {
        for (int k = 0; k < 64; k++) s += ppart[(size_t)(b * 64 + k) * D_ + o];
        for (int k = 0; k < 64; k++) c += pcnt[b * 64 + k];
    } else {
        s = pg[b * D_ + o];
        c = pcntB[b];
    }
    pgs[o] = s / fmaxf(c, 1.f);
    __syncthreads();
    float r = 0.f;
    for (int i = 0; i < D_; i += 4) {
        const float4 g4 = *(const float4*)&pgs[i];
        r = fmaf(g4.x, ldf<BF>(retr, (i + 0) * D_ + o), r);
        r = fmaf(g4.y, ldf<BF>(retr, (i + 1) * D_ + o), r);
        r = fmaf(g4.z, ldf<BF>(retr, (i + 2) * D_ + o), r);
        r = fmaf(g4.w, ldf<BF>(retr, (i + 3) * D_ + o), r);
    }
    float n = r * r;
    n += __shfl_xor(n, 1); n += __shfl_xor(n, 2); n += __shfl_xor(n, 4);
    n += __shfl_xor(n, 8); n += __shfl_xor(n, 16); n += __shfl_xor(n, 32);
    if ((o & 63) == 0) red[o >> 6] = n;
    __syncthreads();
    float nrm = fmaxf(sqrtf(red[0] + red[1]), 1e-12f);
    stf<BF>(out, (size_t)OUT_PZ + b * D_ + o, r / nrm);
}

__global__ __launch_bounds__(128) void pool_p_k(
    const float* ppart, const float* pcnt, const float* pg, const float* pcntB,
    const int* flags, int layoutA, const void* retr, void* out)
{
    if (flags[1]) pool_p_body<1>(ppart, pcnt, pg, pcntB, layoutA, retr, out);
    else          pool_p_body<0>(ppart, pcnt, pg, pcntB, layoutA, retr, out);
}

// ---------------- finalize sharp / neg_ent ----------------
template<int BF> __device__ __forceinline__ void finalize_body(
    const void* l_mask, int mm, const float* sharp_parts, const float* ent_parts, void* out)
{
    const int b = threadIdx.x;
    float cnt = 0.f;
    for (int l = 0; l < L_; l++) cnt += maskf(l_mask, mm, b * L_ + l);
    const float den = fmaxf(cnt, 1.f);
    float sp = 0.f, en = 0.f;
    for (int k = 0; k < 8; k++) { sp += sharp_parts[b * 8 + k]; en += ent_parts[b * 8 + k]; }
    stf<BF>(out, (size_t)OUT_SHARP + b, sp / den);
    stf<BF>(out, (size_t)OUT_NEGENT + b, -(en / den));
}

__global__ __launch_bounds__(128) void finalize_k(
    const void* l_mask, const int* flags,
    const float* sharp_parts, const float* ent_parts, void* out)
{
    const int mm = flags[0];
    if (flags[1]) finalize_body<1>(l_mask, mm, sharp_parts, ent_parts, out);
    else          finalize_body<0>(l_mask, mm, sharp_parts, ent_parts, out);
}

extern "C" void kernel_launch(void* const* d_in, const int* in_sizes, int n_in,
                              void* d_out, int out_size, void* d_ws, size_t ws_size,
                              hipStream_t stream)
{
    const void* l_x     = d_in[0];
    const void* l_typ   = d_in[1];
    const void* p_x     = d_in[2];
    const void* p_typ   = d_in[3];
    const void* p_score = d_in[4];
    const void* p_rad   = d_in[5];
    const void* l_mask  = d_in[6];
    const void* p_mask  = d_in[7];
    const void* lt_emb  = d_in[8];
    const void* lx_w1   = d_in[9];
    const void* lx_b1   = d_in[10];
    const void* lx_w2   = d_in[11];
    const void* lx_b2   = d_in[12];
    const void* l_ln_g  = d_in[13];
    const void* l_ln_b  = d_in[14];
    const void* pt_emb  = d_in[15];
    const void* px_w1   = d_in[16];
    const void* px_b1   = d_in[17];
    const void* px_w2   = d_in[18];
    const void* px_b2   = d_in[19];
    const void* ps_w1   = d_in[20];
    const void* ps_b1   = d_in[21];
    const void* ps_w2   = d_in[22];
    const void* ps_b2   = d_in[23];
    const void* p_ln_g  = d_in[24];
    const void* p_ln_b  = d_in[25];
    const void* proj_l  = d_in[26];
    const void* proj_p  = d_in[27];
    const void* dustv   = d_in[28];
    const void* sg_w1   = d_in[29];
    const void* sg_b1   = d_in[30];
    const void* sg_w2   = d_in[31];
    const void* sg_b2   = d_in[32];
    const void* retr_l  = d_in[33];
    const void* retr_p  = d_in[34];

    float* ws     = (float*)d_ws;
    __hip_bfloat16* hLb = (__hip_bfloat16*)(ws + WS_HLB);
    float* dust   = ws + WS_DUST;
    float* sharpp = ws + WS_SHARPP;
    float* entp   = ws + WS_ENTP;
    float* pg     = ws + WS_PG;
    float* pcntB  = ws + WS_PCNTB;
    int*   flags  = (int*)(ws + WS_FLAG);
    __hip_bfloat16* wt = (__hip_bfloat16*)(ws + WS_WT);
    float* ppart  = ws + WS_PPART;
    float* pcnt   = ws + WS_PCNT;

    const int layoutA = (ws_size >= (size_t)WS_END_A * 4) ? 1 : 0;

    detect_k<<<1, 64, 0, stream>>>((const unsigned int*)p_x, (const unsigned int*)p_mask,
                                   (const unsigned int*)p_typ, flags);
    zero_k<<<(B_ * D_ + 255) / 256, 256, 0, stream>>>(pg, pcntB);
    wt_prep_k<<<64, 256, 0, stream>>>(px_w1, px_w2, ps_w2, proj_p, sg_w1, wt, flags);
    enc_l_k<<<(B_ * L_) / RL, 128, 0, stream>>>(l_x, l_typ, lx_w1, lx_b1, lx_w2, lx_b2,
                                                l_ln_g, l_ln_b, lt_emb, proj_l, dustv,
                                                hLb, dust, flags);
    enc_pl_k<<<B_ * (P_ / 16), 256, ENC_PL_SMEM, stream>>>(
        p_x, p_typ, p_score, p_rad,
        px_b1, px_b2, ps_b2, ps_w1, ps_b1,
        p_ln_g, p_ln_b, pt_emb,
        sg_b1, sg_w2, sg_b2,
        (const unsigned short*)wt, (const unsigned short*)hLb,
        p_mask, flags, layoutA,
        d_out, ppart, pcnt, pg, pcntB);
    softmax_k<<<B_ * 8, 256, 0, stream>>>(dust, l_mask, p_mask, flags, d_out, sharpp, entp);
    pool_l_k<<<B_, 128, 0, stream>>>((const unsigned short*)hLb, l_mask, flags, retr_l, d_out);
    pool_p_k<<<B_, 128, 0, stream>>>(ppart, pcnt, pg, pcntB, flags, layoutA, retr_p, d_out);
    finalize_k<<<1, 128, 0, stream>>>(l_mask, flags, sharpp, entp, d_out);
}

// Round 8
// 341.458 us; speedup vs baseline: 7.2792x; 1.1940x over previous
//
#include <hip/hip_runtime.h>
#include <hip/hip_bf16.h>
#include <math.h>

// PharmMatchNetFast — round 8:
// (a) enc_p: 32 rows/block with M-loop (B-frags register-resident, reused
//     across 2 M-tiles), writes hPb bf16 to ws instead of computing logits.
// (b) logits_sm_k: MFMA logits (hLb x hPb) fused with in-register softmax —
//     eliminates softmax_k and the raw-logit write+read roundtrip.
// ws ~40MB (R1-R4 ran a 76MB layout without faults -> ws_size >= 76MB).
#define B_ 128
#define L_ 128
#define P_ 1024
#define D_ 128
#define NT_ 256

#define NEGF (-__FLT_MAX__)
#define SCALE_ 0.08838834764831845f
#define CLAMPV 1e30f

// output offsets (elements)
#define OUT_SHARP  16793600
#define OUT_NEGENT 16793728
#define OUT_LZ     16793856
#define OUT_PZ     16810240
#define OUT_SIG    16826624

// ws offsets (floats)
#define WS_HLB    0            // bf16 hL [128*128*128]
#define WS_HPB    1048576      // bf16 hP [128*1024*128]
#define WS_DUST   9437184
#define WS_SHARPP 9453568
#define WS_ENTP   9454592
#define WS_FLAG   9455616
#define WS_WT     9455632      // bf16: w1T@0, w2cT@24576, projT@57344, gw1T@73728 (shorts)
#define WS_PPART  9500696      // 4096 blocks x 128
#define WS_PCNT   10024984
#define WS_END    10029080

using bh8  = __attribute__((ext_vector_type(8))) short;   // 8 bf16 (4 VGPR)
using fx4  = __attribute__((ext_vector_type(4))) float;   // MFMA C/D

__device__ __forceinline__ float gelu_(float x) {
    return 0.5f * x * (1.0f + erff(x * 0.7071067811865476f));
}
__device__ __forceinline__ float bf2f(unsigned short u) {
    return __uint_as_float(((unsigned)u) << 16);
}
__device__ __forceinline__ float sanz(float x) {
    return fminf(fmaxf(x, -CLAMPV), CLAMPV);   // NaN -> -CLAMPV
}
template<int BF> __device__ __forceinline__ float ldf(const void* p, int i) {
    if constexpr (BF) return bf2f(((const unsigned short*)p)[i]);
    else return ((const float*)p)[i];
}
template<int BF> __device__ __forceinline__ void stf(void* p, size_t i, float x) {
    x = sanz(x);
    if constexpr (BF) ((__hip_bfloat16*)p)[i] = __float2bfloat16(x);
    else ((float*)p)[i] = x;
}
__device__ __forceinline__ float maskf(const void* m, int mm, int idx) {
    if (mm == 3) return ((const float*)m)[idx] != 0.f ? 1.f : 0.f;
    if (mm == 2) return ((const unsigned short*)m)[idx] ? 1.f : 0.f;
    if (mm == 1) return ((const unsigned char*)m)[idx] ? 1.f : 0.f;
    return ((const int*)m)[idx] ? 1.f : 0.f;
}
__device__ __forceinline__ int typf(const void* p, int tm, int idx) {
    int v;
    if (tm == 2) v = (int)bf2f(((const unsigned short*)p)[idx]);
    else if (tm == 1) v = (int)((const long long*)p)[idx];
    else v = ((const int*)p)[idx];
    return v < 0 ? 0 : (v > NT_ - 1 ? NT_ - 1 : v);
}

// flags[0]=mask mode (0 i32/1 byte/2 bf16/3 f32); flags[1]=float (0 f32/1 bf16);
// flags[2]=typ (0 i32/1 i64/2 bf16)
__global__ __launch_bounds__(64) void detect_k(const unsigned int* __restrict__ px,
                                               const unsigned int* __restrict__ pm,
                                               const unsigned int* __restrict__ pt,
                                               int* __restrict__ flags)
{
    const int t = threadIdx.x;
    int hit = 0;
    for (int i = t; i < 4096; i += 64) {
        unsigned e = (px[i] >> 7) & 0xFFu;
        hit += (e >= 110 && e <= 132) ? 1 : 0;
    }
    for (int s = 1; s < 64; s <<= 1) hit += __shfl_xor(hit, s);

    unsigned big = 0, lo3f = 0, hi3f = 0;
    for (int i = t; i < 1024; i += 64) {
        unsigned wv = pm[i];
        big  |= (wv > 1u) ? 1u : 0u;
        lo3f |= ((wv & 0xFFFFu) == 0x3F80u) ? 1u : 0u;
        hi3f |= ((wv >> 16) == 0x3F80u) ? 1u : 0u;
    }
    unsigned long long aBig = __ballot(big != 0), aLo = __ballot(lo3f != 0), aHi = __ballot(hi3f != 0);

    unsigned tbig = 0, oddnz = 0;
    for (int i = t; i < 512; i += 64) {
        unsigned we = pt[2 * i], wo = pt[2 * i + 1];
        tbig  |= (we > 0xFFFFu || wo > 0xFFFFu) ? 1u : 0u;
        oddnz |= (wo != 0u) ? 1u : 0u;
    }
    unsigned long long aTb = __ballot(tbig != 0), aOdd = __ballot(oddnz != 0);

    if (t == 0) {
        flags[1] = (hit > 2048) ? 1 : 0;
        flags[0] = aLo ? 2 : (aHi ? 3 : (aBig ? 1 : 0));
        flags[2] = aTb ? 2 : (!aOdd ? 1 : 0);
    }
}

// ---------------- weight transpose prep ----------------
template<int BF> __device__ __forceinline__ void wt_prep_body(
    const void* w1, const void* w2, const void* sw2,
    const void* proj, const void* gw1, __hip_bfloat16* wt)
{
    const int idx = blockIdx.x * 256 + threadIdx.x;
    const int stride = gridDim.x * 256;
    for (int i = idx; i < 128 * 192; i += stride) {
        int n = i / 192, k = i - n * 192;
        wt[n * 192 + k] = __float2bfloat16(ldf<BF>(w1, k * 128 + n));
    }
    __hip_bfloat16* w2c = wt + 24576;
    for (int i = idx; i < 128 * 256; i += stride) {
        int n = i >> 8, k = i & 255;
        float v = (k < 128) ? ldf<BF>(w2, k * 128 + n) : ldf<BF>(sw2, (k - 128) * 128 + n);
        w2c[n * 256 + k] = __float2bfloat16(v);
    }
    __hip_bfloat16* pjt = wt + 57344;
    for (int i = idx; i < 128 * 128; i += stride) {
        int n = i >> 7, k = i & 127;
        pjt[n * 128 + k] = __float2bfloat16(ldf<BF>(proj, k * 128 + n));
    }
    __hip_bfloat16* g1t = wt + 73728;
    for (int i = idx; i < 128 * 128; i += stride) {
        int n = i >> 7, k = i & 127;
        g1t[n * 128 + k] = __float2bfloat16(ldf<BF>(gw1, k * 128 + n));
    }
}

__global__ __launch_bounds__(256) void wt_prep_k(
    const void* w1, const void* w2, const void* sw2,
    const void* proj, const void* gw1, __hip_bfloat16* wt, const int* flags)
{
    if (flags[1]) wt_prep_body<1>(w1, w2, sw2, proj, gw1, wt);
    else          wt_prep_body<0>(w1, w2, sw2, proj, gw1, wt);
}

// ---------------- encode L (writes bf16 hLb + f32 dust) ----------------
#define RL 8
template<int BF> __device__ __forceinline__ void enc_l_body(
    const void* l_x, const void* l_typ, int tm,
    const void* w1, const void* b1, const void* w2, const void* b2,
    const void* lng, const void* lnb, const void* emb, const void* proj,
    const void* dustv, __hip_bfloat16* hLb, float* dust)
{
    __shared__ __align__(16) float X[RL * 8];
    __shared__ __align__(16) float H[RL][D_];
    __shared__ __align__(16) float Y[RL][D_];
    __shared__ float mus[RL], rss[RL];
    const int o = threadIdx.x;
    const int base = blockIdx.x * RL;

    if (o < RL * 8) X[o] = ldf<BF>(l_x, base * 8 + o);
    __syncthreads();

    float acc[RL];
    const float b1o = ldf<BF>(b1, o);
#pragma unroll
    for (int r = 0; r < RL; r++) acc[r] = b1o;
#pragma unroll
    for (int i = 0; i < 8; i += 4) {
        float wa = ldf<BF>(w1, (i + 0) * D_ + o), wb = ldf<BF>(w1, (i + 1) * D_ + o);
        float wc = ldf<BF>(w1, (i + 2) * D_ + o), wd = ldf<BF>(w1, (i + 3) * D_ + o);
#pragma unroll
        for (int r = 0; r < RL; r++) {
            const float4 x4 = *(const float4*)&X[r * 8 + i];
            acc[r] = fmaf(x4.x, wa, fmaf(x4.y, wb, fmaf(x4.z, wc, fmaf(x4.w, wd, acc[r]))));
        }
    }
#pragma unroll
    for (int r = 0; r < RL; r++) H[r][o] = gelu_(acc[r]);
    __syncthreads();

#pragma unroll
    for (int r = 0; r < RL; r++) {
        int tt = typf(l_typ, tm, base + r);
        acc[r] = ldf<BF>(b2, o) + ldf<BF>(emb, tt * D_ + o);
    }
    for (int i = 0; i < D_; i += 4) {
        float wa = ldf<BF>(w2, (i + 0) * D_ + o), wb = ldf<BF>(w2, (i + 1) * D_ + o);
        float wc = ldf<BF>(w2, (i + 2) * D_ + o), wd = ldf<BF>(w2, (i + 3) * D_ + o);
#pragma unroll
        for (int r = 0; r < RL; r++) {
            const float4 h4 = *(const float4*)&H[r][i];
            acc[r] = fmaf(h4.x, wa, fmaf(h4.y, wb, fmaf(h4.z, wc, fmaf(h4.w, wd, acc[r]))));
        }
    }
#pragma unroll
    for (int r = 0; r < RL; r++) Y[r][o] = acc[r];
    __syncthreads();

    {
        const int r = o >> 4, j = o & 15;
        float s = 0.f;
#pragma unroll
        for (int i = 0; i < 8; i++) s += Y[r][j * 8 + i];
        s += __shfl_xor(s, 1); s += __shfl_xor(s, 2); s += __shfl_xor(s, 4); s += __shfl_xor(s, 8);
        const float mu = s * (1.f / 128.f);
        float v = 0.f;
#pragma unroll
        for (int i = 0; i < 8; i++) { float d = Y[r][j * 8 + i] - mu; v = fmaf(d, d, v); }
        v += __shfl_xor(v, 1); v += __shfl_xor(v, 2); v += __shfl_xor(v, 4); v += __shfl_xor(v, 8);
        if (j == 0) { mus[r] = mu; rss[r] = rsqrtf(v * (1.f / 128.f) + 1e-5f); }
    }
    __syncthreads();
    {
        const float g = ldf<BF>(lng, o), bl = ldf<BF>(lnb, o);
#pragma unroll
        for (int r = 0; r < RL; r++) Y[r][o] = fmaf((Y[r][o] - mus[r]) * rss[r], g, bl);
    }
    __syncthreads();

#pragma unroll
    for (int r = 0; r < RL; r++) acc[r] = 0.f;
    for (int i = 0; i < D_; i += 4) {
        float wa = ldf<BF>(proj, (i + 0) * D_ + o), wb = ldf<BF>(proj, (i + 1) * D_ + o);
        float wc = ldf<BF>(proj, (i + 2) * D_ + o), wd = ldf<BF>(proj, (i + 3) * D_ + o);
#pragma unroll
        for (int r = 0; r < RL; r++) {
            const float4 y4 = *(const float4*)&Y[r][i];
            acc[r] = fmaf(y4.x, wa, fmaf(y4.y, wb, fmaf(y4.z, wc, fmaf(y4.w, wd, acc[r]))));
        }
    }
    const float dvo = ldf<BF>(dustv, o);
#pragma unroll
    for (int r = 0; r < RL; r++) {
        hLb[(size_t)(base + r) * D_ + o] = __float2bfloat16(acc[r]);
        H[r][o] = acc[r] * dvo;
    }
    __syncthreads();
    {
        const int r = o >> 4, j = o & 15;
        float s = 0.f;
#pragma unroll
        for (int i = 0; i < 8; i++) s += H[r][j * 8 + i];
        s += __shfl_xor(s, 1); s += __shfl_xor(s, 2); s += __shfl_xor(s, 4); s += __shfl_xor(s, 8);
        if (j == 0) dust[base + r] = s * SCALE_;
    }
}

__global__ __launch_bounds__(128) void enc_l_k(
    const void* l_x, const void* l_typ,
    const void* w1, const void* b1, const void* w2, const void* b2,
    const void* lng, const void* lnb, const void* emb, const void* proj,
    const void* dustv, __hip_bfloat16* hLb, float* dust, const int* flags)
{
    const int tm = flags[2];
    if (flags[1]) enc_l_body<1>(l_x, l_typ, tm, w1, b1, w2, b2, lng, lnb, emb, proj, dustv, hLb, dust);
    else          enc_l_body<0>(l_x, l_typ, tm, w1, b1, w2, b2, lng, lnb, emb, proj, dustv, hLb, dust);
}

// ---------------- encode P (MFMA, 32 rows/block, M-loop) ----------------
// 256 thr = 4 waves; wave w owns N-cols w*32..w*32+31 (2 n-tiles); M-loop mt=0,1.
// X: bf16 [32][264]; Bb: f32 [32][128]. Writes hPb bf16, ppart/pcnt, sig.
#define XS 264
#define ROWS 32
#define ENC_P_SMEM 33664
template<int BF> __device__ __forceinline__ void enc_p_body(
    unsigned short* X, float* Bb, float* mus, float* rss, float* pm_s,
    const void* p_x, const void* p_typ, int tm,
    const void* p_score, const void* p_rad,
    const void* b1, const void* b2, const void* sb2,
    const void* sw1, const void* sb1,
    const void* lng, const void* lnb, const void* emb,
    const void* gb1, const void* gw2, const void* gb2,
    const unsigned short* wt, const void* p_mask, int mm,
    void* out, __hip_bfloat16* hPb, float* ppart, float* pcnt)
{
    const int t = threadIdx.x;
    const int o = t & 127, rh = t >> 7;
    const int lane = t & 63, w = t >> 6;
    const int m = lane & 15, g = lane >> 4;
    const int b = blockIdx.x >> 5, tile = blockIdx.x & 31;
    const int base = b * P_ + tile * ROWS;
    const int r0 = rh * 16;
    __hip_bfloat16* Xb = (__hip_bfloat16*)X;

    // stage p_x tile -> X[32][192] bf16
    for (int i = t; i < ROWS * 192; i += 256) {
        int r = i / 192, k = i - r * 192;
        Xb[r * XS + k] = __float2bfloat16(ldf<BF>(p_x, (base + r) * 192 + k));
    }
    if (t < ROWS) pm_s[t] = maskf(p_mask, mm, base + t);
    __syncthreads();

    // GEMM1: X[32x192] @ w1 -> Bb
    {
        const unsigned short* w1T = wt;
        bh8 bf[12];
#pragma unroll
        for (int ks = 0; ks < 6; ks++) {
            bf[ks * 2 + 0] = *(const bh8*)(w1T + ((w * 2 + 0) * 16 + m) * 192 + g * 8 + ks * 32);
            bf[ks * 2 + 1] = *(const bh8*)(w1T + ((w * 2 + 1) * 16 + m) * 192 + g * 8 + ks * 32);
        }
#pragma unroll
        for (int mt = 0; mt < 2; mt++) {
            fx4 a0 = {0.f, 0.f, 0.f, 0.f}, a1 = {0.f, 0.f, 0.f, 0.f};
            const unsigned short* xr = X + (mt * 16 + m) * XS + g * 8;
#pragma unroll
            for (int ks = 0; ks < 6; ks++) {
                bh8 a = *(const bh8*)(xr + ks * 32);
                a0 = __builtin_amdgcn_mfma_f32_16x16x32_bf16(a, bf[ks * 2 + 0], a0, 0, 0, 0);
                a1 = __builtin_amdgcn_mfma_f32_16x16x32_bf16(a, bf[ks * 2 + 1], a1, 0, 0, 0);
            }
#pragma unroll
            for (int j = 0; j < 4; j++) {
                Bb[(mt * 16 + g * 4 + j) * 128 + (w * 2 + 0) * 16 + m] = a0[j];
                Bb[(mt * 16 + g * 4 + j) * 128 + (w * 2 + 1) * 16 + m] = a1[j];
            }
        }
    }
    __syncthreads();

    // ep1: h1 = gelu(D+b1) -> X[:,0:128]; hs -> X[:,128:256]
    {
        const float b1o = ldf<BF>(b1, o);
        const float a1v = ldf<BF>(sw1, o), a0v = ldf<BF>(sb1, o);
#pragma unroll
        for (int r = 0; r < 16; r++) {
            const int row = r0 + r;
            Xb[row * XS + o] = __float2bfloat16(gelu_(Bb[row * 128 + o] + b1o));
            float hs = gelu_(fmaf(ldf<BF>(p_score, base + row), a1v, a0v));
            Xb[row * XS + 128 + o] = __float2bfloat16(hs);
        }
    }
    __syncthreads();

    // GEMM2: [h1|hs][32x256] @ w2c -> Bb
    {
        const unsigned short* w2cT = wt + 24576;
        bh8 bf[16];
#pragma unroll
        for (int ks = 0; ks < 8; ks++) {
            bf[ks * 2 + 0] = *(const bh8*)(w2cT + ((w * 2 + 0) * 16 + m) * 256 + g * 8 + ks * 32);
            bf[ks * 2 + 1] = *(const bh8*)(w2cT + ((w * 2 + 1) * 16 + m) * 256 + g * 8 + ks * 32);
        }
#pragma unroll
        for (int mt = 0; mt < 2; mt++) {
            fx4 a0 = {0.f, 0.f, 0.f, 0.f}, a1 = {0.f, 0.f, 0.f, 0.f};
            const unsigned short* xr = X + (mt * 16 + m) * XS + g * 8;
#pragma unroll
            for (int ks = 0; ks < 8; ks++) {
                bh8 a = *(const bh8*)(xr + ks * 32);
                a0 = __builtin_amdgcn_mfma_f32_16x16x32_bf16(a, bf[ks * 2 + 0], a0, 0, 0, 0);
                a1 = __builtin_amdgcn_mfma_f32_16x16x32_bf16(a, bf[ks * 2 + 1], a1, 0, 0, 0);
            }
#pragma unroll
            for (int j = 0; j < 4; j++) {
                Bb[(mt * 16 + g * 4 + j) * 128 + (w * 2 + 0) * 16 + m] = a0[j];
                Bb[(mt * 16 + g * 4 + j) * 128 + (w * 2 + 1) * 16 + m] = a1[j];
            }
        }
    }
    __syncthreads();

    // ep2: h2 = D + b2 + sb2 + emb[typ]
    {
        const float bo = ldf<BF>(b2, o) + ldf<BF>(sb2, o);
#pragma unroll
        for (int r = 0; r < 16; r++) {
            const int row = r0 + r;
            int tt = typf(p_typ, tm, base + row);
            Bb[row * 128 + o] += bo + ldf<BF>(emb, tt * D_ + o);
        }
    }
    __syncthreads();

    // LN stats: 32 rows, 16 thr/row, 2 iters, two-pass
#pragma unroll
    for (int it = 0; it < 2; it++) {
        const int r = it * 16 + (t >> 4), j = t & 15;
        float s = 0.f;
#pragma unroll
        for (int i = 0; i < 8; i++) s += Bb[r * 128 + j * 8 + i];
        s += __shfl_xor(s, 1); s += __shfl_xor(s, 2); s += __shfl_xor(s, 4); s += __shfl_xor(s, 8);
        const float mu = s * (1.f / 128.f);
        float v = 0.f;
#pragma unroll
        for (int i = 0; i < 8; i++) { float d = Bb[r * 128 + j * 8 + i] - mu; v = fmaf(d, d, v); }
        v += __shfl_xor(v, 1); v += __shfl_xor(v, 2); v += __shfl_xor(v, 4); v += __shfl_xor(v, 8);
        if (j == 0) { mus[r] = mu; rss[r] = rsqrtf(v * (1.f / 128.f) + 1e-5f); }
    }
    __syncthreads();
    // LN apply -> X bf16 [:,0:128]
    {
        const float gg = ldf<BF>(lng, o), bl = ldf<BF>(lnb, o);
#pragma unroll
        for (int r = 0; r < 16; r++) {
            const int row = r0 + r;
            float y = fmaf((Bb[row * 128 + o] - mus[row]) * rss[row], gg, bl);
            Xb[row * XS + o] = __float2bfloat16(y);
        }
    }
    __syncthreads();

    // GEMM3: hp = y[32x128] @ proj -> Bb
    {
        const unsigned short* pjT = wt + 57344;
        bh8 bf[8];
#pragma unroll
        for (int ks = 0; ks < 4; ks++) {
            bf[ks * 2 + 0] = *(const bh8*)(pjT + ((w * 2 + 0) * 16 + m) * 128 + g * 8 + ks * 32);
            bf[ks * 2 + 1] = *(const bh8*)(pjT + ((w * 2 + 1) * 16 + m) * 128 + g * 8 + ks * 32);
        }
#pragma unroll
        for (int mt = 0; mt < 2; mt++) {
            fx4 a0 = {0.f, 0.f, 0.f, 0.f}, a1 = {0.f, 0.f, 0.f, 0.f};
            const unsigned short* xr = X + (mt * 16 + m) * XS + g * 8;
#pragma unroll
            for (int ks = 0; ks < 4; ks++) {
                bh8 a = *(const bh8*)(xr + ks * 32);
                a0 = __builtin_amdgcn_mfma_f32_16x16x32_bf16(a, bf[ks * 2 + 0], a0, 0, 0, 0);
                a1 = __builtin_amdgcn_mfma_f32_16x16x32_bf16(a, bf[ks * 2 + 1], a1, 0, 0, 0);
            }
#pragma unroll
            for (int j = 0; j < 4; j++) {
                Bb[(mt * 16 + g * 4 + j) * 128 + (w * 2 + 0) * 16 + m] = a0[j];
                Bb[(mt * 16 + g * 4 + j) * 128 + (w * 2 + 1) * 16 + m] = a1[j];
            }
        }
    }
    __syncthreads();

    // ep3: hPb store (coalesced) + X <- hp bf16 + pool partials
    {
#pragma unroll
        for (int r = 0; r < 16; r++) {
            const int row = r0 + r;
            float v = Bb[row * 128 + o];
            hPb[(size_t)(base + row) * D_ + o] = __float2bfloat16(v);
            Xb[row * XS + o] = __float2bfloat16(v);
        }
        if (rh == 0) {
            float s = 0.f;
#pragma unroll
            for (int r = 0; r < ROWS; r++) s = fmaf(Bb[r * 128 + o], pm_s[r], s);
            ppart[(size_t)blockIdx.x * D_ + o] = s;
            if (t == 0) {
                float c = 0.f;
#pragma unroll
                for (int r = 0; r < ROWS; r++) c += pm_s[r];
                pcnt[blockIdx.x] = c;
            }
        }
    }
    __syncthreads();

    // GEMM4: g1raw = hp[32x128] @ gw1 -> Bb (pool reads done)
    {
        const unsigned short* g1T = wt + 73728;
        bh8 bf[8];
#pragma unroll
        for (int ks = 0; ks < 4; ks++) {
            bf[ks * 2 + 0] = *(const bh8*)(g1T + ((w * 2 + 0) * 16 + m) * 128 + g * 8 + ks * 32);
            bf[ks * 2 + 1] = *(const bh8*)(g1T + ((w * 2 + 1) * 16 + m) * 128 + g * 8 + ks * 32);
        }
#pragma unroll
        for (int mt = 0; mt < 2; mt++) {
            fx4 a0 = {0.f, 0.f, 0.f, 0.f}, a1 = {0.f, 0.f, 0.f, 0.f};
            const unsigned short* xr = X + (mt * 16 + m) * XS + g * 8;
#pragma unroll
            for (int ks = 0; ks < 4; ks++) {
                bh8 a = *(const bh8*)(xr + ks * 32);
                a0 = __builtin_amdgcn_mfma_f32_16x16x32_bf16(a, bf[ks * 2 + 0], a0, 0, 0, 0);
                a1 = __builtin_amdgcn_mfma_f32_16x16x32_bf16(a, bf[ks * 2 + 1], a1, 0, 0, 0);
            }
#pragma unroll
            for (int j = 0; j < 4; j++) {
                Bb[(mt * 16 + g * 4 + j) * 128 + (w * 2 + 0) * 16 + m] = a0[j];
                Bb[(mt * 16 + g * 4 + j) * 128 + (w * 2 + 1) * 16 + m] = a1[j];
            }
        }
    }
    __syncthreads();

    // ep4: g1 = gelu(Bb + gb1)
    {
        const float gb = ldf<BF>(gb1, o);
#pragma unroll
        for (int r = 0; r < 16; r++) {
            const int row = r0 + r;
            Bb[row * 128 + o] = gelu_(Bb[row * 128 + o] + gb);
        }
    }
    __syncthreads();

    // sigma reduce: 32 rows, 16 thr/row, 2 iters
#pragma unroll
    for (int it = 0; it < 2; it++) {
        const int r = it * 16 + (t >> 4), j = t & 15;
        float s = 0.f;
#pragma unroll
        for (int i = 0; i < 8; i++) s = fmaf(Bb[r * 128 + j * 8 + i], ldf<BF>(gw2, j * 8 + i), s);
        s += __shfl_xor(s, 1); s += __shfl_xor(s, 2); s += __shfl_xor(s, 4); s += __shfl_xor(s, 8);
        if (j == 0) {
            float v = s + ldf<BF>(gb2, 0);
            float sp = fmaxf(v, 0.f) + log1pf(expf(-fabsf(v)));
            stf<BF>(out, (size_t)OUT_SIG + base + r, sp + 1e-3f + fmaxf(ldf<BF>(p_rad, base + r), 0.f));
        }
    }
}

__global__ __launch_bounds__(256) void enc_p_k(
    const void* p_x, const void* p_typ, const void* p_score, const void* p_rad,
    const void* b1, const void* b2, const void* sb2,
    const void* sw1, const void* sb1,
    const void* lng, const void* lnb, const void* emb,
    const void* gb1, const void* gw2, const void* gb2,
    const unsigned short* wt, const void* p_mask, const int* flags,
    void* out, __hip_bfloat16* hPb, float* ppart, float* pcnt)
{
    extern __shared__ __align__(16) char smem[];
    unsigned short* X = (unsigned short*)smem;              // 32*264*2 = 16896 B
    float* Bb   = (float*)(smem + 16896);                   // 32*128*4 = 16384 B
    float* mus  = (float*)(smem + 16896 + 16384);           // 32
    float* rss  = mus + 32;                                 // 32
    float* pm_s = rss + 32;                                 // 32
    const int tm = flags[2], mm = flags[0];
    if (flags[1]) enc_p_body<1>(X, Bb, mus, rss, pm_s,
                                p_x, p_typ, tm, p_score, p_rad, b1, b2, sb2, sw1, sb1,
                                lng, lnb, emb, gb1, gw2, gb2, wt, p_mask, mm,
                                out, hPb, ppart, pcnt);
    else          enc_p_body<0>(X, Bb, mus, rss, pm_s,
                                p_x, p_typ, tm, p_score, p_rad, b1, b2, sb2, sw1, sb1,
                                lng, lnb, emb, gb1, gw2, gb2, wt, p_mask, mm,
                                out, hPb, ppart, pcnt);
}

// ---------------- logits (MFMA) + fused softmax + sharp/ent ----------------
// grid B*8: (b, l0=16-row tile). 4 waves: wave w owns p-cols w*256..w*256+255
// (16 n-tiles). acc[nt][j]: row l0+g*4+j, col w*256+nt*16+m.
template<int BF> __device__ __forceinline__ void logits_sm_body(
    const unsigned short* hLb, const unsigned short* hPb, const float* dust,
    const void* l_mask, const void* p_mask, int mm,
    void* out, float* sharp_parts, float* ent_parts)
{
    __shared__ float pm_s[1024];
    __shared__ float lm_s[16], dv_s[16];
    __shared__ float redA[64], redB[64], redC[64], redD[64], redM[16], redL[16];
    const int t = threadIdx.x;
    const int lane = t & 63, w = t >> 6;
    const int m = lane & 15, g = lane >> 4;
    const int b = blockIdx.x >> 3, l0 = (blockIdx.x & 7) * 16;

    for (int i = t; i < 1024; i += 256) pm_s[i] = maskf(p_mask, mm, b * P_ + i);
    if (t < 16) {
        lm_s[t] = maskf(l_mask, mm, b * L_ + l0 + t);
        dv_s[t] = dust[b * L_ + l0 + t];
    }
    __syncthreads();

    // A-frags: hL rows l0..l0+15 (reused across 16 n-tiles)
    bh8 af[4];
    {
        const unsigned short* ha = hLb + ((size_t)(b * L_ + l0 + m)) * D_ + g * 8;
#pragma unroll
        for (int ks = 0; ks < 4; ks++) af[ks] = *(const bh8*)(ha + ks * 32);
    }
    const unsigned short* hpb = hPb + ((size_t)(b * P_ + w * 256)) * D_;

    fx4 acc[16];
#pragma unroll
    for (int nt = 0; nt < 16; nt++) {
        fx4 c = {0.f, 0.f, 0.f, 0.f};
        const unsigned short* hr = hpb + (nt * 16 + m) * D_ + g * 8;
#pragma unroll
        for (int ks = 0; ks < 4; ks++) {
            bh8 bfr = *(const bh8*)(hr + ks * 32);
            c = __builtin_amdgcn_mfma_f32_16x16x32_bf16(af[ks], bfr, c, 0, 0, 0);
        }
        acc[nt] = c;
    }

    // mask + scale + row max
    float rmax[4] = {NEGF, NEGF, NEGF, NEGF};
#pragma unroll
    for (int nt = 0; nt < 16; nt++) {
        const float pv = pm_s[w * 256 + nt * 16 + m];
#pragma unroll
        for (int j = 0; j < 4; j++) {
            const bool ok = (lm_s[g * 4 + j] != 0.f) && (pv != 0.f);
            float v = ok ? acc[nt][j] * SCALE_ : NEGF;
            acc[nt][j] = v;
            rmax[j] = fmaxf(rmax[j], v);
        }
    }
#pragma unroll
    for (int j = 0; j < 4; j++) {
        rmax[j] = fmaxf(rmax[j], __shfl_xor(rmax[j], 1));
        rmax[j] = fmaxf(rmax[j], __shfl_xor(rmax[j], 2));
        rmax[j] = fmaxf(rmax[j], __shfl_xor(rmax[j], 4));
        rmax[j] = fmaxf(rmax[j], __shfl_xor(rmax[j], 8));
    }
    if (m == 0) {
#pragma unroll
        for (int j = 0; j < 4; j++) redA[(g * 4 + j) * 4 + w] = rmax[j];
    }
    __syncthreads();
    float mrow[4], lse[4];
#pragma unroll
    for (int j = 0; j < 4; j++) {
        const int r = g * 4 + j;
        float mm4 = fmaxf(fmaxf(redA[r * 4 + 0], redA[r * 4 + 1]), fmaxf(redA[r * 4 + 2], redA[r * 4 + 3]));
        float dvr = (lm_s[r] != 0.f) ? dv_s[r] : NEGF;
        mrow[j] = fmaxf(mm4, dvr);
    }
    // sum of exp
    float se[4] = {0.f, 0.f, 0.f, 0.f};
#pragma unroll
    for (int nt = 0; nt < 16; nt++) {
#pragma unroll
        for (int j = 0; j < 4; j++) se[j] += expf(acc[nt][j] - mrow[j]);
    }
#pragma unroll
    for (int j = 0; j < 4; j++) {
        se[j] += __shfl_xor(se[j], 1); se[j] += __shfl_xor(se[j], 2);
        se[j] += __shfl_xor(se[j], 4); se[j] += __shfl_xor(se[j], 8);
    }
    if (m == 0) {
#pragma unroll
        for (int j = 0; j < 4; j++) redB[(g * 4 + j) * 4 + w] = se[j];
    }
    __syncthreads();
#pragma unroll
    for (int j = 0; j < 4; j++) {
        const int r = g * 4 + j;
        float dvr = (lm_s[r] != 0.f) ? dv_s[r] : NEGF;
        float s = (redB[r * 4 + 0] + redB[r * 4 + 1]) + (redB[r * 4 + 2] + redB[r * 4 + 3]);
        s += expf(dvr - mrow[j]);
        lse[j] = logf(s);
    }
    if (w == 0 && m == 0) {
#pragma unroll
        for (int j = 0; j < 4; j++) { redM[g * 4 + j] = mrow[j]; redL[g * 4 + j] = lse[j]; }
    }
    // write logW + W stats
    float mw[4] = {0.f, 0.f, 0.f, 0.f}, es[4] = {0.f, 0.f, 0.f, 0.f};
#pragma unroll
    for (int nt = 0; nt < 16; nt++) {
        const float pv = pm_s[w * 256 + nt * 16 + m];
#pragma unroll
        for (int j = 0; j < 4; j++) {
            float lw = acc[nt][j] - mrow[j] - lse[j];
            stf<BF>(out, (size_t)(b * L_ + l0 + g * 4 + j) * (P_ + 1) + w * 256 + nt * 16 + m, lw);
            float lwc = fmaxf(lw, -CLAMPV);
            float wm = expf(lwc) * pv;
            mw[j] = fmaxf(mw[j], wm);
            if (wm > 0.f) es[j] = fmaf(-wm, lwc, es[j]);
        }
    }
#pragma unroll
    for (int j = 0; j < 4; j++) {
        mw[j] = fmaxf(mw[j], __shfl_xor(mw[j], 1));
        mw[j] = fmaxf(mw[j], __shfl_xor(mw[j], 2));
        mw[j] = fmaxf(mw[j], __shfl_xor(mw[j], 4));
        mw[j] = fmaxf(mw[j], __shfl_xor(mw[j], 8));
        es[j] += __shfl_xor(es[j], 1); es[j] += __shfl_xor(es[j], 2);
        es[j] += __shfl_xor(es[j], 4); es[j] += __shfl_xor(es[j], 8);
    }
    if (m == 0) {
#pragma unroll
        for (int j = 0; j < 4; j++) {
            redC[(g * 4 + j) * 4 + w] = mw[j];
            redD[(g * 4 + j) * 4 + w] = es[j];
        }
    }
    __syncthreads();
    if (t < 16) {   // dustbin column
        float dvr = (lm_s[t] != 0.f) ? dv_s[t] : NEGF;
        stf<BF>(out, (size_t)(b * L_ + l0 + t) * (P_ + 1) + P_, dvr - redM[t] - redL[t]);
    }
    if (t == 0) {
        float sp = 0.f, en = 0.f;
        for (int r = 0; r < 16; r++) {
            float dvr = (lm_s[r] != 0.f) ? dv_s[r] : NEGF;
            float lwd = fmaxf(dvr - redM[r] - redL[r], -CLAMPV);
            float wd = expf(lwd);
            float mwr = fmaxf(fmaxf(redC[r * 4 + 0], redC[r * 4 + 1]), fmaxf(redC[r * 4 + 2], redC[r * 4 + 3]));
            mwr = fmaxf(mwr, wd);
            float esr = (redD[r * 4 + 0] + redD[r * 4 + 1]) + (redD[r * 4 + 2] + redD[r * 4 + 3]);
            if (wd > 0.f) esr = fmaf(-wd, lwd, esr);
            sp = fmaf(mwr, lm_s[r], sp);
            en = fmaf(esr, lm_s[r], en);
        }
        sharp_parts[blockIdx.x] = sp;
        ent_parts[blockIdx.x] = en;
    }
}

__global__ __launch_bounds__(256) void logits_sm_k(
    const unsigned short* hLb, const unsigned short* hPb, const float* dust,
    const void* l_mask, const void* p_mask, const int* flags,
    void* out, float* sharp_parts, float* ent_parts)
{
    const int mm = flags[0];
    if (flags[1]) logits_sm_body<1>(hLb, hPb, dust, l_mask, p_mask, mm, out, sharp_parts, ent_parts);
    else          logits_sm_body<0>(hLb, hPb, dust, l_mask, p_mask, mm, out, sharp_parts, ent_parts);
}

// ---------------- pooled L -> retr -> l2norm (reads bf16 hLb) ----------------
template<int BF> __device__ __forceinline__ void pool_l_body(
    const unsigned short* hLb, const void* l_mask, int mm, const void* retr, void* out)
{
    __shared__ float lmv[L_];
    __shared__ __align__(16) float lg[D_];
    __shared__ float red[2];
    const int o = threadIdx.x, b = blockIdx.x;
    lmv[o] = maskf(l_mask, mm, b * L_ + o);
    __syncthreads();
    float cnt = 0.f;
    for (int l = 0; l < L_; l++) cnt += lmv[l];
    float s0 = 0, s1 = 0, s2 = 0, s3 = 0;
    const unsigned short* hb = hLb + (size_t)b * L_ * D_;
    for (int l = 0; l < L_; l += 4) {
        s0 = fmaf(bf2f(hb[(l + 0) * D_ + o]), lmv[l + 0], s0);
        s1 = fmaf(bf2f(hb[(l + 1) * D_ + o]), lmv[l + 1], s1);
        s2 = fmaf(bf2f(hb[(l + 2) * D_ + o]), lmv[l + 2], s2);
        s3 = fmaf(bf2f(hb[(l + 3) * D_ + o]), lmv[l + 3], s3);
    }
    lg[o] = ((s0 + s1) + (s2 + s3)) / fmaxf(cnt, 1.f);
    __syncthreads();
    float r = 0.f;
    for (int i = 0; i < D_; i += 4) {
        const float4 g4 = *(const float4*)&lg[i];
        r = fmaf(g4.x, ldf<BF>(retr, (i + 0) * D_ + o), r);
        r = fmaf(g4.y, ldf<BF>(retr, (i + 1) * D_ + o), r);
        r = fmaf(g4.z, ldf<BF>(retr, (i + 2) * D_ + o), r);
        r = fmaf(g4.w, ldf<BF>(retr, (i + 3) * D_ + o), r);
    }
    float n = r * r;
    n += __shfl_xor(n, 1); n += __shfl_xor(n, 2); n += __shfl_xor(n, 4);
    n += __shfl_xor(n, 8); n += __shfl_xor(n, 16); n += __shfl_xor(n, 32);
    if ((o & 63) == 0) red[o >> 6] = n;
    __syncthreads();
    float nrm = fmaxf(sqrtf(red[0] + red[1]), 1e-12f);
    stf<BF>(out, (size_t)OUT_LZ + b * D_ + o, r / nrm);
}

__global__ __launch_bounds__(128) void pool_l_k(
    const unsigned short* hLb, const void* l_mask, const int* flags, const void* retr, void* out)
{
    const int mm = flags[0];
    if (flags[1]) pool_l_body<1>(hLb, l_mask, mm, retr, out);
    else          pool_l_body<0>(hLb, l_mask, mm, retr, out);
}

// ---------------- pooled P -> retr -> l2norm ----------------
template<int BF> __device__ __forceinline__ void pool_p_body(
    const float* ppart, const float* pcnt, const void* retr, void* out)
{
    __shared__ __align__(16) float pgs[D_];
    __shared__ float red[2];
    const int o = threadIdx.x, b = blockIdx.x;
    float s = 0.f, c = 0.f;
    for (int k = 0; k < 32; k++) s += ppart[(size_t)(b * 32 + k) * D_ + o];
    for (int k = 0; k < 32; k++) c += pcnt[b * 32 + k];
    pgs[o] = s / fmaxf(c, 1.f);
    __syncthreads();
    float r = 0.f;
    for (int i = 0; i < D_; i += 4) {
        const float4 g4 = *(const float4*)&pgs[i];
        r = fmaf(g4.x, ldf<BF>(retr, (i + 0) * D_ + o), r);
        r = fmaf(g4.y, ldf<BF>(retr, (i + 1) * D_ + o), r);
        r = fmaf(g4.z, ldf<BF>(retr, (i + 2) * D_ + o), r);
        r = fmaf(g4.w, ldf<BF>(retr, (i + 3) * D_ + o), r);
    }
    float n = r * r;
    n += __shfl_xor(n, 1); n += __shfl_xor(n, 2); n += __shfl_xor(n, 4);
    n += __shfl_xor(n, 8); n += __shfl_xor(n, 16); n += __shfl_xor(n, 32);
    if ((o & 63) == 0) red[o >> 6] = n;
    __syncthreads();
    float nrm = fmaxf(sqrtf(red[0] + red[1]), 1e-12f);
    stf<BF>(out, (size_t)OUT_PZ + b * D_ + o, r / nrm);
}

__global__ __launch_bounds__(128) void pool_p_k(
    const float* ppart, const float* pcnt, const int* flags, const void* retr, void* out)
{
    if (flags[1]) pool_p_body<1>(ppart, pcnt, retr, out);
    else          pool_p_body<0>(ppart, pcnt, retr, out);
}

// ---------------- finalize sharp / neg_ent ----------------
template<int BF> __device__ __forceinline__ void finalize_body(
    const void* l_mask, int mm, const float* sharp_parts, const float* ent_parts, void* out)
{
    const int b = threadIdx.x;
    float cnt = 0.f;
    for (int l = 0; l < L_; l++) cnt += maskf(l_mask, mm, b * L_ + l);
    const float den = fmaxf(cnt, 1.f);
    float sp = 0.f, en = 0.f;
    for (int k = 0; k < 8; k++) { sp += sharp_parts[b * 8 + k]; en += ent_parts[b * 8 + k]; }
    stf<BF>(out, (size_t)OUT_SHARP + b, sp / den);
    stf<BF>(out, (size_t)OUT_NEGENT + b, -(en / den));
}

__global__ __launch_bounds__(128) void finalize_k(
    const void* l_mask, const int* flags,
    const float* sharp_parts, const float* ent_parts, void* out)
{
    const int mm = flags[0];
    if (flags[1]) finalize_body<1>(l_mask, mm, sharp_parts, ent_parts, out);
    else          finalize_body<0>(l_mask, mm, sharp_parts, ent_parts, out);
}

extern "C" void kernel_launch(void* const* d_in, const int* in_sizes, int n_in,
                              void* d_out, int out_size, void* d_ws, size_t ws_size,
                              hipStream_t stream)
{
    const void* l_x     = d_in[0];
    const void* l_typ   = d_in[1];
    const void* p_x     = d_in[2];
    const void* p_typ   = d_in[3];
    const void* p_score = d_in[4];
    const void* p_rad   = d_in[5];
    const void* l_mask  = d_in[6];
    const void* p_mask  = d_in[7];
    const void* lt_emb  = d_in[8];
    const void* lx_w1   = d_in[9];
    const void* lx_b1   = d_in[10];
    const void* lx_w2   = d_in[11];
    const void* lx_b2   = d_in[12];
    const void* l_ln_g  = d_in[13];
    const void* l_ln_b  = d_in[14];
    const void* pt_emb  = d_in[15];
    const void* px_w1   = d_in[16];
    const void* px_b1   = d_in[17];
    const void* px_w2   = d_in[18];
    const void* px_b2   = d_in[19];
    const void* ps_w1   = d_in[20];
    const void* ps_b1   = d_in[21];
    const void* ps_w2   = d_in[22];
    const void* ps_b2   = d_in[23];
    const void* p_ln_g  = d_in[24];
    const void* p_ln_b  = d_in[25];
    const void* proj_l  = d_in[26];
    const void* proj_p  = d_in[27];
    const void* dustv   = d_in[28];
    const void* sg_w1   = d_in[29];
    const void* sg_b1   = d_in[30];
    const void* sg_w2   = d_in[31];
    const void* sg_b2   = d_in[32];
    const void* retr_l  = d_in[33];
    const void* retr_p  = d_in[34];

    float* ws     = (float*)d_ws;
    __hip_bfloat16* hLb = (__hip_bfloat16*)(ws + WS_HLB);
    __hip_bfloat16* hPb = (__hip_bfloat16*)(ws + WS_HPB);
    float* dust   = ws + WS_DUST;
    float* sharpp = ws + WS_SHARPP;
    float* entp   = ws + WS_ENTP;
    int*   flags  = (int*)(ws + WS_FLAG);
    __hip_bfloat16* wt = (__hip_bfloat16*)(ws + WS_WT);
    float* ppart  = ws + WS_PPART;
    float* pcnt   = ws + WS_PCNT;

    detect_k<<<1, 64, 0, stream>>>((const unsigned int*)p_x, (const unsigned int*)p_mask,
                                   (const unsigned int*)p_typ, flags);
    wt_prep_k<<<64, 256, 0, stream>>>(px_w1, px_w2, ps_w2, proj_p, sg_w1, wt, flags);
    enc_l_k<<<(B_ * L_) / RL, 128, 0, stream>>>(l_x, l_typ, lx_w1, lx_b1, lx_w2, lx_b2,
                                                l_ln_g, l_ln_b, lt_emb, proj_l, dustv,
                                                hLb, dust, flags);
    enc_p_k<<<B_ * (P_ / ROWS), 256, ENC_P_SMEM, stream>>>(
        p_x, p_typ, p_score, p_rad,
        px_b1, px_b2, ps_b2, ps_w1, ps_b1,
        p_ln_g, p_ln_b, pt_emb,
        sg_b1, sg_w2, sg_b2,
        (const unsigned short*)wt, p_mask, flags,
        d_out, hPb, ppart, pcnt);
    logits_sm_k<<<B_ * 8, 256, 0, stream>>>((const unsigned short*)hLb, (const unsigned short*)hPb,
                                            dust, l_mask, p_mask, flags, d_out, sharpp, entp);
    pool_l_k<<<B_, 128, 0, stream>>>((const unsigned short*)hLb, l_mask, flags, retr_l, d_out);
    pool_p_k<<<B_, 128, 0, stream>>>(ppart, pcnt, flags, retr_p, d_out);
    finalize_k<<<1, 128, 0, stream>>>(l_mask, flags, sharpp, entp, d_out);
}

// Round 9
// 262.711 us; speedup vs baseline: 9.4611x; 1.2997x over previous
//
#include <hip/hip_runtime.h>
#include <hip/hip_bf16.h>
#include <math.h>

// PharmMatchNetFast — round 9:
// (a) enc_p epilogues moved into registers (MFMA D-layout native): bias/gelu/
//     emb/LN/pool/sigma via shfl-reduces + 128-float LDS scratch. f32 Bb LDS
//     buffer deleted (33.6KB -> 18.3KB), bank-conflict LN pattern gone.
// (b) logits_sm blockIdx remap (b-minor) so the 8 tiles of one batch share an
//     XCD's L2 for the 256KB hPb panel.
#define B_ 128
#define L_ 128
#define P_ 1024
#define D_ 128
#define NT_ 256

#define NEGF (-__FLT_MAX__)
#define SCALE_ 0.08838834764831845f
#define CLAMPV 1e30f

// output offsets (elements)
#define OUT_SHARP  16793600
#define OUT_NEGENT 16793728
#define OUT_LZ     16793856
#define OUT_PZ     16810240
#define OUT_SIG    16826624

// ws offsets (floats)
#define WS_HLB    0
#define WS_HPB    1048576
#define WS_DUST   9437184
#define WS_SHARPP 9453568
#define WS_ENTP   9454592
#define WS_FLAG   9455616
#define WS_WT     9455632
#define WS_PPART  9500696
#define WS_PCNT   10024984

using bh8  = __attribute__((ext_vector_type(8))) short;
using fx4  = __attribute__((ext_vector_type(4))) float;

__device__ __forceinline__ float gelu_(float x) {
    return 0.5f * x * (1.0f + erff(x * 0.7071067811865476f));
}
__device__ __forceinline__ float bf2f(unsigned short u) {
    return __uint_as_float(((unsigned)u) << 16);
}
__device__ __forceinline__ float sanz(float x) {
    return fminf(fmaxf(x, -CLAMPV), CLAMPV);
}
template<int BF> __device__ __forceinline__ float ldf(const void* p, int i) {
    if constexpr (BF) return bf2f(((const unsigned short*)p)[i]);
    else return ((const float*)p)[i];
}
template<int BF> __device__ __forceinline__ void stf(void* p, size_t i, float x) {
    x = sanz(x);
    if constexpr (BF) ((__hip_bfloat16*)p)[i] = __float2bfloat16(x);
    else ((float*)p)[i] = x;
}
__device__ __forceinline__ float maskf(const void* m, int mm, int idx) {
    if (mm == 3) return ((const float*)m)[idx] != 0.f ? 1.f : 0.f;
    if (mm == 2) return ((const unsigned short*)m)[idx] ? 1.f : 0.f;
    if (mm == 1) return ((const unsigned char*)m)[idx] ? 1.f : 0.f;
    return ((const int*)m)[idx] ? 1.f : 0.f;
}
__device__ __forceinline__ int typf(const void* p, int tm, int idx) {
    int v;
    if (tm == 2) v = (int)bf2f(((const unsigned short*)p)[idx]);
    else if (tm == 1) v = (int)((const long long*)p)[idx];
    else v = ((const int*)p)[idx];
    return v < 0 ? 0 : (v > NT_ - 1 ? NT_ - 1 : v);
}

__global__ __launch_bounds__(64) void detect_k(const unsigned int* __restrict__ px,
                                               const unsigned int* __restrict__ pm,
                                               const unsigned int* __restrict__ pt,
                                               int* __restrict__ flags)
{
    const int t = threadIdx.x;
    int hit = 0;
    for (int i = t; i < 4096; i += 64) {
        unsigned e = (px[i] >> 7) & 0xFFu;
        hit += (e >= 110 && e <= 132) ? 1 : 0;
    }
    for (int s = 1; s < 64; s <<= 1) hit += __shfl_xor(hit, s);

    unsigned big = 0, lo3f = 0, hi3f = 0;
    for (int i = t; i < 1024; i += 64) {
        unsigned wv = pm[i];
        big  |= (wv > 1u) ? 1u : 0u;
        lo3f |= ((wv & 0xFFFFu) == 0x3F80u) ? 1u : 0u;
        hi3f |= ((wv >> 16) == 0x3F80u) ? 1u : 0u;
    }
    unsigned long long aBig = __ballot(big != 0), aLo = __ballot(lo3f != 0), aHi = __ballot(hi3f != 0);

    unsigned tbig = 0, oddnz = 0;
    for (int i = t; i < 512; i += 64) {
        unsigned we = pt[2 * i], wo = pt[2 * i + 1];
        tbig  |= (we > 0xFFFFu || wo > 0xFFFFu) ? 1u : 0u;
        oddnz |= (wo != 0u) ? 1u : 0u;
    }
    unsigned long long aTb = __ballot(tbig != 0), aOdd = __ballot(oddnz != 0);

    if (t == 0) {
        flags[1] = (hit > 2048) ? 1 : 0;
        flags[0] = aLo ? 2 : (aHi ? 3 : (aBig ? 1 : 0));
        flags[2] = aTb ? 2 : (!aOdd ? 1 : 0);
    }
}

// ---------------- weight transpose prep ----------------
template<int BF> __device__ __forceinline__ void wt_prep_body(
    const void* w1, const void* w2, const void* sw2,
    const void* proj, const void* gw1, __hip_bfloat16* wt)
{
    const int idx = blockIdx.x * 256 + threadIdx.x;
    const int stride = gridDim.x * 256;
    for (int i = idx; i < 128 * 192; i += stride) {
        int n = i / 192, k = i - n * 192;
        wt[n * 192 + k] = __float2bfloat16(ldf<BF>(w1, k * 128 + n));
    }
    __hip_bfloat16* w2c = wt + 24576;
    for (int i = idx; i < 128 * 256; i += stride) {
        int n = i >> 8, k = i & 255;
        float v = (k < 128) ? ldf<BF>(w2, k * 128 + n) : ldf<BF>(sw2, (k - 128) * 128 + n);
        w2c[n * 256 + k] = __float2bfloat16(v);
    }
    __hip_bfloat16* pjt = wt + 57344;
    for (int i = idx; i < 128 * 128; i += stride) {
        int n = i >> 7, k = i & 127;
        pjt[n * 128 + k] = __float2bfloat16(ldf<BF>(proj, k * 128 + n));
    }
    __hip_bfloat16* g1t = wt + 73728;
    for (int i = idx; i < 128 * 128; i += stride) {
        int n = i >> 7, k = i & 127;
        g1t[n * 128 + k] = __float2bfloat16(ldf<BF>(gw1, k * 128 + n));
    }
}

__global__ __launch_bounds__(256) void wt_prep_k(
    const void* w1, const void* w2, const void* sw2,
    const void* proj, const void* gw1, __hip_bfloat16* wt, const int* flags)
{
    if (flags[1]) wt_prep_body<1>(w1, w2, sw2, proj, gw1, wt);
    else          wt_prep_body<0>(w1, w2, sw2, proj, gw1, wt);
}

// ---------------- encode L (unchanged, passing) ----------------
#define RL 8
template<int BF> __device__ __forceinline__ void enc_l_body(
    const void* l_x, const void* l_typ, int tm,
    const void* w1, const void* b1, const void* w2, const void* b2,
    const void* lng, const void* lnb, const void* emb, const void* proj,
    const void* dustv, __hip_bfloat16* hLb, float* dust)
{
    __shared__ __align__(16) float X[RL * 8];
    __shared__ __align__(16) float H[RL][D_];
    __shared__ __align__(16) float Y[RL][D_];
    __shared__ float mus[RL], rss[RL];
    const int o = threadIdx.x;
    const int base = blockIdx.x * RL;

    if (o < RL * 8) X[o] = ldf<BF>(l_x, base * 8 + o);
    __syncthreads();

    float acc[RL];
    const float b1o = ldf<BF>(b1, o);
#pragma unroll
    for (int r = 0; r < RL; r++) acc[r] = b1o;
#pragma unroll
    for (int i = 0; i < 8; i += 4) {
        float wa = ldf<BF>(w1, (i + 0) * D_ + o), wb = ldf<BF>(w1, (i + 1) * D_ + o);
        float wc = ldf<BF>(w1, (i + 2) * D_ + o), wd = ldf<BF>(w1, (i + 3) * D_ + o);
#pragma unroll
        for (int r = 0; r < RL; r++) {
            const float4 x4 = *(const float4*)&X[r * 8 + i];
            acc[r] = fmaf(x4.x, wa, fmaf(x4.y, wb, fmaf(x4.z, wc, fmaf(x4.w, wd, acc[r]))));
        }
    }
#pragma unroll
    for (int r = 0; r < RL; r++) H[r][o] = gelu_(acc[r]);
    __syncthreads();

#pragma unroll
    for (int r = 0; r < RL; r++) {
        int tt = typf(l_typ, tm, base + r);
        acc[r] = ldf<BF>(b2, o) + ldf<BF>(emb, tt * D_ + o);
    }
    for (int i = 0; i < D_; i += 4) {
        float wa = ldf<BF>(w2, (i + 0) * D_ + o), wb = ldf<BF>(w2, (i + 1) * D_ + o);
        float wc = ldf<BF>(w2, (i + 2) * D_ + o), wd = ldf<BF>(w2, (i + 3) * D_ + o);
#pragma unroll
        for (int r = 0; r < RL; r++) {
            const float4 h4 = *(const float4*)&H[r][i];
            acc[r] = fmaf(h4.x, wa, fmaf(h4.y, wb, fmaf(h4.z, wc, fmaf(h4.w, wd, acc[r]))));
        }
    }
#pragma unroll
    for (int r = 0; r < RL; r++) Y[r][o] = acc[r];
    __syncthreads();

    {
        const int r = o >> 4, j = o & 15;
        float s = 0.f;
#pragma unroll
        for (int i = 0; i < 8; i++) s += Y[r][j * 8 + i];
        s += __shfl_xor(s, 1); s += __shfl_xor(s, 2); s += __shfl_xor(s, 4); s += __shfl_xor(s, 8);
        const float mu = s * (1.f / 128.f);
        float v = 0.f;
#pragma unroll
        for (int i = 0; i < 8; i++) { float d = Y[r][j * 8 + i] - mu; v = fmaf(d, d, v); }
        v += __shfl_xor(v, 1); v += __shfl_xor(v, 2); v += __shfl_xor(v, 4); v += __shfl_xor(v, 8);
        if (j == 0) { mus[r] = mu; rss[r] = rsqrtf(v * (1.f / 128.f) + 1e-5f); }
    }
    __syncthreads();
    {
        const float g = ldf<BF>(lng, o), bl = ldf<BF>(lnb, o);
#pragma unroll
        for (int r = 0; r < RL; r++) Y[r][o] = fmaf((Y[r][o] - mus[r]) * rss[r], g, bl);
    }
    __syncthreads();

#pragma unroll
    for (int r = 0; r < RL; r++) acc[r] = 0.f;
    for (int i = 0; i < D_; i += 4) {
        float wa = ldf<BF>(proj, (i + 0) * D_ + o), wb = ldf<BF>(proj, (i + 1) * D_ + o);
        float wc = ldf<BF>(proj, (i + 2) * D_ + o), wd = ldf<BF>(proj, (i + 3) * D_ + o);
#pragma unroll
        for (int r = 0; r < RL; r++) {
            const float4 y4 = *(const float4*)&Y[r][i];
            acc[r] = fmaf(y4.x, wa, fmaf(y4.y, wb, fmaf(y4.z, wc, fmaf(y4.w, wd, acc[r]))));
        }
    }
    const float dvo = ldf<BF>(dustv, o);
#pragma unroll
    for (int r = 0; r < RL; r++) {
        hLb[(size_t)(base + r) * D_ + o] = __float2bfloat16(acc[r]);
        H[r][o] = acc[r] * dvo;
    }
    __syncthreads();
    {
        const int r = o >> 4, j = o & 15;
        float s = 0.f;
#pragma unroll
        for (int i = 0; i < 8; i++) s += H[r][j * 8 + i];
        s += __shfl_xor(s, 1); s += __shfl_xor(s, 2); s += __shfl_xor(s, 4); s += __shfl_xor(s, 8);
        if (j == 0) dust[base + r] = s * SCALE_;
    }
}

__global__ __launch_bounds__(128) void enc_l_k(
    const void* l_x, const void* l_typ,
    const void* w1, const void* b1, const void* w2, const void* b2,
    const void* lng, const void* lnb, const void* emb, const void* proj,
    const void* dustv, __hip_bfloat16* hLb, float* dust, const int* flags)
{
    const int tm = flags[2];
    if (flags[1]) enc_l_body<1>(l_x, l_typ, tm, w1, b1, w2, b2, lng, lnb, emb, proj, dustv, hLb, dust);
    else          enc_l_body<0>(l_x, l_typ, tm, w1, b1, w2, b2, lng, lnb, emb, proj, dustv, hLb, dust);
}

// ---------------- encode P (MFMA, in-register epilogues) ----------------
// 256 thr = 4 waves; wave w owns cols 32w..32w+31 (2 n-tiles); M-loop mt=0,1.
// Lane (m,g): D rows mt*16+g*4+j, cols c0=32w+m, c1=32w+16+m.
// LDS: X bf16 [32][264] + red1/red2[128] + pm/sc[32] f32 + tt[32] int = 18304 B
#define XS 264
#define ROWS 32
#define ENC_P_SMEM 18304
template<int BF> __device__ __forceinline__ void enc_p_body(
    unsigned short* X, float* red1, float* red2, float* pm_s, float* sc_s, int* tt_s,
    const void* p_x, const void* p_typ, int tm,
    const void* p_score, const void* p_rad,
    const void* b1, const void* b2, const void* sb2,
    const void* sw1, const void* sb1,
    const void* lng, const void* lnb, const void* emb,
    const void* gb1, const void* gw2, const void* gb2,
    const unsigned short* wt, const void* p_mask, int mm,
    void* out, __hip_bfloat16* hPb, float* ppart, float* pcnt)
{
    const int t = threadIdx.x;
    const int o = t & 127, rh = t >> 7;
    const int lane = t & 63, w = t >> 6;
    const int m = lane & 15, g = lane >> 4;
    const int b = blockIdx.x >> 5, tile = blockIdx.x & 31;
    const int base = b * P_ + tile * ROWS;
    const int c0 = 32 * w + m, c1 = 32 * w + 16 + m;
    __hip_bfloat16* Xb = (__hip_bfloat16*)X;

    // stage p_x tile + row scalars
    for (int i = t; i < ROWS * 192; i += 256) {
        int r = i / 192, k = i - r * 192;
        Xb[r * XS + k] = __float2bfloat16(ldf<BF>(p_x, (base + r) * 192 + k));
    }
    if (t < ROWS) {
        pm_s[t] = maskf(p_mask, mm, base + t);
        sc_s[t] = ldf<BF>(p_score, base + t);
        tt_s[t] = typf(p_typ, tm, base + t);
    }
    __syncthreads();

    // GEMM1: X[32x192] @ w1
    fx4 A1[2][2];
#pragma unroll
    for (int mt = 0; mt < 2; mt++) { A1[mt][0] = fx4{0,0,0,0}; A1[mt][1] = fx4{0,0,0,0}; }
    {
        const unsigned short* w1T = wt;
        bh8 bf[12];
#pragma unroll
        for (int ks = 0; ks < 6; ks++) {
            bf[ks * 2 + 0] = *(const bh8*)(w1T + ((2 * w + 0) * 16 + m) * 192 + g * 8 + ks * 32);
            bf[ks * 2 + 1] = *(const bh8*)(w1T + ((2 * w + 1) * 16 + m) * 192 + g * 8 + ks * 32);
        }
#pragma unroll
        for (int mt = 0; mt < 2; mt++) {
            const unsigned short* xr = X + (mt * 16 + m) * XS + g * 8;
#pragma unroll
            for (int ks = 0; ks < 6; ks++) {
                bh8 a = *(const bh8*)(xr + ks * 32);
                A1[mt][0] = __builtin_amdgcn_mfma_f32_16x16x32_bf16(a, bf[ks * 2 + 0], A1[mt][0], 0, 0, 0);
                A1[mt][1] = __builtin_amdgcn_mfma_f32_16x16x32_bf16(a, bf[ks * 2 + 1], A1[mt][1], 0, 0, 0);
            }
        }
    }
    __syncthreads();   // all X reads done before overwriting

    // ep1 (in-reg): h1 = gelu(D + b1[c]) -> X[:,0:128]
    {
        const float bb0 = ldf<BF>(b1, c0), bb1 = ldf<BF>(b1, c1);
#pragma unroll
        for (int mt = 0; mt < 2; mt++)
#pragma unroll
            for (int j = 0; j < 4; j++) {
                const int row = mt * 16 + g * 4 + j;
                Xb[row * XS + c0] = __float2bfloat16(gelu_(A1[mt][0][j] + bb0));
                Xb[row * XS + c1] = __float2bfloat16(gelu_(A1[mt][1][j] + bb1));
            }
    }
    // hs = gelu(score*sw1+sb1) -> X[:,128:256] (o/rh mapping)
    {
        const float a1v = ldf<BF>(sw1, o), a0v = ldf<BF>(sb1, o);
#pragma unroll
        for (int r = 0; r < 16; r++) {
            const int row = rh * 16 + r;
            Xb[row * XS + 128 + o] = __float2bfloat16(gelu_(fmaf(sc_s[row], a1v, a0v)));
        }
    }
    __syncthreads();

    // GEMM2: [h1|hs][32x256] @ w2c
    fx4 A2[2][2];
#pragma unroll
    for (int mt = 0; mt < 2; mt++) { A2[mt][0] = fx4{0,0,0,0}; A2[mt][1] = fx4{0,0,0,0}; }
    {
        const unsigned short* w2cT = wt + 24576;
        bh8 bf[16];
#pragma unroll
        for (int ks = 0; ks < 8; ks++) {
            bf[ks * 2 + 0] = *(const bh8*)(w2cT + ((2 * w + 0) * 16 + m) * 256 + g * 8 + ks * 32);
            bf[ks * 2 + 1] = *(const bh8*)(w2cT + ((2 * w + 1) * 16 + m) * 256 + g * 8 + ks * 32);
        }
#pragma unroll
        for (int mt = 0; mt < 2; mt++) {
            const unsigned short* xr = X + (mt * 16 + m) * XS + g * 8;
#pragma unroll
            for (int ks = 0; ks < 8; ks++) {
                bh8 a = *(const bh8*)(xr + ks * 32);
                A2[mt][0] = __builtin_amdgcn_mfma_f32_16x16x32_bf16(a, bf[ks * 2 + 0], A2[mt][0], 0, 0, 0);
                A2[mt][1] = __builtin_amdgcn_mfma_f32_16x16x32_bf16(a, bf[ks * 2 + 1], A2[mt][1], 0, 0, 0);
            }
        }
    }
    // ep2 (in-reg): h2 = D + b2 + sb2 + emb[typ]
    {
        const float bc0 = ldf<BF>(b2, c0) + ldf<BF>(sb2, c0);
        const float bc1 = ldf<BF>(b2, c1) + ldf<BF>(sb2, c1);
#pragma unroll
        for (int mt = 0; mt < 2; mt++)
#pragma unroll
            for (int j = 0; j < 4; j++) {
                const int row = mt * 16 + g * 4 + j;
                const int tt = tt_s[row];
                A2[mt][0][j] += bc0 + ldf<BF>(emb, tt * D_ + c0);
                A2[mt][1][j] += bc1 + ldf<BF>(emb, tt * D_ + c1);
            }
    }
    // LN mean partials (sum over wave's 32 cols per row)
#pragma unroll
    for (int mt = 0; mt < 2; mt++)
#pragma unroll
        for (int j = 0; j < 4; j++) {
            float s = A2[mt][0][j] + A2[mt][1][j];
            s += __shfl_xor(s, 1); s += __shfl_xor(s, 2); s += __shfl_xor(s, 4); s += __shfl_xor(s, 8);
            if (m == 0) red1[(mt * 16 + g * 4 + j) * 4 + w] = s;
        }
    __syncthreads();
    float mu_[2][4];
#pragma unroll
    for (int mt = 0; mt < 2; mt++)
#pragma unroll
        for (int j = 0; j < 4; j++) {
            const int row = mt * 16 + g * 4 + j;
            mu_[mt][j] = ((red1[row * 4 + 0] + red1[row * 4 + 1]) +
                          (red1[row * 4 + 2] + red1[row * 4 + 3])) * (1.f / 128.f);
            float d0 = A2[mt][0][j] - mu_[mt][j];
            float d1 = A2[mt][1][j] - mu_[mt][j];
            float v = fmaf(d0, d0, d1 * d1);
            v += __shfl_xor(v, 1); v += __shfl_xor(v, 2); v += __shfl_xor(v, 4); v += __shfl_xor(v, 8);
            if (m == 0) red2[row * 4 + w] = v;
        }
    __syncthreads();
    // LN apply -> X bf16 [:,0:128]
    {
        const float gc0 = ldf<BF>(lng, c0), bl0 = ldf<BF>(lnb, c0);
        const float gc1 = ldf<BF>(lng, c1), bl1 = ldf<BF>(lnb, c1);
#pragma unroll
        for (int mt = 0; mt < 2; mt++)
#pragma unroll
            for (int j = 0; j < 4; j++) {
                const int row = mt * 16 + g * 4 + j;
                float var = ((red2[row * 4 + 0] + red2[row * 4 + 1]) +
                             (red2[row * 4 + 2] + red2[row * 4 + 3])) * (1.f / 128.f);
                float rs = rsqrtf(var + 1e-5f);
                float y0 = fmaf((A2[mt][0][j] - mu_[mt][j]) * rs, gc0, bl0);
                float y1 = fmaf((A2[mt][1][j] - mu_[mt][j]) * rs, gc1, bl1);
                Xb[row * XS + c0] = __float2bfloat16(y0);
                Xb[row * XS + c1] = __float2bfloat16(y1);
            }
    }
    __syncthreads();

    // GEMM3: hp = y[32x128] @ proj
    fx4 A3[2][2];
#pragma unroll
    for (int mt = 0; mt < 2; mt++) { A3[mt][0] = fx4{0,0,0,0}; A3[mt][1] = fx4{0,0,0,0}; }
    {
        const unsigned short* pjT = wt + 57344;
        bh8 bf[8];
#pragma unroll
        for (int ks = 0; ks < 4; ks++) {
            bf[ks * 2 + 0] = *(const bh8*)(pjT + ((2 * w + 0) * 16 + m) * 128 + g * 8 + ks * 32);
            bf[ks * 2 + 1] = *(const bh8*)(pjT + ((2 * w + 1) * 16 + m) * 128 + g * 8 + ks * 32);
        }
#pragma unroll
        for (int mt = 0; mt < 2; mt++) {
            const unsigned short* xr = X + (mt * 16 + m) * XS + g * 8;
#pragma unroll
            for (int ks = 0; ks < 4; ks++) {
                bh8 a = *(const bh8*)(xr + ks * 32);
                A3[mt][0] = __builtin_amdgcn_mfma_f32_16x16x32_bf16(a, bf[ks * 2 + 0], A3[mt][0], 0, 0, 0);
                A3[mt][1] = __builtin_amdgcn_mfma_f32_16x16x32_bf16(a, bf[ks * 2 + 1], A3[mt][1], 0, 0, 0);
            }
        }
    }
    __syncthreads();   // all X reads done

    // ep3: hPb store (32B chunks) + X <- hp bf16 + in-reg pool partials
    {
#pragma unroll
        for (int mt = 0; mt < 2; mt++)
#pragma unroll
            for (int j = 0; j < 4; j++) {
                const int row = mt * 16 + g * 4 + j;
                __hip_bfloat16 h0 = __float2bfloat16(A3[mt][0][j]);
                __hip_bfloat16 h1 = __float2bfloat16(A3[mt][1][j]);
                hPb[(size_t)(base + row) * D_ + c0] = h0;
                hPb[(size_t)(base + row) * D_ + c1] = h1;
                Xb[row * XS + c0] = *(unsigned short*)&h0 ? h0 : h0;  // plain store
                Xb[row * XS + c1] = h1;
            }
        float ps0 = 0.f, ps1 = 0.f;
#pragma unroll
        for (int mt = 0; mt < 2; mt++)
#pragma unroll
            for (int j = 0; j < 4; j++) {
                const int row = mt * 16 + g * 4 + j;
                ps0 = fmaf(A3[mt][0][j], pm_s[row], ps0);
                ps1 = fmaf(A3[mt][1][j], pm_s[row], ps1);
            }
        ps0 += __shfl_xor(ps0, 16); ps0 += __shfl_xor(ps0, 32);
        ps1 += __shfl_xor(ps1, 16); ps1 += __shfl_xor(ps1, 32);
        if (g == 0) {
            ppart[(size_t)blockIdx.x * D_ + c0] = ps0;
            ppart[(size_t)blockIdx.x * D_ + c1] = ps1;
        }
        if (t == 0) {
            float c = 0.f;
#pragma unroll
            for (int r = 0; r < ROWS; r++) c += pm_s[r];
            pcnt[blockIdx.x] = c;
        }
    }
    __syncthreads();

    // GEMM4: g1raw = hp[32x128] @ gw1
    fx4 A4[2][2];
#pragma unroll
    for (int mt = 0; mt < 2; mt++) { A4[mt][0] = fx4{0,0,0,0}; A4[mt][1] = fx4{0,0,0,0}; }
    {
        const unsigned short* g1T = wt + 73728;
        bh8 bf[8];
#pragma unroll
        for (int ks = 0; ks < 4; ks++) {
            bf[ks * 2 + 0] = *(const bh8*)(g1T + ((2 * w + 0) * 16 + m) * 128 + g * 8 + ks * 32);
            bf[ks * 2 + 1] = *(const bh8*)(g1T + ((2 * w + 1) * 16 + m) * 128 + g * 8 + ks * 32);
        }
#pragma unroll
        for (int mt = 0; mt < 2; mt++) {
            const unsigned short* xr = X + (mt * 16 + m) * XS + g * 8;
#pragma unroll
            for (int ks = 0; ks < 4; ks++) {
                bh8 a = *(const bh8*)(xr + ks * 32);
                A4[mt][0] = __builtin_amdgcn_mfma_f32_16x16x32_bf16(a, bf[ks * 2 + 0], A4[mt][0], 0, 0, 0);
                A4[mt][1] = __builtin_amdgcn_mfma_f32_16x16x32_bf16(a, bf[ks * 2 + 1], A4[mt][1], 0, 0, 0);
            }
        }
    }
    // ep4 (in-reg): g1 = gelu(D+gb1); sigma dot partials over wave cols
    {
        const float gb0 = ldf<BF>(gb1, c0), gb1v = ldf<BF>(gb1, c1);
        const float w20 = ldf<BF>(gw2, c0), w21 = ldf<BF>(gw2, c1);
#pragma unroll
        for (int mt = 0; mt < 2; mt++)
#pragma unroll
            for (int j = 0; j < 4; j++) {
                const int row = mt * 16 + g * 4 + j;
                float g0 = gelu_(A4[mt][0][j] + gb0);
                float g1v = gelu_(A4[mt][1][j] + gb1v);
                float p = fmaf(g0, w20, g1v * w21);
                p += __shfl_xor(p, 1); p += __shfl_xor(p, 2); p += __shfl_xor(p, 4); p += __shfl_xor(p, 8);
                if (m == 0) red1[row * 4 + w] = p;
            }
    }
    __syncthreads();
    if (t < ROWS) {
        float s = (red1[t * 4 + 0] + red1[t * 4 + 1]) + (red1[t * 4 + 2] + red1[t * 4 + 3]);
        float v = s + ldf<BF>(gb2, 0);
        float sp = fmaxf(v, 0.f) + log1pf(expf(-fabsf(v)));
        stf<BF>(out, (size_t)OUT_SIG + base + t, sp + 1e-3f + fmaxf(ldf<BF>(p_rad, base + t), 0.f));
    }
}

__global__ __launch_bounds__(256) void enc_p_k(
    const void* p_x, const void* p_typ, const void* p_score, const void* p_rad,
    const void* b1, const void* b2, const void* sb2,
    const void* sw1, const void* sb1,
    const void* lng, const void* lnb, const void* emb,
    const void* gb1, const void* gw2, const void* gb2,
    const unsigned short* wt, const void* p_mask, const int* flags,
    void* out, __hip_bfloat16* hPb, float* ppart, float* pcnt)
{
    extern __shared__ __align__(16) char smem[];
    unsigned short* X = (unsigned short*)smem;          // 16896 B
    float* red1 = (float*)(smem + 16896);               // 512 B
    float* red2 = (float*)(smem + 17408);               // 512 B
    float* pm_s = (float*)(smem + 17920);               // 128 B
    float* sc_s = (float*)(smem + 18048);               // 128 B
    int*   tt_s = (int*)(smem + 18176);                 // 128 B
    const int tm = flags[2], mm = flags[0];
    if (flags[1]) enc_p_body<1>(X, red1, red2, pm_s, sc_s, tt_s,
                                p_x, p_typ, tm, p_score, p_rad, b1, b2, sb2, sw1, sb1,
                                lng, lnb, emb, gb1, gw2, gb2, wt, p_mask, mm,
                                out, hPb, ppart, pcnt);
    else          enc_p_body<0>(X, red1, red2, pm_s, sc_s, tt_s,
                                p_x, p_typ, tm, p_score, p_rad, b1, b2, sb2, sw1, sb1,
                                lng, lnb, emb, gb1, gw2, gb2, wt, p_mask, mm,
                                out, hPb, ppart, pcnt);
}

// ---------------- logits (MFMA) + fused softmax + sharp/ent ----------------
// blockIdx remapped b-minor: b = bid & 127, l0t = bid >> 7 -> all 8 tiles of a
// batch land on the same XCD (L2-resident 256KB hPb panel).
template<int BF> __device__ __forceinline__ void logits_sm_body(
    const unsigned short* hLb, const unsigned short* hPb, const float* dust,
    const void* l_mask, const void* p_mask, int mm,
    void* out, float* sharp_parts, float* ent_parts)
{
    __shared__ float pm_s[1024];
    __shared__ float lm_s[16], dv_s[16];
    __shared__ float redA[64], redB[64], redC[64], redD[64], redM[16], redL[16];
    const int t = threadIdx.x;
    const int lane = t & 63, w = t >> 6;
    const int m = lane & 15, g = lane >> 4;
    const int b = blockIdx.x & 127, l0 = (blockIdx.x >> 7) * 16;

    for (int i = t; i < 1024; i += 256) pm_s[i] = maskf(p_mask, mm, b * P_ + i);
    if (t < 16) {
        lm_s[t] = maskf(l_mask, mm, b * L_ + l0 + t);
        dv_s[t] = dust[b * L_ + l0 + t];
    }
    __syncthreads();

    bh8 af[4];
    {
        const unsigned short* ha = hLb + ((size_t)(b * L_ + l0 + m)) * D_ + g * 8;
#pragma unroll
        for (int ks = 0; ks < 4; ks++) af[ks] = *(const bh8*)(ha + ks * 32);
    }
    const unsigned short* hpb = hPb + ((size_t)(b * P_ + w * 256)) * D_;

    fx4 acc[16];
#pragma unroll
    for (int nt = 0; nt < 16; nt++) {
        fx4 c = {0.f, 0.f, 0.f, 0.f};
        const unsigned short* hr = hpb + (nt * 16 + m) * D_ + g * 8;
#pragma unroll
        for (int ks = 0; ks < 4; ks++) {
            bh8 bfr = *(const bh8*)(hr + ks * 32);
            c = __builtin_amdgcn_mfma_f32_16x16x32_bf16(af[ks], bfr, c, 0, 0, 0);
        }
        acc[nt] = c;
    }

    float rmax[4] = {NEGF, NEGF, NEGF, NEGF};
#pragma unroll
    for (int nt = 0; nt < 16; nt++) {
        const float pv = pm_s[w * 256 + nt * 16 + m];
#pragma unroll
        for (int j = 0; j < 4; j++) {
            const bool ok = (lm_s[g * 4 + j] != 0.f) && (pv != 0.f);
            float v = ok ? acc[nt][j] * SCALE_ : NEGF;
            acc[nt][j] = v;
            rmax[j] = fmaxf(rmax[j], v);
        }
    }
#pragma unroll
    for (int j = 0; j < 4; j++) {
        rmax[j] = fmaxf(rmax[j], __shfl_xor(rmax[j], 1));
        rmax[j] = fmaxf(rmax[j], __shfl_xor(rmax[j], 2));
        rmax[j] = fmaxf(rmax[j], __shfl_xor(rmax[j], 4));
        rmax[j] = fmaxf(rmax[j], __shfl_xor(rmax[j], 8));
    }
    if (m == 0) {
#pragma unroll
        for (int j = 0; j < 4; j++) redA[(g * 4 + j) * 4 + w] = rmax[j];
    }
    __syncthreads();
    float mrow[4], lse[4];
#pragma unroll
    for (int j = 0; j < 4; j++) {
        const int r = g * 4 + j;
        float mm4 = fmaxf(fmaxf(redA[r * 4 + 0], redA[r * 4 + 1]), fmaxf(redA[r * 4 + 2], redA[r * 4 + 3]));
        float dvr = (lm_s[r] != 0.f) ? dv_s[r] : NEGF;
        mrow[j] = fmaxf(mm4, dvr);
    }
    float se[4] = {0.f, 0.f, 0.f, 0.f};
#pragma unroll
    for (int nt = 0; nt < 16; nt++) {
#pragma unroll
        for (int j = 0; j < 4; j++) se[j] += expf(acc[nt][j] - mrow[j]);
    }
#pragma unroll
    for (int j = 0; j < 4; j++) {
        se[j] += __shfl_xor(se[j], 1); se[j] += __shfl_xor(se[j], 2);
        se[j] += __shfl_xor(se[j], 4); se[j] += __shfl_xor(se[j], 8);
    }
    if (m == 0) {
#pragma unroll
        for (int j = 0; j < 4; j++) redB[(g * 4 + j) * 4 + w] = se[j];
    }
    __syncthreads();
#pragma unroll
    for (int j = 0; j < 4; j++) {
        const int r = g * 4 + j;
        float dvr = (lm_s[r] != 0.f) ? dv_s[r] : NEGF;
        float s = (redB[r * 4 + 0] + redB[r * 4 + 1]) + (redB[r * 4 + 2] + redB[r * 4 + 3]);
        s += expf(dvr - mrow[j]);
        lse[j] = logf(s);
    }
    if (w == 0 && m == 0) {
#pragma unroll
        for (int j = 0; j < 4; j++) { redM[g * 4 + j] = mrow[j]; redL[g * 4 + j] = lse[j]; }
    }
    float mw[4] = {0.f, 0.f, 0.f, 0.f}, es[4] = {0.f, 0.f, 0.f, 0.f};
#pragma unroll
    for (int nt = 0; nt < 16; nt++) {
        const float pv = pm_s[w * 256 + nt * 16 + m];
#pragma unroll
        for (int j = 0; j < 4; j++) {
            float lw = acc[nt][j] - mrow[j] - lse[j];
            stf<BF>(out, (size_t)(b * L_ + l0 + g * 4 + j) * (P_ + 1) + w * 256 + nt * 16 + m, lw);
            float lwc = fmaxf(lw, -CLAMPV);
            float wm = expf(lwc) * pv;
            mw[j] = fmaxf(mw[j], wm);
            if (wm > 0.f) es[j] = fmaf(-wm, lwc, es[j]);
        }
    }
#pragma unroll
    for (int j = 0; j < 4; j++) {
        mw[j] = fmaxf(mw[j], __shfl_xor(mw[j], 1));
        mw[j] = fmaxf(mw[j], __shfl_xor(mw[j], 2));
        mw[j] = fmaxf(mw[j], __shfl_xor(mw[j], 4));
        mw[j] = fmaxf(mw[j], __shfl_xor(mw[j], 8));
        es[j] += __shfl_xor(es[j], 1); es[j] += __shfl_xor(es[j], 2);
        es[j] += __shfl_xor(es[j], 4); es[j] += __shfl_xor(es[j], 8);
    }
    if (m == 0) {
#pragma unroll
        for (int j = 0; j < 4; j++) {
            redC[(g * 4 + j) * 4 + w] = mw[j];
            redD[(g * 4 + j) * 4 + w] = es[j];
        }
    }
    __syncthreads();
    if (t < 16) {
        float dvr = (lm_s[t] != 0.f) ? dv_s[t] : NEGF;
        stf<BF>(out, (size_t)(b * L_ + l0 + t) * (P_ + 1) + P_, dvr - redM[t] - redL[t]);
    }
    if (t == 0) {
        float sp = 0.f, en = 0.f;
        for (int r = 0; r < 16; r++) {
            float dvr = (lm_s[r] != 0.f) ? dv_s[r] : NEGF;
            float lwd = fmaxf(dvr - redM[r] - redL[r], -CLAMPV);
            float wd = expf(lwd);
            float mwr = fmaxf(fmaxf(redC[r * 4 + 0], redC[r * 4 + 1]), fmaxf(redC[r * 4 + 2], redC[r * 4 + 3]));
            mwr = fmaxf(mwr, wd);
            float esr = (redD[r * 4 + 0] + redD[r * 4 + 1]) + (redD[r * 4 + 2] + redD[r * 4 + 3]);
            if (wd > 0.f) esr = fmaf(-wd, lwd, esr);
            sp = fmaf(mwr, lm_s[r], sp);
            en = fmaf(esr, lm_s[r], en);
        }
        sharp_parts[blockIdx.x] = sp;
        ent_parts[blockIdx.x] = en;
    }
}

__global__ __launch_bounds__(256) void logits_sm_k(
    const unsigned short* hLb, const unsigned short* hPb, const float* dust,
    const void* l_mask, const void* p_mask, const int* flags,
    void* out, float* sharp_parts, float* ent_parts)
{
    const int mm = flags[0];
    if (flags[1]) logits_sm_body<1>(hLb, hPb, dust, l_mask, p_mask, mm, out, sharp_parts, ent_parts);
    else          logits_sm_body<0>(hLb, hPb, dust, l_mask, p_mask, mm, out, sharp_parts, ent_parts);
}

// ---------------- pooled L ----------------
template<int BF> __device__ __forceinline__ void pool_l_body(
    const unsigned short* hLb, const void* l_mask, int mm, const void* retr, void* out)
{
    __shared__ float lmv[L_];
    __shared__ __align__(16) float lg[D_];
    __shared__ float red[2];
    const int o = threadIdx.x, b = blockIdx.x;
    lmv[o] = maskf(l_mask, mm, b * L_ + o);
    __syncthreads();
    float cnt = 0.f;
    for (int l = 0; l < L_; l++) cnt += lmv[l];
    float s0 = 0, s1 = 0, s2 = 0, s3 = 0;
    const unsigned short* hb = hLb + (size_t)b * L_ * D_;
    for (int l = 0; l < L_; l += 4) {
        s0 = fmaf(bf2f(hb[(l + 0) * D_ + o]), lmv[l + 0], s0);
        s1 = fmaf(bf2f(hb[(l + 1) * D_ + o]), lmv[l + 1], s1);
        s2 = fmaf(bf2f(hb[(l + 2) * D_ + o]), lmv[l + 2], s2);
        s3 = fmaf(bf2f(hb[(l + 3) * D_ + o]), lmv[l + 3], s3);
    }
    lg[o] = ((s0 + s1) + (s2 + s3)) / fmaxf(cnt, 1.f);
    __syncthreads();
    float r = 0.f;
    for (int i = 0; i < D_; i += 4) {
        const float4 g4 = *(const float4*)&lg[i];
        r = fmaf(g4.x, ldf<BF>(retr, (i + 0) * D_ + o), r);
        r = fmaf(g4.y, ldf<BF>(retr, (i + 1) * D_ + o), r);
        r = fmaf(g4.z, ldf<BF>(retr, (i + 2) * D_ + o), r);
        r = fmaf(g4.w, ldf<BF>(retr, (i + 3) * D_ + o), r);
    }
    float n = r * r;
    n += __shfl_xor(n, 1); n += __shfl_xor(n, 2); n += __shfl_xor(n, 4);
    n += __shfl_xor(n, 8); n += __shfl_xor(n, 16); n += __shfl_xor(n, 32);
    if ((o & 63) == 0) red[o >> 6] = n;
    __syncthreads();
    float nrm = fmaxf(sqrtf(red[0] + red[1]), 1e-12f);
    stf<BF>(out, (size_t)OUT_LZ + b * D_ + o, r / nrm);
}

__global__ __launch_bounds__(128) void pool_l_k(
    const unsigned short* hLb, const void* l_mask, const int* flags, const void* retr, void* out)
{
    const int mm = flags[0];
    if (flags[1]) pool_l_body<1>(hLb, l_mask, mm, retr, out);
    else          pool_l_body<0>(hLb, l_mask, mm, retr, out);
}

// ---------------- pooled P ----------------
template<int BF> __device__ __forceinline__ void pool_p_body(
    const float* ppart, const float* pcnt, const void* retr, void* out)
{
    __shared__ __align__(16) float pgs[D_];
    __shared__ float red[2];
    const int o = threadIdx.x, b = blockIdx.x;
    float s = 0.f, c = 0.f;
    for (int k = 0; k < 32; k++) s += ppart[(size_t)(b * 32 + k) * D_ + o];
    for (int k = 0; k < 32; k++) c += pcnt[b * 32 + k];
    pgs[o] = s / fmaxf(c, 1.f);
    __syncthreads();
    float r = 0.f;
    for (int i = 0; i < D_; i += 4) {
        const float4 g4 = *(const float4*)&pgs[i];
        r = fmaf(g4.x, ldf<BF>(retr, (i + 0) * D_ + o), r);
        r = fmaf(g4.y, ldf<BF>(retr, (i + 1) * D_ + o), r);
        r = fmaf(g4.z, ldf<BF>(retr, (i + 2) * D_ + o), r);
        r = fmaf(g4.w, ldf<BF>(retr, (i + 3) * D_ + o), r);
    }
    float n = r * r;
    n += __shfl_xor(n, 1); n += __shfl_xor(n, 2); n += __shfl_xor(n, 4);
    n += __shfl_xor(n, 8); n += __shfl_xor(n, 16); n += __shfl_xor(n, 32);
    if ((o & 63) == 0) red[o >> 6] = n;
    __syncthreads();
    float nrm = fmaxf(sqrtf(red[0] + red[1]), 1e-12f);
    stf<BF>(out, (size_t)OUT_PZ + b * D_ + o, r / nrm);
}

__global__ __launch_bounds__(128) void pool_p_k(
    const float* ppart, const float* pcnt, const int* flags, const void* retr, void* out)
{
    if (flags[1]) pool_p_body<1>(ppart, pcnt, retr, out);
    else          pool_p_body<0>(ppart, pcnt, retr, out);
}

// ---------------- finalize ----------------
template<int BF> __device__ __forceinline__ void finalize_body(
    const void* l_mask, int mm, const float* sharp_parts, const float* ent_parts, void* out)
{
    const int b = threadIdx.x;
    float cnt = 0.f;
    for (int l = 0; l < L_; l++) cnt += maskf(l_mask, mm, b * L_ + l);
    const float den = fmaxf(cnt, 1.f);
    float sp = 0.f, en = 0.f;
    // logits_sm grid is b-minor: block index = l0t*128 + b
    for (int k = 0; k < 8; k++) { sp += sharp_parts[k * 128 + b]; en += ent_parts[k * 128 + b]; }
    stf<BF>(out, (size_t)OUT_SHARP + b, sp / den);
    stf<BF>(out, (size_t)OUT_NEGENT + b, -(en / den));
}

__global__ __launch_bounds__(128) void finalize_k(
    const void* l_mask, const int* flags,
    const float* sharp_parts, const float* ent_parts, void* out)
{
    const int mm = flags[0];
    if (flags[1]) finalize_body<1>(l_mask, mm, sharp_parts, ent_parts, out);
    else          finalize_body<0>(l_mask, mm, sharp_parts, ent_parts, out);
}

extern "C" void kernel_launch(void* const* d_in, const int* in_sizes, int n_in,
                              void* d_out, int out_size, void* d_ws, size_t ws_size,
                              hipStream_t stream)
{
    const void* l_x     = d_in[0];
    const void* l_typ   = d_in[1];
    const void* p_x     = d_in[2];
    const void* p_typ   = d_in[3];
    const void* p_score = d_in[4];
    const void* p_rad   = d_in[5];
    const void* l_mask  = d_in[6];
    const void* p_mask  = d_in[7];
    const void* lt_emb  = d_in[8];
    const void* lx_w1   = d_in[9];
    const void* lx_b1   = d_in[10];
    const void* lx_w2   = d_in[11];
    const void* lx_b2   = d_in[12];
    const void* l_ln_g  = d_in[13];
    const void* l_ln_b  = d_in[14];
    const void* pt_emb  = d_in[15];
    const void* px_w1   = d_in[16];
    const void* px_b1   = d_in[17];
    const void* px_w2   = d_in[18];
    const void* px_b2   = d_in[19];
    const void* ps_w1   = d_in[20];
    const void* ps_b1   = d_in[21];
    const void* ps_w2   = d_in[22];
    const void* ps_b2   = d_in[23];
    const void* p_ln_g  = d_in[24];
    const void* p_ln_b  = d_in[25];
    const void* proj_l  = d_in[26];
    const void* proj_p  = d_in[27];
    const void* dustv   = d_in[28];
    const void* sg_w1   = d_in[29];
    const void* sg_b1   = d_in[30];
    const void* sg_w2   = d_in[31];
    const void* sg_b2   = d_in[32];
    const void* retr_l  = d_in[33];
    const void* retr_p  = d_in[34];

    float* ws     = (float*)d_ws;
    __hip_bfloat16* hLb = (__hip_bfloat16*)(ws + WS_HLB);
    __hip_bfloat16* hPb = (__hip_bfloat16*)(ws + WS_HPB);
    float* dust   = ws + WS_DUST;
    float* sharpp = ws + WS_SHARPP;
    float* entp   = ws + WS_ENTP;
    int*   flags  = (int*)(ws + WS_FLAG);
    __hip_bfloat16* wt = (__hip_bfloat16*)(ws + WS_WT);
    float* ppart  = ws + WS_PPART;
    float* pcnt   = ws + WS_PCNT;

    detect_k<<<1, 64, 0, stream>>>((const unsigned int*)p_x, (const unsigned int*)p_mask,
                                   (const unsigned int*)p_typ, flags);
    wt_prep_k<<<64, 256, 0, stream>>>(px_w1, px_w2, ps_w2, proj_p, sg_w1, wt, flags);
    enc_l_k<<<(B_ * L_) / RL, 128, 0, stream>>>(l_x, l_typ, lx_w1, lx_b1, lx_w2, lx_b2,
                                                l_ln_g, l_ln_b, lt_emb, proj_l, dustv,
                                                hLb, dust, flags);
    enc_p_k<<<B_ * (P_ / ROWS), 256, ENC_P_SMEM, stream>>>(
        p_x, p_typ, p_score, p_rad,
        px_b1, px_b2, ps_b2, ps_w1, ps_b1,
        p_ln_g, p_ln_b, pt_emb,
        sg_b1, sg_w2, sg_b2,
        (const unsigned short*)wt, p_mask, flags,
        d_out, hPb, ppart, pcnt);
    logits_sm_k<<<B_ * 8, 256, 0, stream>>>((const unsigned short*)hLb, (const unsigned short*)hPb,
                                            dust, l_mask, p_mask, flags, d_out, sharpp, entp);
    pool_l_k<<<B_, 128, 0, stream>>>((const unsigned short*)hLb, l_mask, flags, retr_l, d_out);
    pool_p_k<<<B_, 128, 0, stream>>>(ppart, pcnt, flags, retr_p, d_out);
    finalize_k<<<1, 128, 0, stream>>>(l_mask, flags, sharpp, entp, d_out);
}

// Round 10
// 220.537 us; speedup vs baseline: 11.2704x; 1.1912x over previous
//
#include <hip/hip_runtime.h>
#include <hip/hip_bf16.h>
#include <math.h>

// PharmMatchNetFast — round 10:
// (a) GELU via tanh-form sigmoid identity: x*sigma(1.59577x+0.071355x^3),
//     native v_exp+v_rcp (~7 VALU) vs ocml erff (~25-30). Max abs dev ~3e-4,
//     below the bf16 rounding (4e-3) of every stored intermediate.
// (b) logits_sm uses __expf/__logf (native v_exp/v_log).
// (c) pool_l + pool_p + finalize merged into one epilogue kernel.
#define B_ 128
#define L_ 128
#define P_ 1024
#define D_ 128
#define NT_ 256

#define NEGF (-__FLT_MAX__)
#define SCALE_ 0.08838834764831845f
#define CLAMPV 1e30f

// output offsets (elements)
#define OUT_SHARP  16793600
#define OUT_NEGENT 16793728
#define OUT_LZ     16793856
#define OUT_PZ     16810240
#define OUT_SIG    16826624

// ws offsets (floats)
#define WS_HLB    0
#define WS_HPB    1048576
#define WS_DUST   9437184
#define WS_SHARPP 9453568
#define WS_ENTP   9454592
#define WS_FLAG   9455616
#define WS_WT     9455632
#define WS_PPART  9500696
#define WS_PCNT   10024984

using bh8  = __attribute__((ext_vector_type(8))) short;
using fx4  = __attribute__((ext_vector_type(4))) float;

// tanh-form GELU (see header note): numerically invisible under bf16 storage.
__device__ __forceinline__ float gelu_(float x) {
    float c = x * x;
    float v = x * fmaf(c, 0.07135481584f, 1.5957691216f);
    return x * __builtin_amdgcn_rcpf(1.0f + __expf(-v));
}
__device__ __forceinline__ float bf2f(unsigned short u) {
    return __uint_as_float(((unsigned)u) << 16);
}
__device__ __forceinline__ float sanz(float x) {
    return fminf(fmaxf(x, -CLAMPV), CLAMPV);
}
template<int BF> __device__ __forceinline__ float ldf(const void* p, int i) {
    if constexpr (BF) return bf2f(((const unsigned short*)p)[i]);
    else return ((const float*)p)[i];
}
template<int BF> __device__ __forceinline__ void stf(void* p, size_t i, float x) {
    x = sanz(x);
    if constexpr (BF) ((__hip_bfloat16*)p)[i] = __float2bfloat16(x);
    else ((float*)p)[i] = x;
}
__device__ __forceinline__ float maskf(const void* m, int mm, int idx) {
    if (mm == 3) return ((const float*)m)[idx] != 0.f ? 1.f : 0.f;
    if (mm == 2) return ((const unsigned short*)m)[idx] ? 1.f : 0.f;
    if (mm == 1) return ((const unsigned char*)m)[idx] ? 1.f : 0.f;
    return ((const int*)m)[idx] ? 1.f : 0.f;
}
__device__ __forceinline__ int typf(const void* p, int tm, int idx) {
    int v;
    if (tm == 2) v = (int)bf2f(((const unsigned short*)p)[idx]);
    else if (tm == 1) v = (int)((const long long*)p)[idx];
    else v = ((const int*)p)[idx];
    return v < 0 ? 0 : (v > NT_ - 1 ? NT_ - 1 : v);
}

__global__ __launch_bounds__(64) void detect_k(const unsigned int* __restrict__ px,
                                               const unsigned int* __restrict__ pm,
                                               const unsigned int* __restrict__ pt,
                                               int* __restrict__ flags)
{
    const int t = threadIdx.x;
    int hit = 0;
    for (int i = t; i < 4096; i += 64) {
        unsigned e = (px[i] >> 7) & 0xFFu;
        hit += (e >= 110 && e <= 132) ? 1 : 0;
    }
    for (int s = 1; s < 64; s <<= 1) hit += __shfl_xor(hit, s);

    unsigned big = 0, lo3f = 0, hi3f = 0;
    for (int i = t; i < 1024; i += 64) {
        unsigned wv = pm[i];
        big  |= (wv > 1u) ? 1u : 0u;
        lo3f |= ((wv & 0xFFFFu) == 0x3F80u) ? 1u : 0u;
        hi3f |= ((wv >> 16) == 0x3F80u) ? 1u : 0u;
    }
    unsigned long long aBig = __ballot(big != 0), aLo = __ballot(lo3f != 0), aHi = __ballot(hi3f != 0);

    unsigned tbig = 0, oddnz = 0;
    for (int i = t; i < 512; i += 64) {
        unsigned we = pt[2 * i], wo = pt[2 * i + 1];
        tbig  |= (we > 0xFFFFu || wo > 0xFFFFu) ? 1u : 0u;
        oddnz |= (wo != 0u) ? 1u : 0u;
    }
    unsigned long long aTb = __ballot(tbig != 0), aOdd = __ballot(oddnz != 0);

    if (t == 0) {
        flags[1] = (hit > 2048) ? 1 : 0;
        flags[0] = aLo ? 2 : (aHi ? 3 : (aBig ? 1 : 0));
        flags[2] = aTb ? 2 : (!aOdd ? 1 : 0);
    }
}

// ---------------- weight transpose prep ----------------
template<int BF> __device__ __forceinline__ void wt_prep_body(
    const void* w1, const void* w2, const void* sw2,
    const void* proj, const void* gw1, __hip_bfloat16* wt)
{
    const int idx = blockIdx.x * 256 + threadIdx.x;
    const int stride = gridDim.x * 256;
    for (int i = idx; i < 128 * 192; i += stride) {
        int n = i / 192, k = i - n * 192;
        wt[n * 192 + k] = __float2bfloat16(ldf<BF>(w1, k * 128 + n));
    }
    __hip_bfloat16* w2c = wt + 24576;
    for (int i = idx; i < 128 * 256; i += stride) {
        int n = i >> 8, k = i & 255;
        float v = (k < 128) ? ldf<BF>(w2, k * 128 + n) : ldf<BF>(sw2, (k - 128) * 128 + n);
        w2c[n * 256 + k] = __float2bfloat16(v);
    }
    __hip_bfloat16* pjt = wt + 57344;
    for (int i = idx; i < 128 * 128; i += stride) {
        int n = i >> 7, k = i & 127;
        pjt[n * 128 + k] = __float2bfloat16(ldf<BF>(proj, k * 128 + n));
    }
    __hip_bfloat16* g1t = wt + 73728;
    for (int i = idx; i < 128 * 128; i += stride) {
        int n = i >> 7, k = i & 127;
        g1t[n * 128 + k] = __float2bfloat16(ldf<BF>(gw1, k * 128 + n));
    }
}

__global__ __launch_bounds__(256) void wt_prep_k(
    const void* w1, const void* w2, const void* sw2,
    const void* proj, const void* gw1, __hip_bfloat16* wt, const int* flags)
{
    if (flags[1]) wt_prep_body<1>(w1, w2, sw2, proj, gw1, wt);
    else          wt_prep_body<0>(w1, w2, sw2, proj, gw1, wt);
}

// ---------------- encode L ----------------
#define RL 8
template<int BF> __device__ __forceinline__ void enc_l_body(
    const void* l_x, const void* l_typ, int tm,
    const void* w1, const void* b1, const void* w2, const void* b2,
    const void* lng, const void* lnb, const void* emb, const void* proj,
    const void* dustv, __hip_bfloat16* hLb, float* dust)
{
    __shared__ __align__(16) float X[RL * 8];
    __shared__ __align__(16) float H[RL][D_];
    __shared__ __align__(16) float Y[RL][D_];
    __shared__ float mus[RL], rss[RL];
    const int o = threadIdx.x;
    const int base = blockIdx.x * RL;

    if (o < RL * 8) X[o] = ldf<BF>(l_x, base * 8 + o);
    __syncthreads();

    float acc[RL];
    const float b1o = ldf<BF>(b1, o);
#pragma unroll
    for (int r = 0; r < RL; r++) acc[r] = b1o;
#pragma unroll
    for (int i = 0; i < 8; i += 4) {
        float wa = ldf<BF>(w1, (i + 0) * D_ + o), wb = ldf<BF>(w1, (i + 1) * D_ + o);
        float wc = ldf<BF>(w1, (i + 2) * D_ + o), wd = ldf<BF>(w1, (i + 3) * D_ + o);
#pragma unroll
        for (int r = 0; r < RL; r++) {
            const float4 x4 = *(const float4*)&X[r * 8 + i];
            acc[r] = fmaf(x4.x, wa, fmaf(x4.y, wb, fmaf(x4.z, wc, fmaf(x4.w, wd, acc[r]))));
        }
    }
#pragma unroll
    for (int r = 0; r < RL; r++) H[r][o] = gelu_(acc[r]);
    __syncthreads();

#pragma unroll
    for (int r = 0; r < RL; r++) {
        int tt = typf(l_typ, tm, base + r);
        acc[r] = ldf<BF>(b2, o) + ldf<BF>(emb, tt * D_ + o);
    }
    for (int i = 0; i < D_; i += 4) {
        float wa = ldf<BF>(w2, (i + 0) * D_ + o), wb = ldf<BF>(w2, (i + 1) * D_ + o);
        float wc = ldf<BF>(w2, (i + 2) * D_ + o), wd = ldf<BF>(w2, (i + 3) * D_ + o);
#pragma unroll
        for (int r = 0; r < RL; r++) {
            const float4 h4 = *(const float4*)&H[r][i];
            acc[r] = fmaf(h4.x, wa, fmaf(h4.y, wb, fmaf(h4.z, wc, fmaf(h4.w, wd, acc[r]))));
        }
    }
#pragma unroll
    for (int r = 0; r < RL; r++) Y[r][o] = acc[r];
    __syncthreads();

    {
        const int r = o >> 4, j = o & 15;
        float s = 0.f;
#pragma unroll
        for (int i = 0; i < 8; i++) s += Y[r][j * 8 + i];
        s += __shfl_xor(s, 1); s += __shfl_xor(s, 2); s += __shfl_xor(s, 4); s += __shfl_xor(s, 8);
        const float mu = s * (1.f / 128.f);
        float v = 0.f;
#pragma unroll
        for (int i = 0; i < 8; i++) { float d = Y[r][j * 8 + i] - mu; v = fmaf(d, d, v); }
        v += __shfl_xor(v, 1); v += __shfl_xor(v, 2); v += __shfl_xor(v, 4); v += __shfl_xor(v, 8);
        if (j == 0) { mus[r] = mu; rss[r] = rsqrtf(v * (1.f / 128.f) + 1e-5f); }
    }
    __syncthreads();
    {
        const float g = ldf<BF>(lng, o), bl = ldf<BF>(lnb, o);
#pragma unroll
        for (int r = 0; r < RL; r++) Y[r][o] = fmaf((Y[r][o] - mus[r]) * rss[r], g, bl);
    }
    __syncthreads();

#pragma unroll
    for (int r = 0; r < RL; r++) acc[r] = 0.f;
    for (int i = 0; i < D_; i += 4) {
        float wa = ldf<BF>(proj, (i + 0) * D_ + o), wb = ldf<BF>(proj, (i + 1) * D_ + o);
        float wc = ldf<BF>(proj, (i + 2) * D_ + o), wd = ldf<BF>(proj, (i + 3) * D_ + o);
#pragma unroll
        for (int r = 0; r < RL; r++) {
            const float4 y4 = *(const float4*)&Y[r][i];
            acc[r] = fmaf(y4.x, wa, fmaf(y4.y, wb, fmaf(y4.z, wc, fmaf(y4.w, wd, acc[r]))));
        }
    }
    const float dvo = ldf<BF>(dustv, o);
#pragma unroll
    for (int r = 0; r < RL; r++) {
        hLb[(size_t)(base + r) * D_ + o] = __float2bfloat16(acc[r]);
        H[r][o] = acc[r] * dvo;
    }
    __syncthreads();
    {
        const int r = o >> 4, j = o & 15;
        float s = 0.f;
#pragma unroll
        for (int i = 0; i < 8; i++) s += H[r][j * 8 + i];
        s += __shfl_xor(s, 1); s += __shfl_xor(s, 2); s += __shfl_xor(s, 4); s += __shfl_xor(s, 8);
        if (j == 0) dust[base + r] = s * SCALE_;
    }
}

__global__ __launch_bounds__(128) void enc_l_k(
    const void* l_x, const void* l_typ,
    const void* w1, const void* b1, const void* w2, const void* b2,
    const void* lng, const void* lnb, const void* emb, const void* proj,
    const void* dustv, __hip_bfloat16* hLb, float* dust, const int* flags)
{
    const int tm = flags[2];
    if (flags[1]) enc_l_body<1>(l_x, l_typ, tm, w1, b1, w2, b2, lng, lnb, emb, proj, dustv, hLb, dust);
    else          enc_l_body<0>(l_x, l_typ, tm, w1, b1, w2, b2, lng, lnb, emb, proj, dustv, hLb, dust);
}

// ---------------- encode P (MFMA, in-register epilogues) ----------------
#define XS 264
#define ROWS 32
#define ENC_P_SMEM 18304
template<int BF> __device__ __forceinline__ void enc_p_body(
    unsigned short* X, float* red1, float* red2, float* pm_s, float* sc_s, int* tt_s,
    const void* p_x, const void* p_typ, int tm,
    const void* p_score, const void* p_rad,
    const void* b1, const void* b2, const void* sb2,
    const void* sw1, const void* sb1,
    const void* lng, const void* lnb, const void* emb,
    const void* gb1, const void* gw2, const void* gb2,
    const unsigned short* wt, const void* p_mask, int mm,
    void* out, __hip_bfloat16* hPb, float* ppart, float* pcnt)
{
    const int t = threadIdx.x;
    const int o = t & 127, rh = t >> 7;
    const int lane = t & 63, w = t >> 6;
    const int m = lane & 15, g = lane >> 4;
    const int b = blockIdx.x >> 5, tile = blockIdx.x & 31;
    const int base = b * P_ + tile * ROWS;
    const int c0 = 32 * w + m, c1 = 32 * w + 16 + m;
    __hip_bfloat16* Xb = (__hip_bfloat16*)X;

    for (int i = t; i < ROWS * 192; i += 256) {
        int r = i / 192, k = i - r * 192;
        Xb[r * XS + k] = __float2bfloat16(ldf<BF>(p_x, (base + r) * 192 + k));
    }
    if (t < ROWS) {
        pm_s[t] = maskf(p_mask, mm, base + t);
        sc_s[t] = ldf<BF>(p_score, base + t);
        tt_s[t] = typf(p_typ, tm, base + t);
    }
    __syncthreads();

    // GEMM1: X[32x192] @ w1
    fx4 A1[2][2];
#pragma unroll
    for (int mt = 0; mt < 2; mt++) { A1[mt][0] = fx4{0,0,0,0}; A1[mt][1] = fx4{0,0,0,0}; }
    {
        const unsigned short* w1T = wt;
        bh8 bf[12];
#pragma unroll
        for (int ks = 0; ks < 6; ks++) {
            bf[ks * 2 + 0] = *(const bh8*)(w1T + ((2 * w + 0) * 16 + m) * 192 + g * 8 + ks * 32);
            bf[ks * 2 + 1] = *(const bh8*)(w1T + ((2 * w + 1) * 16 + m) * 192 + g * 8 + ks * 32);
        }
#pragma unroll
        for (int mt = 0; mt < 2; mt++) {
            const unsigned short* xr = X + (mt * 16 + m) * XS + g * 8;
#pragma unroll
            for (int ks = 0; ks < 6; ks++) {
                bh8 a = *(const bh8*)(xr + ks * 32);
                A1[mt][0] = __builtin_amdgcn_mfma_f32_16x16x32_bf16(a, bf[ks * 2 + 0], A1[mt][0], 0, 0, 0);
                A1[mt][1] = __builtin_amdgcn_mfma_f32_16x16x32_bf16(a, bf[ks * 2 + 1], A1[mt][1], 0, 0, 0);
            }
        }
    }
    __syncthreads();

    // ep1: h1 = gelu(D + b1) -> X[:,0:128]; hs -> X[:,128:256]
    {
        const float bb0 = ldf<BF>(b1, c0), bb1 = ldf<BF>(b1, c1);
#pragma unroll
        for (int mt = 0; mt < 2; mt++)
#pragma unroll
            for (int j = 0; j < 4; j++) {
                const int row = mt * 16 + g * 4 + j;
                Xb[row * XS + c0] = __float2bfloat16(gelu_(A1[mt][0][j] + bb0));
                Xb[row * XS + c1] = __float2bfloat16(gelu_(A1[mt][1][j] + bb1));
            }
    }
    {
        const float a1v = ldf<BF>(sw1, o), a0v = ldf<BF>(sb1, o);
#pragma unroll
        for (int r = 0; r < 16; r++) {
            const int row = rh * 16 + r;
            Xb[row * XS + 128 + o] = __float2bfloat16(gelu_(fmaf(sc_s[row], a1v, a0v)));
        }
    }
    __syncthreads();

    // GEMM2: [h1|hs][32x256] @ w2c
    fx4 A2[2][2];
#pragma unroll
    for (int mt = 0; mt < 2; mt++) { A2[mt][0] = fx4{0,0,0,0}; A2[mt][1] = fx4{0,0,0,0}; }
    {
        const unsigned short* w2cT = wt + 24576;
        bh8 bf[16];
#pragma unroll
        for (int ks = 0; ks < 8; ks++) {
            bf[ks * 2 + 0] = *(const bh8*)(w2cT + ((2 * w + 0) * 16 + m) * 256 + g * 8 + ks * 32);
            bf[ks * 2 + 1] = *(const bh8*)(w2cT + ((2 * w + 1) * 16 + m) * 256 + g * 8 + ks * 32);
        }
#pragma unroll
        for (int mt = 0; mt < 2; mt++) {
            const unsigned short* xr = X + (mt * 16 + m) * XS + g * 8;
#pragma unroll
            for (int ks = 0; ks < 8; ks++) {
                bh8 a = *(const bh8*)(xr + ks * 32);
                A2[mt][0] = __builtin_amdgcn_mfma_f32_16x16x32_bf16(a, bf[ks * 2 + 0], A2[mt][0], 0, 0, 0);
                A2[mt][1] = __builtin_amdgcn_mfma_f32_16x16x32_bf16(a, bf[ks * 2 + 1], A2[mt][1], 0, 0, 0);
            }
        }
    }
    // ep2: h2 = D + b2 + sb2 + emb[typ]
    {
        const float bc0 = ldf<BF>(b2, c0) + ldf<BF>(sb2, c0);
        const float bc1 = ldf<BF>(b2, c1) + ldf<BF>(sb2, c1);
#pragma unroll
        for (int mt = 0; mt < 2; mt++)
#pragma unroll
            for (int j = 0; j < 4; j++) {
                const int row = mt * 16 + g * 4 + j;
                const int tt = tt_s[row];
                A2[mt][0][j] += bc0 + ldf<BF>(emb, tt * D_ + c0);
                A2[mt][1][j] += bc1 + ldf<BF>(emb, tt * D_ + c1);
            }
    }
    // LN mean partials
#pragma unroll
    for (int mt = 0; mt < 2; mt++)
#pragma unroll
        for (int j = 0; j < 4; j++) {
            float s = A2[mt][0][j] + A2[mt][1][j];
            s += __shfl_xor(s, 1); s += __shfl_xor(s, 2); s += __shfl_xor(s, 4); s += __shfl_xor(s, 8);
            if (m == 0) red1[(mt * 16 + g * 4 + j) * 4 + w] = s;
        }
    __syncthreads();
    float mu_[2][4];
#pragma unroll
    for (int mt = 0; mt < 2; mt++)
#pragma unroll
        for (int j = 0; j < 4; j++) {
            const int row = mt * 16 + g * 4 + j;
            mu_[mt][j] = ((red1[row * 4 + 0] + red1[row * 4 + 1]) +
                          (red1[row * 4 + 2] + red1[row * 4 + 3])) * (1.f / 128.f);
            float d0 = A2[mt][0][j] - mu_[mt][j];
            float d1 = A2[mt][1][j] - mu_[mt][j];
            float v = fmaf(d0, d0, d1 * d1);
            v += __shfl_xor(v, 1); v += __shfl_xor(v, 2); v += __shfl_xor(v, 4); v += __shfl_xor(v, 8);
            if (m == 0) red2[row * 4 + w] = v;
        }
    __syncthreads();
    // LN apply -> X bf16
    {
        const float gc0 = ldf<BF>(lng, c0), bl0 = ldf<BF>(lnb, c0);
        const float gc1 = ldf<BF>(lng, c1), bl1 = ldf<BF>(lnb, c1);
#pragma unroll
        for (int mt = 0; mt < 2; mt++)
#pragma unroll
            for (int j = 0; j < 4; j++) {
                const int row = mt * 16 + g * 4 + j;
                float var = ((red2[row * 4 + 0] + red2[row * 4 + 1]) +
                             (red2[row * 4 + 2] + red2[row * 4 + 3])) * (1.f / 128.f);
                float rs = rsqrtf(var + 1e-5f);
                float y0 = fmaf((A2[mt][0][j] - mu_[mt][j]) * rs, gc0, bl0);
                float y1 = fmaf((A2[mt][1][j] - mu_[mt][j]) * rs, gc1, bl1);
                Xb[row * XS + c0] = __float2bfloat16(y0);
                Xb[row * XS + c1] = __float2bfloat16(y1);
            }
    }
    __syncthreads();

    // GEMM3: hp = y[32x128] @ proj
    fx4 A3[2][2];
#pragma unroll
    for (int mt = 0; mt < 2; mt++) { A3[mt][0] = fx4{0,0,0,0}; A3[mt][1] = fx4{0,0,0,0}; }
    {
        const unsigned short* pjT = wt + 57344;
        bh8 bf[8];
#pragma unroll
        for (int ks = 0; ks < 4; ks++) {
            bf[ks * 2 + 0] = *(const bh8*)(pjT + ((2 * w + 0) * 16 + m) * 128 + g * 8 + ks * 32);
            bf[ks * 2 + 1] = *(const bh8*)(pjT + ((2 * w + 1) * 16 + m) * 128 + g * 8 + ks * 32);
        }
#pragma unroll
        for (int mt = 0; mt < 2; mt++) {
            const unsigned short* xr = X + (mt * 16 + m) * XS + g * 8;
#pragma unroll
            for (int ks = 0; ks < 4; ks++) {
                bh8 a = *(const bh8*)(xr + ks * 32);
                A3[mt][0] = __builtin_amdgcn_mfma_f32_16x16x32_bf16(a, bf[ks * 2 + 0], A3[mt][0], 0, 0, 0);
                A3[mt][1] = __builtin_amdgcn_mfma_f32_16x16x32_bf16(a, bf[ks * 2 + 1], A3[mt][1], 0, 0, 0);
            }
        }
    }
    __syncthreads();

    // ep3: hPb store + X <- hp bf16 + in-reg pool partials
    {
#pragma unroll
        for (int mt = 0; mt < 2; mt++)
#pragma unroll
            for (int j = 0; j < 4; j++) {
                const int row = mt * 16 + g * 4 + j;
                __hip_bfloat16 h0 = __float2bfloat16(A3[mt][0][j]);
                __hip_bfloat16 h1 = __float2bfloat16(A3[mt][1][j]);
                hPb[(size_t)(base + row) * D_ + c0] = h0;
                hPb[(size_t)(base + row) * D_ + c1] = h1;
                Xb[row * XS + c0] = h0;
                Xb[row * XS + c1] = h1;
            }
        float ps0 = 0.f, ps1 = 0.f;
#pragma unroll
        for (int mt = 0; mt < 2; mt++)
#pragma unroll
            for (int j = 0; j < 4; j++) {
                const int row = mt * 16 + g * 4 + j;
                ps0 = fmaf(A3[mt][0][j], pm_s[row], ps0);
                ps1 = fmaf(A3[mt][1][j], pm_s[row], ps1);
            }
        ps0 += __shfl_xor(ps0, 16); ps0 += __shfl_xor(ps0, 32);
        ps1 += __shfl_xor(ps1, 16); ps1 += __shfl_xor(ps1, 32);
        if (g == 0) {
            ppart[(size_t)blockIdx.x * D_ + c0] = ps0;
            ppart[(size_t)blockIdx.x * D_ + c1] = ps1;
        }
        if (t == 0) {
            float c = 0.f;
#pragma unroll
            for (int r = 0; r < ROWS; r++) c += pm_s[r];
            pcnt[blockIdx.x] = c;
        }
    }
    __syncthreads();

    // GEMM4: g1raw = hp[32x128] @ gw1
    fx4 A4[2][2];
#pragma unroll
    for (int mt = 0; mt < 2; mt++) { A4[mt][0] = fx4{0,0,0,0}; A4[mt][1] = fx4{0,0,0,0}; }
    {
        const unsigned short* g1T = wt + 73728;
        bh8 bf[8];
#pragma unroll
        for (int ks = 0; ks < 4; ks++) {
            bf[ks * 2 + 0] = *(const bh8*)(g1T + ((2 * w + 0) * 16 + m) * 128 + g * 8 + ks * 32);
            bf[ks * 2 + 1] = *(const bh8*)(g1T + ((2 * w + 1) * 16 + m) * 128 + g * 8 + ks * 32);
        }
#pragma unroll
        for (int mt = 0; mt < 2; mt++) {
            const unsigned short* xr = X + (mt * 16 + m) * XS + g * 8;
#pragma unroll
            for (int ks = 0; ks < 4; ks++) {
                bh8 a = *(const bh8*)(xr + ks * 32);
                A4[mt][0] = __builtin_amdgcn_mfma_f32_16x16x32_bf16(a, bf[ks * 2 + 0], A4[mt][0], 0, 0, 0);
                A4[mt][1] = __builtin_amdgcn_mfma_f32_16x16x32_bf16(a, bf[ks * 2 + 1], A4[mt][1], 0, 0, 0);
            }
        }
    }
    // ep4: g1 = gelu(D+gb1); sigma dot partials
    {
        const float gb0 = ldf<BF>(gb1, c0), gb1v = ldf<BF>(gb1, c1);
        const float w20 = ldf<BF>(gw2, c0), w21 = ldf<BF>(gw2, c1);
#pragma unroll
        for (int mt = 0; mt < 2; mt++)
#pragma unroll
            for (int j = 0; j < 4; j++) {
                const int row = mt * 16 + g * 4 + j;
                float g0 = gelu_(A4[mt][0][j] + gb0);
                float g1v = gelu_(A4[mt][1][j] + gb1v);
                float p = fmaf(g0, w20, g1v * w21);
                p += __shfl_xor(p, 1); p += __shfl_xor(p, 2); p += __shfl_xor(p, 4); p += __shfl_xor(p, 8);
                if (m == 0) red1[row * 4 + w] = p;
            }
    }
    __syncthreads();
    if (t < ROWS) {
        float s = (red1[t * 4 + 0] + red1[t * 4 + 1]) + (red1[t * 4 + 2] + red1[t * 4 + 3]);
        float v = s + ldf<BF>(gb2, 0);
        float sp = fmaxf(v, 0.f) + log1pf(expf(-fabsf(v)));
        stf<BF>(out, (size_t)OUT_SIG + base + t, sp + 1e-3f + fmaxf(ldf<BF>(p_rad, base + t), 0.f));
    }
}

__global__ __launch_bounds__(256) void enc_p_k(
    const void* p_x, const void* p_typ, const void* p_score, const void* p_rad,
    const void* b1, const void* b2, const void* sb2,
    const void* sw1, const void* sb1,
    const void* lng, const void* lnb, const void* emb,
    const void* gb1, const void* gw2, const void* gb2,
    const unsigned short* wt, const void* p_mask, const int* flags,
    void* out, __hip_bfloat16* hPb, float* ppart, float* pcnt)
{
    extern __shared__ __align__(16) char smem[];
    unsigned short* X = (unsigned short*)smem;
    float* red1 = (float*)(smem + 16896);
    float* red2 = (float*)(smem + 17408);
    float* pm_s = (float*)(smem + 17920);
    float* sc_s = (float*)(smem + 18048);
    int*   tt_s = (int*)(smem + 18176);
    const int tm = flags[2], mm = flags[0];
    if (flags[1]) enc_p_body<1>(X, red1, red2, pm_s, sc_s, tt_s,
                                p_x, p_typ, tm, p_score, p_rad, b1, b2, sb2, sw1, sb1,
                                lng, lnb, emb, gb1, gw2, gb2, wt, p_mask, mm,
                                out, hPb, ppart, pcnt);
    else          enc_p_body<0>(X, red1, red2, pm_s, sc_s, tt_s,
                                p_x, p_typ, tm, p_score, p_rad, b1, b2, sb2, sw1, sb1,
                                lng, lnb, emb, gb1, gw2, gb2, wt, p_mask, mm,
                                out, hPb, ppart, pcnt);
}

// ---------------- logits (MFMA) + fused softmax + sharp/ent ----------------
template<int BF> __device__ __forceinline__ void logits_sm_body(
    const unsigned short* hLb, const unsigned short* hPb, const float* dust,
    const void* l_mask, const void* p_mask, int mm,
    void* out, float* sharp_parts, float* ent_parts)
{
    __shared__ float pm_s[1024];
    __shared__ float lm_s[16], dv_s[16];
    __shared__ float redA[64], redB[64], redC[64], redD[64], redM[16], redL[16];
    const int t = threadIdx.x;
    const int lane = t & 63, w = t >> 6;
    const int m = lane & 15, g = lane >> 4;
    const int b = blockIdx.x & 127, l0 = (blockIdx.x >> 7) * 16;

    for (int i = t; i < 1024; i += 256) pm_s[i] = maskf(p_mask, mm, b * P_ + i);
    if (t < 16) {
        lm_s[t] = maskf(l_mask, mm, b * L_ + l0 + t);
        dv_s[t] = dust[b * L_ + l0 + t];
    }
    __syncthreads();

    bh8 af[4];
    {
        const unsigned short* ha = hLb + ((size_t)(b * L_ + l0 + m)) * D_ + g * 8;
#pragma unroll
        for (int ks = 0; ks < 4; ks++) af[ks] = *(const bh8*)(ha + ks * 32);
    }
    const unsigned short* hpb = hPb + ((size_t)(b * P_ + w * 256)) * D_;

    fx4 acc[16];
#pragma unroll
    for (int nt = 0; nt < 16; nt++) {
        fx4 c = {0.f, 0.f, 0.f, 0.f};
        const unsigned short* hr = hpb + (nt * 16 + m) * D_ + g * 8;
#pragma unroll
        for (int ks = 0; ks < 4; ks++) {
            bh8 bfr = *(const bh8*)(hr + ks * 32);
            c = __builtin_amdgcn_mfma_f32_16x16x32_bf16(af[ks], bfr, c, 0, 0, 0);
        }
        acc[nt] = c;
    }

    float rmax[4] = {NEGF, NEGF, NEGF, NEGF};
#pragma unroll
    for (int nt = 0; nt < 16; nt++) {
        const float pv = pm_s[w * 256 + nt * 16 + m];
#pragma unroll
        for (int j = 0; j < 4; j++) {
            const bool ok = (lm_s[g * 4 + j] != 0.f) && (pv != 0.f);
            float v = ok ? acc[nt][j] * SCALE_ : NEGF;
            acc[nt][j] = v;
            rmax[j] = fmaxf(rmax[j], v);
        }
    }
#pragma unroll
    for (int j = 0; j < 4; j++) {
        rmax[j] = fmaxf(rmax[j], __shfl_xor(rmax[j], 1));
        rmax[j] = fmaxf(rmax[j], __shfl_xor(rmax[j], 2));
        rmax[j] = fmaxf(rmax[j], __shfl_xor(rmax[j], 4));
        rmax[j] = fmaxf(rmax[j], __shfl_xor(rmax[j], 8));
    }
    if (m == 0) {
#pragma unroll
        for (int j = 0; j < 4; j++) redA[(g * 4 + j) * 4 + w] = rmax[j];
    }
    __syncthreads();
    float mrow[4], lse[4];
#pragma unroll
    for (int j = 0; j < 4; j++) {
        const int r = g * 4 + j;
        float mm4 = fmaxf(fmaxf(redA[r * 4 + 0], redA[r * 4 + 1]), fmaxf(redA[r * 4 + 2], redA[r * 4 + 3]));
        float dvr = (lm_s[r] != 0.f) ? dv_s[r] : NEGF;
        mrow[j] = fmaxf(mm4, dvr);
    }
    float se[4] = {0.f, 0.f, 0.f, 0.f};
#pragma unroll
    for (int nt = 0; nt < 16; nt++) {
#pragma unroll
        for (int j = 0; j < 4; j++) se[j] += __expf(acc[nt][j] - mrow[j]);
    }
#pragma unroll
    for (int j = 0; j < 4; j++) {
        se[j] += __shfl_xor(se[j], 1); se[j] += __shfl_xor(se[j], 2);
        se[j] += __shfl_xor(se[j], 4); se[j] += __shfl_xor(se[j], 8);
    }
    if (m == 0) {
#pragma unroll
        for (int j = 0; j < 4; j++) redB[(g * 4 + j) * 4 + w] = se[j];
    }
    __syncthreads();
#pragma unroll
    for (int j = 0; j < 4; j++) {
        const int r = g * 4 + j;
        float dvr = (lm_s[r] != 0.f) ? dv_s[r] : NEGF;
        float s = (redB[r * 4 + 0] + redB[r * 4 + 1]) + (redB[r * 4 + 2] + redB[r * 4 + 3]);
        s += __expf(dvr - mrow[j]);
        lse[j] = __logf(s);
    }
    if (w == 0 && m == 0) {
#pragma unroll
        for (int j = 0; j < 4; j++) { redM[g * 4 + j] = mrow[j]; redL[g * 4 + j] = lse[j]; }
    }
    float mw[4] = {0.f, 0.f, 0.f, 0.f}, es[4] = {0.f, 0.f, 0.f, 0.f};
#pragma unroll
    for (int nt = 0; nt < 16; nt++) {
        const float pv = pm_s[w * 256 + nt * 16 + m];
#pragma unroll
        for (int j = 0; j < 4; j++) {
            float lw = acc[nt][j] - mrow[j] - lse[j];
            stf<BF>(out, (size_t)(b * L_ + l0 + g * 4 + j) * (P_ + 1) + w * 256 + nt * 16 + m, lw);
            float lwc = fmaxf(lw, -CLAMPV);
            float wm = __expf(lwc) * pv;
            mw[j] = fmaxf(mw[j], wm);
            if (wm > 0.f) es[j] = fmaf(-wm, lwc, es[j]);
        }
    }
#pragma unroll
    for (int j = 0; j < 4; j++) {
        mw[j] = fmaxf(mw[j], __shfl_xor(mw[j], 1));
        mw[j] = fmaxf(mw[j], __shfl_xor(mw[j], 2));
        mw[j] = fmaxf(mw[j], __shfl_xor(mw[j], 4));
        mw[j] = fmaxf(mw[j], __shfl_xor(mw[j], 8));
        es[j] += __shfl_xor(es[j], 1); es[j] += __shfl_xor(es[j], 2);
        es[j] += __shfl_xor(es[j], 4); es[j] += __shfl_xor(es[j], 8);
    }
    if (m == 0) {
#pragma unroll
        for (int j = 0; j < 4; j++) {
            redC[(g * 4 + j) * 4 + w] = mw[j];
            redD[(g * 4 + j) * 4 + w] = es[j];
        }
    }
    __syncthreads();
    if (t < 16) {
        float dvr = (lm_s[t] != 0.f) ? dv_s[t] : NEGF;
        stf<BF>(out, (size_t)(b * L_ + l0 + t) * (P_ + 1) + P_, dvr - redM[t] - redL[t]);
    }
    if (t == 0) {
        float sp = 0.f, en = 0.f;
        for (int r = 0; r < 16; r++) {
            float dvr = (lm_s[r] != 0.f) ? dv_s[r] : NEGF;
            float lwd = fmaxf(dvr - redM[r] - redL[r], -CLAMPV);
            float wd = __expf(lwd);
            float mwr = fmaxf(fmaxf(redC[r * 4 + 0], redC[r * 4 + 1]), fmaxf(redC[r * 4 + 2], redC[r * 4 + 3]));
            mwr = fmaxf(mwr, wd);
            float esr = (redD[r * 4 + 0] + redD[r * 4 + 1]) + (redD[r * 4 + 2] + redD[r * 4 + 3]);
            if (wd > 0.f) esr = fmaf(-wd, lwd, esr);
            sp = fmaf(mwr, lm_s[r], sp);
            en = fmaf(esr, lm_s[r], en);
        }
        sharp_parts[blockIdx.x] = sp;
        ent_parts[blockIdx.x] = en;
    }
}

__global__ __launch_bounds__(256) void logits_sm_k(
    const unsigned short* hLb, const unsigned short* hPb, const float* dust,
    const void* l_mask, const void* p_mask, const int* flags,
    void* out, float* sharp_parts, float* ent_parts)
{
    const int mm = flags[0];
    if (flags[1]) logits_sm_body<1>(hLb, hPb, dust, l_mask, p_mask, mm, out, sharp_parts, ent_parts);
    else          logits_sm_body<0>(hLb, hPb, dust, l_mask, p_mask, mm, out, sharp_parts, ent_parts);
}

// ---------------- epilogue: pool_l + pool_p + finalize in one kernel ----------------
template<int BF> __device__ __forceinline__ void epilogue_body(
    const unsigned short* hLb, const void* l_mask, int mm,
    const void* retr_l, const void* retr_p,
    const float* ppart, const float* pcnt,
    const float* sharp_parts, const float* ent_parts, void* out)
{
    __shared__ float lmv[L_];
    __shared__ __align__(16) float lg[D_];
    __shared__ __align__(16) float pgs[D_];
    __shared__ float red[4];
    const int o = threadIdx.x, b = blockIdx.x;
    lmv[o] = maskf(l_mask, mm, b * L_ + o);
    __syncthreads();
    float cnt = 0.f;
    for (int l = 0; l < L_; l++) cnt += lmv[l];
    // pool L
    {
        float s0 = 0, s1 = 0, s2 = 0, s3 = 0;
        const unsigned short* hb = hLb + (size_t)b * L_ * D_;
        for (int l = 0; l < L_; l += 4) {
            s0 = fmaf(bf2f(hb[(l + 0) * D_ + o]), lmv[l + 0], s0);
            s1 = fmaf(bf2f(hb[(l + 1) * D_ + o]), lmv[l + 1], s1);
            s2 = fmaf(bf2f(hb[(l + 2) * D_ + o]), lmv[l + 2], s2);
            s3 = fmaf(bf2f(hb[(l + 3) * D_ + o]), lmv[l + 3], s3);
        }
        lg[o] = ((s0 + s1) + (s2 + s3)) / fmaxf(cnt, 1.f);
    }
    // pool P
    {
        float s = 0.f, c = 0.f;
        for (int k = 0; k < 32; k++) s += ppart[(size_t)(b * 32 + k) * D_ + o];
        for (int k = 0; k < 32; k++) c += pcnt[b * 32 + k];
        pgs[o] = s / fmaxf(c, 1.f);
    }
    __syncthreads();
    // retr matvecs + l2norms
    float rL = 0.f, rP = 0.f;
    for (int i = 0; i < D_; i += 4) {
        const float4 g4 = *(const float4*)&lg[i];
        rL = fmaf(g4.x, ldf<BF>(retr_l, (i + 0) * D_ + o), rL);
        rL = fmaf(g4.y, ldf<BF>(retr_l, (i + 1) * D_ + o), rL);
        rL = fmaf(g4.z, ldf<BF>(retr_l, (i + 2) * D_ + o), rL);
        rL = fmaf(g4.w, ldf<BF>(retr_l, (i + 3) * D_ + o), rL);
        const float4 p4 = *(const float4*)&pgs[i];
        rP = fmaf(p4.x, ldf<BF>(retr_p, (i + 0) * D_ + o), rP);
        rP = fmaf(p4.y, ldf<BF>(retr_p, (i + 1) * D_ + o), rP);
        rP = fmaf(p4.z, ldf<BF>(retr_p, (i + 2) * D_ + o), rP);
        rP = fmaf(p4.w, ldf<BF>(retr_p, (i + 3) * D_ + o), rP);
    }
    float nL = rL * rL, nP = rP * rP;
    nL += __shfl_xor(nL, 1); nL += __shfl_xor(nL, 2); nL += __shfl_xor(nL, 4);
    nL += __shfl_xor(nL, 8); nL += __shfl_xor(nL, 16); nL += __shfl_xor(nL, 32);
    nP += __shfl_xor(nP, 1); nP += __shfl_xor(nP, 2); nP += __shfl_xor(nP, 4);
    nP += __shfl_xor(nP, 8); nP += __shfl_xor(nP, 16); nP += __shfl_xor(nP, 32);
    if ((o & 63) == 0) { red[o >> 6] = nL; red[2 + (o >> 6)] = nP; }
    __syncthreads();
    {
        float nrmL = fmaxf(sqrtf(red[0] + red[1]), 1e-12f);
        float nrmP = fmaxf(sqrtf(red[2] + red[3]), 1e-12f);
        stf<BF>(out, (size_t)OUT_LZ + b * D_ + o, rL / nrmL);
        stf<BF>(out, (size_t)OUT_PZ + b * D_ + o, rP / nrmP);
    }
    if (o == 0) {
        const float den = fmaxf(cnt, 1.f);
        float sp = 0.f, en = 0.f;
        // logits_sm grid is b-minor: block index = l0t*128 + b
        for (int k = 0; k < 8; k++) { sp += sharp_parts[k * 128 + b]; en += ent_parts[k * 128 + b]; }
        stf<BF>(out, (size_t)OUT_SHARP + b, sp / den);
        stf<BF>(out, (size_t)OUT_NEGENT + b, -(en / den));
    }
}

__global__ __launch_bounds__(128) void epilogue_k(
    const unsigned short* hLb, const void* l_mask, const int* flags,
    const void* retr_l, const void* retr_p,
    const float* ppart, const float* pcnt,
    const float* sharp_parts, const float* ent_parts, void* out)
{
    const int mm = flags[0];
    if (flags[1]) epilogue_body<1>(hLb, l_mask, mm, retr_l, retr_p, ppart, pcnt, sharp_parts, ent_parts, out);
    else          epilogue_body<0>(hLb, l_mask, mm, retr_l, retr_p, ppart, pcnt, sharp_parts, ent_parts, out);
}

extern "C" void kernel_launch(void* const* d_in, const int* in_sizes, int n_in,
                              void* d_out, int out_size, void* d_ws, size_t ws_size,
                              hipStream_t stream)
{
    const void* l_x     = d_in[0];
    const void* l_typ   = d_in[1];
    const void* p_x     = d_in[2];
    const void* p_typ   = d_in[3];
    const void* p_score = d_in[4];
    const void* p_rad   = d_in[5];
    const void* l_mask  = d_in[6];
    const void* p_mask  = d_in[7];
    const void* lt_emb  = d_in[8];
    const void* lx_w1   = d_in[9];
    const void* lx_b1   = d_in[10];
    const void* lx_w2   = d_in[11];
    const void* lx_b2   = d_in[12];
    const void* l_ln_g  = d_in[13];
    const void* l_ln_b  = d_in[14];
    const void* pt_emb  = d_in[15];
    const void* px_w1   = d_in[16];
    const void* px_b1   = d_in[17];
    const void* px_w2   = d_in[18];
    const void* px_b2   = d_in[19];
    const void* ps_w1   = d_in[20];
    const void* ps_b1   = d_in[21];
    const void* ps_w2   = d_in[22];
    const void* ps_b2   = d_in[23];
    const void* p_ln_g  = d_in[24];
    const void* p_ln_b  = d_in[25];
    const void* proj_l  = d_in[26];
    const void* proj_p  = d_in[27];
    const void* dustv   = d_in[28];
    const void* sg_w1   = d_in[29];
    const void* sg_b1   = d_in[30];
    const void* sg_w2   = d_in[31];
    const void* sg_b2   = d_in[32];
    const void* retr_l  = d_in[33];
    const void* retr_p  = d_in[34];

    float* ws     = (float*)d_ws;
    __hip_bfloat16* hLb = (__hip_bfloat16*)(ws + WS_HLB);
    __hip_bfloat16* hPb = (__hip_bfloat16*)(ws + WS_HPB);
    float* dust   = ws + WS_DUST;
    float* sharpp = ws + WS_SHARPP;
    float* entp   = ws + WS_ENTP;
    int*   flags  = (int*)(ws + WS_FLAG);
    __hip_bfloat16* wt = (__hip_bfloat16*)(ws + WS_WT);
    float* ppart  = ws + WS_PPART;
    float* pcnt   = ws + WS_PCNT;

    detect_k<<<1, 64, 0, stream>>>((const unsigned int*)p_x, (const unsigned int*)p_mask,
                                   (const unsigned int*)p_typ, flags);
    wt_prep_k<<<64, 256, 0, stream>>>(px_w1, px_w2, ps_w2, proj_p, sg_w1, wt, flags);
    enc_l_k<<<(B_ * L_) / RL, 128, 0, stream>>>(l_x, l_typ, lx_w1, lx_b1, lx_w2, lx_b2,
                                                l_ln_g, l_ln_b, lt_emb, proj_l, dustv,
                                                hLb, dust, flags);
    enc_p_k<<<B_ * (P_ / ROWS), 256, ENC_P_SMEM, stream>>>(
        p_x, p_typ, p_score, p_rad,
        px_b1, px_b2, ps_b2, ps_w1, ps_b1,
        p_ln_g, p_ln_b, pt_emb,
        sg_b1, sg_w2, sg_b2,
        (const unsigned short*)wt, p_mask, flags,
        d_out, hPb, ppart, pcnt);
    logits_sm_k<<<B_ * 8, 256, 0, stream>>>((const unsigned short*)hLb, (const unsigned short*)hPb,
                                            dust, l_mask, p_mask, flags, d_out, sharpp, entp);
    epilogue_k<<<B_, 128, 0, stream>>>((const unsigned short*)hLb, l_mask, flags,
                                       retr_l, retr_p, ppart, pcnt, sharpp, entp, d_out);
}

// Round 11
// 211.219 us; speedup vs baseline: 11.7676x; 1.0441x over previous
//
#include <hip/hip_runtime.h>
#include <hip/hip_bf16.h>
#include <math.h>

// PharmMatchNetFast — round 11:
// (a) enc_p staging fast path: p_x already bf16 -> raw 16B vector copies into
//     LDS (was per-element u16->f32->bf16 round trip, ~100 VALU/thread).
// (b) enc_p 64 rows/block (4 M-tiles), ks-outer GEMM loops: each weight-frag
//     load feeds 8 MFMAs; weight traffic + barriers per row halved.
#define B_ 128
#define L_ 128
#define P_ 1024
#define D_ 128
#define NT_ 256

#define NEGF (-__FLT_MAX__)
#define SCALE_ 0.08838834764831845f
#define CLAMPV 1e30f

// output offsets (elements)
#define OUT_SHARP  16793600
#define OUT_NEGENT 16793728
#define OUT_LZ     16793856
#define OUT_PZ     16810240
#define OUT_SIG    16826624

// ws offsets (floats)
#define WS_HLB    0
#define WS_HPB    1048576
#define WS_DUST   9437184
#define WS_SHARPP 9453568
#define WS_ENTP   9454592
#define WS_FLAG   9455616
#define WS_WT     9455632
#define WS_PPART  9500696
#define WS_PCNT   10024984

using bh8  = __attribute__((ext_vector_type(8))) short;
using fx4  = __attribute__((ext_vector_type(4))) float;

__device__ __forceinline__ float gelu_(float x) {
    float c = x * x;
    float v = x * fmaf(c, 0.07135481584f, 1.5957691216f);
    return x * __builtin_amdgcn_rcpf(1.0f + __expf(-v));
}
__device__ __forceinline__ float bf2f(unsigned short u) {
    return __uint_as_float(((unsigned)u) << 16);
}
__device__ __forceinline__ float sanz(float x) {
    return fminf(fmaxf(x, -CLAMPV), CLAMPV);
}
template<int BF> __device__ __forceinline__ float ldf(const void* p, int i) {
    if constexpr (BF) return bf2f(((const unsigned short*)p)[i]);
    else return ((const float*)p)[i];
}
template<int BF> __device__ __forceinline__ void stf(void* p, size_t i, float x) {
    x = sanz(x);
    if constexpr (BF) ((__hip_bfloat16*)p)[i] = __float2bfloat16(x);
    else ((float*)p)[i] = x;
}
__device__ __forceinline__ float maskf(const void* m, int mm, int idx) {
    if (mm == 3) return ((const float*)m)[idx] != 0.f ? 1.f : 0.f;
    if (mm == 2) return ((const unsigned short*)m)[idx] ? 1.f : 0.f;
    if (mm == 1) return ((const unsigned char*)m)[idx] ? 1.f : 0.f;
    return ((const int*)m)[idx] ? 1.f : 0.f;
}
__device__ __forceinline__ int typf(const void* p, int tm, int idx) {
    int v;
    if (tm == 2) v = (int)bf2f(((const unsigned short*)p)[idx]);
    else if (tm == 1) v = (int)((const long long*)p)[idx];
    else v = ((const int*)p)[idx];
    return v < 0 ? 0 : (v > NT_ - 1 ? NT_ - 1 : v);
}

__global__ __launch_bounds__(64) void detect_k(const unsigned int* __restrict__ px,
                                               const unsigned int* __restrict__ pm,
                                               const unsigned int* __restrict__ pt,
                                               int* __restrict__ flags)
{
    const int t = threadIdx.x;
    int hit = 0;
    for (int i = t; i < 4096; i += 64) {
        unsigned e = (px[i] >> 7) & 0xFFu;
        hit += (e >= 110 && e <= 132) ? 1 : 0;
    }
    for (int s = 1; s < 64; s <<= 1) hit += __shfl_xor(hit, s);

    unsigned big = 0, lo3f = 0, hi3f = 0;
    for (int i = t; i < 1024; i += 64) {
        unsigned wv = pm[i];
        big  |= (wv > 1u) ? 1u : 0u;
        lo3f |= ((wv & 0xFFFFu) == 0x3F80u) ? 1u : 0u;
        hi3f |= ((wv >> 16) == 0x3F80u) ? 1u : 0u;
    }
    unsigned long long aBig = __ballot(big != 0), aLo = __ballot(lo3f != 0), aHi = __ballot(hi3f != 0);

    unsigned tbig = 0, oddnz = 0;
    for (int i = t; i < 512; i += 64) {
        unsigned we = pt[2 * i], wo = pt[2 * i + 1];
        tbig  |= (we > 0xFFFFu || wo > 0xFFFFu) ? 1u : 0u;
        oddnz |= (wo != 0u) ? 1u : 0u;
    }
    unsigned long long aTb = __ballot(tbig != 0), aOdd = __ballot(oddnz != 0);

    if (t == 0) {
        flags[1] = (hit > 2048) ? 1 : 0;
        flags[0] = aLo ? 2 : (aHi ? 3 : (aBig ? 1 : 0));
        flags[2] = aTb ? 2 : (!aOdd ? 1 : 0);
    }
}

// ---------------- weight transpose prep ----------------
template<int BF> __device__ __forceinline__ void wt_prep_body(
    const void* w1, const void* w2, const void* sw2,
    const void* proj, const void* gw1, __hip_bfloat16* wt)
{
    const int idx = blockIdx.x * 256 + threadIdx.x;
    const int stride = gridDim.x * 256;
    for (int i = idx; i < 128 * 192; i += stride) {
        int n = i / 192, k = i - n * 192;
        wt[n * 192 + k] = __float2bfloat16(ldf<BF>(w1, k * 128 + n));
    }
    __hip_bfloat16* w2c = wt + 24576;
    for (int i = idx; i < 128 * 256; i += stride) {
        int n = i >> 8, k = i & 255;
        float v = (k < 128) ? ldf<BF>(w2, k * 128 + n) : ldf<BF>(sw2, (k - 128) * 128 + n);
        w2c[n * 256 + k] = __float2bfloat16(v);
    }
    __hip_bfloat16* pjt = wt + 57344;
    for (int i = idx; i < 128 * 128; i += stride) {
        int n = i >> 7, k = i & 127;
        pjt[n * 128 + k] = __float2bfloat16(ldf<BF>(proj, k * 128 + n));
    }
    __hip_bfloat16* g1t = wt + 73728;
    for (int i = idx; i < 128 * 128; i += stride) {
        int n = i >> 7, k = i & 127;
        g1t[n * 128 + k] = __float2bfloat16(ldf<BF>(gw1, k * 128 + n));
    }
}

__global__ __launch_bounds__(256) void wt_prep_k(
    const void* w1, const void* w2, const void* sw2,
    const void* proj, const void* gw1, __hip_bfloat16* wt, const int* flags)
{
    if (flags[1]) wt_prep_body<1>(w1, w2, sw2, proj, gw1, wt);
    else          wt_prep_body<0>(w1, w2, sw2, proj, gw1, wt);
}

// ---------------- encode L ----------------
#define RL 8
template<int BF> __device__ __forceinline__ void enc_l_body(
    const void* l_x, const void* l_typ, int tm,
    const void* w1, const void* b1, const void* w2, const void* b2,
    const void* lng, const void* lnb, const void* emb, const void* proj,
    const void* dustv, __hip_bfloat16* hLb, float* dust)
{
    __shared__ __align__(16) float X[RL * 8];
    __shared__ __align__(16) float H[RL][D_];
    __shared__ __align__(16) float Y[RL][D_];
    __shared__ float mus[RL], rss[RL];
    const int o = threadIdx.x;
    const int base = blockIdx.x * RL;

    if (o < RL * 8) X[o] = ldf<BF>(l_x, base * 8 + o);
    __syncthreads();

    float acc[RL];
    const float b1o = ldf<BF>(b1, o);
#pragma unroll
    for (int r = 0; r < RL; r++) acc[r] = b1o;
#pragma unroll
    for (int i = 0; i < 8; i += 4) {
        float wa = ldf<BF>(w1, (i + 0) * D_ + o), wb = ldf<BF>(w1, (i + 1) * D_ + o);
        float wc = ldf<BF>(w1, (i + 2) * D_ + o), wd = ldf<BF>(w1, (i + 3) * D_ + o);
#pragma unroll
        for (int r = 0; r < RL; r++) {
            const float4 x4 = *(const float4*)&X[r * 8 + i];
            acc[r] = fmaf(x4.x, wa, fmaf(x4.y, wb, fmaf(x4.z, wc, fmaf(x4.w, wd, acc[r]))));
        }
    }
#pragma unroll
    for (int r = 0; r < RL; r++) H[r][o] = gelu_(acc[r]);
    __syncthreads();

#pragma unroll
    for (int r = 0; r < RL; r++) {
        int tt = typf(l_typ, tm, base + r);
        acc[r] = ldf<BF>(b2, o) + ldf<BF>(emb, tt * D_ + o);
    }
    for (int i = 0; i < D_; i += 4) {
        float wa = ldf<BF>(w2, (i + 0) * D_ + o), wb = ldf<BF>(w2, (i + 1) * D_ + o);
        float wc = ldf<BF>(w2, (i + 2) * D_ + o), wd = ldf<BF>(w2, (i + 3) * D_ + o);
#pragma unroll
        for (int r = 0; r < RL; r++) {
            const float4 h4 = *(const float4*)&H[r][i];
            acc[r] = fmaf(h4.x, wa, fmaf(h4.y, wb, fmaf(h4.z, wc, fmaf(h4.w, wd, acc[r]))));
        }
    }
#pragma unroll
    for (int r = 0; r < RL; r++) Y[r][o] = acc[r];
    __syncthreads();

    {
        const int r = o >> 4, j = o & 15;
        float s = 0.f;
#pragma unroll
        for (int i = 0; i < 8; i++) s += Y[r][j * 8 + i];
        s += __shfl_xor(s, 1); s += __shfl_xor(s, 2); s += __shfl_xor(s, 4); s += __shfl_xor(s, 8);
        const float mu = s * (1.f / 128.f);
        float v = 0.f;
#pragma unroll
        for (int i = 0; i < 8; i++) { float d = Y[r][j * 8 + i] - mu; v = fmaf(d, d, v); }
        v += __shfl_xor(v, 1); v += __shfl_xor(v, 2); v += __shfl_xor(v, 4); v += __shfl_xor(v, 8);
        if (j == 0) { mus[r] = mu; rss[r] = rsqrtf(v * (1.f / 128.f) + 1e-5f); }
    }
    __syncthreads();
    {
        const float g = ldf<BF>(lng, o), bl = ldf<BF>(lnb, o);
#pragma unroll
        for (int r = 0; r < RL; r++) Y[r][o] = fmaf((Y[r][o] - mus[r]) * rss[r], g, bl);
    }
    __syncthreads();

#pragma unroll
    for (int r = 0; r < RL; r++) acc[r] = 0.f;
    for (int i = 0; i < D_; i += 4) {
        float wa = ldf<BF>(proj, (i + 0) * D_ + o), wb = ldf<BF>(proj, (i + 1) * D_ + o);
        float wc = ldf<BF>(proj, (i + 2) * D_ + o), wd = ldf<BF>(proj, (i + 3) * D_ + o);
#pragma unroll
        for (int r = 0; r < RL; r++) {
            const float4 y4 = *(const float4*)&Y[r][i];
            acc[r] = fmaf(y4.x, wa, fmaf(y4.y, wb, fmaf(y4.z, wc, fmaf(y4.w, wd, acc[r]))));
        }
    }
    const float dvo = ldf<BF>(dustv, o);
#pragma unroll
    for (int r = 0; r < RL; r++) {
        hLb[(size_t)(base + r) * D_ + o] = __float2bfloat16(acc[r]);
        H[r][o] = acc[r] * dvo;
    }
    __syncthreads();
    {
        const int r = o >> 4, j = o & 15;
        float s = 0.f;
#pragma unroll
        for (int i = 0; i < 8; i++) s += H[r][j * 8 + i];
        s += __shfl_xor(s, 1); s += __shfl_xor(s, 2); s += __shfl_xor(s, 4); s += __shfl_xor(s, 8);
        if (j == 0) dust[base + r] = s * SCALE_;
    }
}

__global__ __launch_bounds__(128) void enc_l_k(
    const void* l_x, const void* l_typ,
    const void* w1, const void* b1, const void* w2, const void* b2,
    const void* lng, const void* lnb, const void* emb, const void* proj,
    const void* dustv, __hip_bfloat16* hLb, float* dust, const int* flags)
{
    const int tm = flags[2];
    if (flags[1]) enc_l_body<1>(l_x, l_typ, tm, w1, b1, w2, b2, lng, lnb, emb, proj, dustv, hLb, dust);
    else          enc_l_body<0>(l_x, l_typ, tm, w1, b1, w2, b2, lng, lnb, emb, proj, dustv, hLb, dust);
}

// ---------------- encode P (MFMA, 64 rows/block, in-register epilogues) ----------------
// 256 thr = 4 waves; wave w owns cols 32w..32w+31 (2 n-tiles); M-tiles mt=0..3.
// Lane (m,g): D rows mt*16+g*4+j, cols c0=32w+m, c1=32w+16+m.
#define XS 264
#define ROWS 64
#define ENC_P_SMEM 36608
template<int BF> __device__ __forceinline__ void enc_p_body(
    unsigned short* X, float* red1, float* red2, float* pm_s, float* sc_s, int* tt_s,
    const void* p_x, const void* p_typ, int tm,
    const void* p_score, const void* p_rad,
    const void* b1, const void* b2, const void* sb2,
    const void* sw1, const void* sb1,
    const void* lng, const void* lnb, const void* emb,
    const void* gb1, const void* gw2, const void* gb2,
    const unsigned short* wt, const void* p_mask, int mm,
    void* out, __hip_bfloat16* hPb, float* ppart, float* pcnt)
{
    const int t = threadIdx.x;
    const int o = t & 127, rh = t >> 7;
    const int lane = t & 63, w = t >> 6;
    const int m = lane & 15, g = lane >> 4;
    const int b = blockIdx.x >> 4, tile = blockIdx.x & 15;
    const int base = b * P_ + tile * ROWS;
    const int c0 = 32 * w + m, c1 = 32 * w + 16 + m;
    __hip_bfloat16* Xb = (__hip_bfloat16*)X;

    // stage p_x tile (ROWS*192 elems). BF=1: raw 16B copies (192%8==0, XS%8==0).
    if constexpr (BF) {
        const unsigned short* src = (const unsigned short*)p_x + (size_t)base * 192;
#pragma unroll
        for (int i = t * 8; i < ROWS * 192; i += 256 * 8) {
            const int r = i / 192, k = i - r * 192;
            *(bh8*)(X + r * XS + k) = *(const bh8*)(src + i);
        }
    } else {
        for (int i = t; i < ROWS * 192; i += 256) {
            int r = i / 192, k = i - r * 192;
            Xb[r * XS + k] = __float2bfloat16(((const float*)p_x)[(size_t)base * 192 + i]);
        }
    }
    if (t < ROWS) {
        pm_s[t] = maskf(p_mask, mm, base + t);
        sc_s[t] = ldf<BF>(p_score, base + t);
        tt_s[t] = typf(p_typ, tm, base + t);
    }
    __syncthreads();

    // GEMM1: X[64x192] @ w1 (ks-outer)
    fx4 A1[4][2];
#pragma unroll
    for (int mt = 0; mt < 4; mt++) { A1[mt][0] = fx4{0,0,0,0}; A1[mt][1] = fx4{0,0,0,0}; }
    {
        const unsigned short* q0 = wt + ((2 * w + 0) * 16 + m) * 192 + g * 8;
        const unsigned short* q1 = wt + ((2 * w + 1) * 16 + m) * 192 + g * 8;
#pragma unroll
        for (int ks = 0; ks < 6; ks++) {
            bh8 f0 = *(const bh8*)(q0 + ks * 32);
            bh8 f1 = *(const bh8*)(q1 + ks * 32);
#pragma unroll
            for (int mt = 0; mt < 4; mt++) {
                bh8 a = *(const bh8*)(X + (mt * 16 + m) * XS + g * 8 + ks * 32);
                A1[mt][0] = __builtin_amdgcn_mfma_f32_16x16x32_bf16(a, f0, A1[mt][0], 0, 0, 0);
                A1[mt][1] = __builtin_amdgcn_mfma_f32_16x16x32_bf16(a, f1, A1[mt][1], 0, 0, 0);
            }
        }
    }
    __syncthreads();

    // ep1: h1 = gelu(D + b1) -> X[:,0:128]; hs -> X[:,128:256]
    {
        const float bb0 = ldf<BF>(b1, c0), bb1 = ldf<BF>(b1, c1);
#pragma unroll
        for (int mt = 0; mt < 4; mt++)
#pragma unroll
            for (int j = 0; j < 4; j++) {
                const int row = mt * 16 + g * 4 + j;
                Xb[row * XS + c0] = __float2bfloat16(gelu_(A1[mt][0][j] + bb0));
                Xb[row * XS + c1] = __float2bfloat16(gelu_(A1[mt][1][j] + bb1));
            }
    }
    {
        const float a1v = ldf<BF>(sw1, o), a0v = ldf<BF>(sb1, o);
#pragma unroll
        for (int r = 0; r < 32; r++) {
            const int row = rh * 32 + r;
            Xb[row * XS + 128 + o] = __float2bfloat16(gelu_(fmaf(sc_s[row], a1v, a0v)));
        }
    }
    __syncthreads();

    // GEMM2: [h1|hs][64x256] @ w2c
    fx4 A2[4][2];
#pragma unroll
    for (int mt = 0; mt < 4; mt++) { A2[mt][0] = fx4{0,0,0,0}; A2[mt][1] = fx4{0,0,0,0}; }
    {
        const unsigned short* w2cT = wt + 24576;
        const unsigned short* q0 = w2cT + ((2 * w + 0) * 16 + m) * 256 + g * 8;
        const unsigned short* q1 = w2cT + ((2 * w + 1) * 16 + m) * 256 + g * 8;
#pragma unroll
        for (int ks = 0; ks < 8; ks++) {
            bh8 f0 = *(const bh8*)(q0 + ks * 32);
            bh8 f1 = *(const bh8*)(q1 + ks * 32);
#pragma unroll
            for (int mt = 0; mt < 4; mt++) {
                bh8 a = *(const bh8*)(X + (mt * 16 + m) * XS + g * 8 + ks * 32);
                A2[mt][0] = __builtin_amdgcn_mfma_f32_16x16x32_bf16(a, f0, A2[mt][0], 0, 0, 0);
                A2[mt][1] = __builtin_amdgcn_mfma_f32_16x16x32_bf16(a, f1, A2[mt][1], 0, 0, 0);
            }
        }
    }
    // ep2: h2 = D + b2 + sb2 + emb[typ]
    {
        const float bc0 = ldf<BF>(b2, c0) + ldf<BF>(sb2, c0);
        const float bc1 = ldf<BF>(b2, c1) + ldf<BF>(sb2, c1);
#pragma unroll
        for (int mt = 0; mt < 4; mt++)
#pragma unroll
            for (int j = 0; j < 4; j++) {
                const int row = mt * 16 + g * 4 + j;
                const int tt = tt_s[row];
                A2[mt][0][j] += bc0 + ldf<BF>(emb, tt * D_ + c0);
                A2[mt][1][j] += bc1 + ldf<BF>(emb, tt * D_ + c1);
            }
    }
    // LN mean partials
#pragma unroll
    for (int mt = 0; mt < 4; mt++)
#pragma unroll
        for (int j = 0; j < 4; j++) {
            float s = A2[mt][0][j] + A2[mt][1][j];
            s += __shfl_xor(s, 1); s += __shfl_xor(s, 2); s += __shfl_xor(s, 4); s += __shfl_xor(s, 8);
            if (m == 0) red1[(mt * 16 + g * 4 + j) * 4 + w] = s;
        }
    __syncthreads();
    float mu_[4][4];
#pragma unroll
    for (int mt = 0; mt < 4; mt++)
#pragma unroll
        for (int j = 0; j < 4; j++) {
            const int row = mt * 16 + g * 4 + j;
            mu_[mt][j] = ((red1[row * 4 + 0] + red1[row * 4 + 1]) +
                          (red1[row * 4 + 2] + red1[row * 4 + 3])) * (1.f / 128.f);
            float d0 = A2[mt][0][j] - mu_[mt][j];
            float d1 = A2[mt][1][j] - mu_[mt][j];
            float v = fmaf(d0, d0, d1 * d1);
            v += __shfl_xor(v, 1); v += __shfl_xor(v, 2); v += __shfl_xor(v, 4); v += __shfl_xor(v, 8);
            if (m == 0) red2[row * 4 + w] = v;
        }
    __syncthreads();
    // LN apply -> X bf16
    {
        const float gc0 = ldf<BF>(lng, c0), bl0 = ldf<BF>(lnb, c0);
        const float gc1 = ldf<BF>(lng, c1), bl1 = ldf<BF>(lnb, c1);
#pragma unroll
        for (int mt = 0; mt < 4; mt++)
#pragma unroll
            for (int j = 0; j < 4; j++) {
                const int row = mt * 16 + g * 4 + j;
                float var = ((red2[row * 4 + 0] + red2[row * 4 + 1]) +
                             (red2[row * 4 + 2] + red2[row * 4 + 3])) * (1.f / 128.f);
                float rs = rsqrtf(var + 1e-5f);
                float y0 = fmaf((A2[mt][0][j] - mu_[mt][j]) * rs, gc0, bl0);
                float y1 = fmaf((A2[mt][1][j] - mu_[mt][j]) * rs, gc1, bl1);
                Xb[row * XS + c0] = __float2bfloat16(y0);
                Xb[row * XS + c1] = __float2bfloat16(y1);
            }
    }
    __syncthreads();

    // GEMM3: hp = y[64x128] @ proj
    fx4 A3[4][2];
#pragma unroll
    for (int mt = 0; mt < 4; mt++) { A3[mt][0] = fx4{0,0,0,0}; A3[mt][1] = fx4{0,0,0,0}; }
    {
        const unsigned short* pjT = wt + 57344;
        const unsigned short* q0 = pjT + ((2 * w + 0) * 16 + m) * 128 + g * 8;
        const unsigned short* q1 = pjT + ((2 * w + 1) * 16 + m) * 128 + g * 8;
#pragma unroll
        for (int ks = 0; ks < 4; ks++) {
            bh8 f0 = *(const bh8*)(q0 + ks * 32);
            bh8 f1 = *(const bh8*)(q1 + ks * 32);
#pragma unroll
            for (int mt = 0; mt < 4; mt++) {
                bh8 a = *(const bh8*)(X + (mt * 16 + m) * XS + g * 8 + ks * 32);
                A3[mt][0] = __builtin_amdgcn_mfma_f32_16x16x32_bf16(a, f0, A3[mt][0], 0, 0, 0);
                A3[mt][1] = __builtin_amdgcn_mfma_f32_16x16x32_bf16(a, f1, A3[mt][1], 0, 0, 0);
            }
        }
    }
    __syncthreads();

    // ep3: hPb store + X <- hp bf16 + in-reg pool partials
    {
#pragma unroll
        for (int mt = 0; mt < 4; mt++)
#pragma unroll
            for (int j = 0; j < 4; j++) {
                const int row = mt * 16 + g * 4 + j;
                __hip_bfloat16 h0 = __float2bfloat16(A3[mt][0][j]);
                __hip_bfloat16 h1 = __float2bfloat16(A3[mt][1][j]);
                hPb[(size_t)(base + row) * D_ + c0] = h0;
                hPb[(size_t)(base + row) * D_ + c1] = h1;
                Xb[row * XS + c0] = h0;
                Xb[row * XS + c1] = h1;
            }
        float ps0 = 0.f, ps1 = 0.f;
#pragma unroll
        for (int mt = 0; mt < 4; mt++)
#pragma unroll
            for (int j = 0; j < 4; j++) {
                const int row = mt * 16 + g * 4 + j;
                ps0 = fmaf(A3[mt][0][j], pm_s[row], ps0);
                ps1 = fmaf(A3[mt][1][j], pm_s[row], ps1);
            }
        ps0 += __shfl_xor(ps0, 16); ps0 += __shfl_xor(ps0, 32);
        ps1 += __shfl_xor(ps1, 16); ps1 += __shfl_xor(ps1, 32);
        if (g == 0) {
            ppart[(size_t)blockIdx.x * D_ + c0] = ps0;
            ppart[(size_t)blockIdx.x * D_ + c1] = ps1;
        }
        if (t == 0) {
            float c = 0.f;
#pragma unroll
            for (int r = 0; r < ROWS; r++) c += pm_s[r];
            pcnt[blockIdx.x] = c;
        }
    }
    __syncthreads();

    // GEMM4: g1raw = hp[64x128] @ gw1
    fx4 A4[4][2];
#pragma unroll
    for (int mt = 0; mt < 4; mt++) { A4[mt][0] = fx4{0,0,0,0}; A4[mt][1] = fx4{0,0,0,0}; }
    {
        const unsigned short* g1T = wt + 73728;
        const unsigned short* q0 = g1T + ((2 * w + 0) * 16 + m) * 128 + g * 8;
        const unsigned short* q1 = g1T + ((2 * w + 1) * 16 + m) * 128 + g * 8;
#pragma unroll
        for (int ks = 0; ks < 4; ks++) {
            bh8 f0 = *(const bh8*)(q0 + ks * 32);
            bh8 f1 = *(const bh8*)(q1 + ks * 32);
#pragma unroll
            for (int mt = 0; mt < 4; mt++) {
                bh8 a = *(const bh8*)(X + (mt * 16 + m) * XS + g * 8 + ks * 32);
                A4[mt][0] = __builtin_amdgcn_mfma_f32_16x16x32_bf16(a, f0, A4[mt][0], 0, 0, 0);
                A4[mt][1] = __builtin_amdgcn_mfma_f32_16x16x32_bf16(a, f1, A4[mt][1], 0, 0, 0);
            }
        }
    }
    // ep4: g1 = gelu(D+gb1); sigma dot partials
    {
        const float gb0 = ldf<BF>(gb1, c0), gb1v = ldf<BF>(gb1, c1);
        const float w20 = ldf<BF>(gw2, c0), w21 = ldf<BF>(gw2, c1);
#pragma unroll
        for (int mt = 0; mt < 4; mt++)
#pragma unroll
            for (int j = 0; j < 4; j++) {
                const int row = mt * 16 + g * 4 + j;
                float g0 = gelu_(A4[mt][0][j] + gb0);
                float g1v = gelu_(A4[mt][1][j] + gb1v);
                float p = fmaf(g0, w20, g1v * w21);
                p += __shfl_xor(p, 1); p += __shfl_xor(p, 2); p += __shfl_xor(p, 4); p += __shfl_xor(p, 8);
                if (m == 0) red1[row * 4 + w] = p;
            }
    }
    __syncthreads();
    if (t < ROWS) {
        float s = (red1[t * 4 + 0] + red1[t * 4 + 1]) + (red1[t * 4 + 2] + red1[t * 4 + 3]);
        float v = s + ldf<BF>(gb2, 0);
        float sp = fmaxf(v, 0.f) + log1pf(expf(-fabsf(v)));
        stf<BF>(out, (size_t)OUT_SIG + base + t, sp + 1e-3f + fmaxf(ldf<BF>(p_rad, base + t), 0.f));
    }
}

__global__ __launch_bounds__(256) void enc_p_k(
    const void* p_x, const void* p_typ, const void* p_score, const void* p_rad,
    const void* b1, const void* b2, const void* sb2,
    const void* sw1, const void* sb1,
    const void* lng, const void* lnb, const void* emb,
    const void* gb1, const void* gw2, const void* gb2,
    const unsigned short* wt, const void* p_mask, const int* flags,
    void* out, __hip_bfloat16* hPb, float* ppart, float* pcnt)
{
    extern __shared__ __align__(16) char smem[];
    unsigned short* X = (unsigned short*)smem;          // 64*264*2 = 33792 B
    float* red1 = (float*)(smem + 33792);               // 1024 B
    float* red2 = (float*)(smem + 34816);               // 1024 B
    float* pm_s = (float*)(smem + 35840);               // 256 B
    float* sc_s = (float*)(smem + 36096);               // 256 B
    int*   tt_s = (int*)(smem + 36352);                 // 256 B
    const int tm = flags[2], mm = flags[0];
    if (flags[1]) enc_p_body<1>(X, red1, red2, pm_s, sc_s, tt_s,
                                p_x, p_typ, tm, p_score, p_rad, b1, b2, sb2, sw1, sb1,
                                lng, lnb, emb, gb1, gw2, gb2, wt, p_mask, mm,
                                out, hPb, ppart, pcnt);
    else          enc_p_body<0>(X, red1, red2, pm_s, sc_s, tt_s,
                                p_x, p_typ, tm, p_score, p_rad, b1, b2, sb2, sw1, sb1,
                                lng, lnb, emb, gb1, gw2, gb2, wt, p_mask, mm,
                                out, hPb, ppart, pcnt);
}

// ---------------- logits (MFMA) + fused softmax + sharp/ent ----------------
template<int BF> __device__ __forceinline__ void logits_sm_body(
    const unsigned short* hLb, const unsigned short* hPb, const float* dust,
    const void* l_mask, const void* p_mask, int mm,
    void* out, float* sharp_parts, float* ent_parts)
{
    __shared__ float pm_s[1024];
    __shared__ float lm_s[16], dv_s[16];
    __shared__ float redA[64], redB[64], redC[64], redD[64], redM[16], redL[16];
    const int t = threadIdx.x;
    const int lane = t & 63, w = t >> 6;
    const int m = lane & 15, g = lane >> 4;
    const int b = blockIdx.x & 127, l0 = (blockIdx.x >> 7) * 16;

    for (int i = t; i < 1024; i += 256) pm_s[i] = maskf(p_mask, mm, b * P_ + i);
    if (t < 16) {
        lm_s[t] = maskf(l_mask, mm, b * L_ + l0 + t);
        dv_s[t] = dust[b * L_ + l0 + t];
    }
    __syncthreads();

    bh8 af[4];
    {
        const unsigned short* ha = hLb + ((size_t)(b * L_ + l0 + m)) * D_ + g * 8;
#pragma unroll
        for (int ks = 0; ks < 4; ks++) af[ks] = *(const bh8*)(ha + ks * 32);
    }
    const unsigned short* hpb = hPb + ((size_t)(b * P_ + w * 256)) * D_;

    fx4 acc[16];
#pragma unroll
    for (int nt = 0; nt < 16; nt++) {
        fx4 c = {0.f, 0.f, 0.f, 0.f};
        const unsigned short* hr = hpb + (nt * 16 + m) * D_ + g * 8;
#pragma unroll
        for (int ks = 0; ks < 4; ks++) {
            bh8 bfr = *(const bh8*)(hr + ks * 32);
            c = __builtin_amdgcn_mfma_f32_16x16x32_bf16(af[ks], bfr, c, 0, 0, 0);
        }
        acc[nt] = c;
    }

    float rmax[4] = {NEGF, NEGF, NEGF, NEGF};
#pragma unroll
    for (int nt = 0; nt < 16; nt++) {
        const float pv = pm_s[w * 256 + nt * 16 + m];
#pragma unroll
        for (int j = 0; j < 4; j++) {
            const bool ok = (lm_s[g * 4 + j] != 0.f) && (pv != 0.f);
            float v = ok ? acc[nt][j] * SCALE_ : NEGF;
            acc[nt][j] = v;
            rmax[j] = fmaxf(rmax[j], v);
        }
    }
#pragma unroll
    for (int j = 0; j < 4; j++) {
        rmax[j] = fmaxf(rmax[j], __shfl_xor(rmax[j], 1));
        rmax[j] = fmaxf(rmax[j], __shfl_xor(rmax[j], 2));
        rmax[j] = fmaxf(rmax[j], __shfl_xor(rmax[j], 4));
        rmax[j] = fmaxf(rmax[j], __shfl_xor(rmax[j], 8));
    }
    if (m == 0) {
#pragma unroll
        for (int j = 0; j < 4; j++) redA[(g * 4 + j) * 4 + w] = rmax[j];
    }
    __syncthreads();
    float mrow[4], lse[4];
#pragma unroll
    for (int j = 0; j < 4; j++) {
        const int r = g * 4 + j;
        float mm4 = fmaxf(fmaxf(redA[r * 4 + 0], redA[r * 4 + 1]), fmaxf(redA[r * 4 + 2], redA[r * 4 + 3]));
        float dvr = (lm_s[r] != 0.f) ? dv_s[r] : NEGF;
        mrow[j] = fmaxf(mm4, dvr);
    }
    float se[4] = {0.f, 0.f, 0.f, 0.f};
#pragma unroll
    for (int nt = 0; nt < 16; nt++) {
#pragma unroll
        for (int j = 0; j < 4; j++) se[j] += __expf(acc[nt][j] - mrow[j]);
    }
#pragma unroll
    for (int j = 0; j < 4; j++) {
        se[j] += __shfl_xor(se[j], 1); se[j] += __shfl_xor(se[j], 2);
        se[j] += __shfl_xor(se[j], 4); se[j] += __shfl_xor(se[j], 8);
    }
    if (m == 0) {
#pragma unroll
        for (int j = 0; j < 4; j++) redB[(g * 4 + j) * 4 + w] = se[j];
    }
    __syncthreads();
#pragma unroll
    for (int j = 0; j < 4; j++) {
        const int r = g * 4 + j;
        float dvr = (lm_s[r] != 0.f) ? dv_s[r] : NEGF;
        float s = (redB[r * 4 + 0] + redB[r * 4 + 1]) + (redB[r * 4 + 2] + redB[r * 4 + 3]);
        s += __expf(dvr - mrow[j]);
        lse[j] = __logf(s);
    }
    if (w == 0 && m == 0) {
#pragma unroll
        for (int j = 0; j < 4; j++) { redM[g * 4 + j] = mrow[j]; redL[g * 4 + j] = lse[j]; }
    }
    float mw[4] = {0.f, 0.f, 0.f, 0.f}, es[4] = {0.f, 0.f, 0.f, 0.f};
#pragma unroll
    for (int nt = 0; nt < 16; nt++) {
        const float pv = pm_s[w * 256 + nt * 16 + m];
#pragma unroll
        for (int j = 0; j < 4; j++) {
            float lw = acc[nt][j] - mrow[j] - lse[j];
            stf<BF>(out, (size_t)(b * L_ + l0 + g * 4 + j) * (P_ + 1) + w * 256 + nt * 16 + m, lw);
            float lwc = fmaxf(lw, -CLAMPV);
            float wm = __expf(lwc) * pv;
            mw[j] = fmaxf(mw[j], wm);
            if (wm > 0.f) es[j] = fmaf(-wm, lwc, es[j]);
        }
    }
#pragma unroll
    for (int j = 0; j < 4; j++) {
        mw[j] = fmaxf(mw[j], __shfl_xor(mw[j], 1));
        mw[j] = fmaxf(mw[j], __shfl_xor(mw[j], 2));
        mw[j] = fmaxf(mw[j], __shfl_xor(mw[j], 4));
        mw[j] = fmaxf(mw[j], __shfl_xor(mw[j], 8));
        es[j] += __shfl_xor(es[j], 1); es[j] += __shfl_xor(es[j], 2);
        es[j] += __shfl_xor(es[j], 4); es[j] += __shfl_xor(es[j], 8);
    }
    if (m == 0) {
#pragma unroll
        for (int j = 0; j < 4; j++) {
            redC[(g * 4 + j) * 4 + w] = mw[j];
            redD[(g * 4 + j) * 4 + w] = es[j];
        }
    }
    __syncthreads();
    if (t < 16) {
        float dvr = (lm_s[t] != 0.f) ? dv_s[t] : NEGF;
        stf<BF>(out, (size_t)(b * L_ + l0 + t) * (P_ + 1) + P_, dvr - redM[t] - redL[t]);
    }
    if (t == 0) {
        float sp = 0.f, en = 0.f;
        for (int r = 0; r < 16; r++) {
            float dvr = (lm_s[r] != 0.f) ? dv_s[r] : NEGF;
            float lwd = fmaxf(dvr - redM[r] - redL[r], -CLAMPV);
            float wd = __expf(lwd);
            float mwr = fmaxf(fmaxf(redC[r * 4 + 0], redC[r * 4 + 1]), fmaxf(redC[r * 4 + 2], redC[r * 4 + 3]));
            mwr = fmaxf(mwr, wd);
            float esr = (redD[r * 4 + 0] + redD[r * 4 + 1]) + (redD[r * 4 + 2] + redD[r * 4 + 3]);
            if (wd > 0.f) esr = fmaf(-wd, lwd, esr);
            sp = fmaf(mwr, lm_s[r], sp);
            en = fmaf(esr, lm_s[r], en);
        }
        sharp_parts[blockIdx.x] = sp;
        ent_parts[blockIdx.x] = en;
    }
}

__global__ __launch_bounds__(256) void logits_sm_k(
    const unsigned short* hLb, const unsigned short* hPb, const float* dust,
    const void* l_mask, const void* p_mask, const int* flags,
    void* out, float* sharp_parts, float* ent_parts)
{
    const int mm = flags[0];
    if (flags[1]) logits_sm_body<1>(hLb, hPb, dust, l_mask, p_mask, mm, out, sharp_parts, ent_parts);
    else          logits_sm_body<0>(hLb, hPb, dust, l_mask, p_mask, mm, out, sharp_parts, ent_parts);
}

// ---------------- epilogue: pool_l + pool_p + finalize ----------------
template<int BF> __device__ __forceinline__ void epilogue_body(
    const unsigned short* hLb, const void* l_mask, int mm,
    const void* retr_l, const void* retr_p,
    const float* ppart, const float* pcnt,
    const float* sharp_parts, const float* ent_parts, void* out)
{
    __shared__ float lmv[L_];
    __shared__ __align__(16) float lg[D_];
    __shared__ __align__(16) float pgs[D_];
    __shared__ float red[4];
    const int o = threadIdx.x, b = blockIdx.x;
    lmv[o] = maskf(l_mask, mm, b * L_ + o);
    __syncthreads();
    float cnt = 0.f;
    for (int l = 0; l < L_; l++) cnt += lmv[l];
    {
        float s0 = 0, s1 = 0, s2 = 0, s3 = 0;
        const unsigned short* hb = hLb + (size_t)b * L_ * D_;
        for (int l = 0; l < L_; l += 4) {
            s0 = fmaf(bf2f(hb[(l + 0) * D_ + o]), lmv[l + 0], s0);
            s1 = fmaf(bf2f(hb[(l + 1) * D_ + o]), lmv[l + 1], s1);
            s2 = fmaf(bf2f(hb[(l + 2) * D_ + o]), lmv[l + 2], s2);
            s3 = fmaf(bf2f(hb[(l + 3) * D_ + o]), lmv[l + 3], s3);
        }
        lg[o] = ((s0 + s1) + (s2 + s3)) / fmaxf(cnt, 1.f);
    }
    {
        float s = 0.f, c = 0.f;
        for (int k = 0; k < 16; k++) s += ppart[(size_t)(b * 16 + k) * D_ + o];
        for (int k = 0; k < 16; k++) c += pcnt[b * 16 + k];
        pgs[o] = s / fmaxf(c, 1.f);
    }
    __syncthreads();
    float rL = 0.f, rP = 0.f;
    for (int i = 0; i < D_; i += 4) {
        const float4 g4 = *(const float4*)&lg[i];
        rL = fmaf(g4.x, ldf<BF>(retr_l, (i + 0) * D_ + o), rL);
        rL = fmaf(g4.y, ldf<BF>(retr_l, (i + 1) * D_ + o), rL);
        rL = fmaf(g4.z, ldf<BF>(retr_l, (i + 2) * D_ + o), rL);
        rL = fmaf(g4.w, ldf<BF>(retr_l, (i + 3) * D_ + o), rL);
        const float4 p4 = *(const float4*)&pgs[i];
        rP = fmaf(p4.x, ldf<BF>(retr_p, (i + 0) * D_ + o), rP);
        rP = fmaf(p4.y, ldf<BF>(retr_p, (i + 1) * D_ + o), rP);
        rP = fmaf(p4.z, ldf<BF>(retr_p, (i + 2) * D_ + o), rP);
        rP = fmaf(p4.w, ldf<BF>(retr_p, (i + 3) * D_ + o), rP);
    }
    float nL = rL * rL, nP = rP * rP;
    nL += __shfl_xor(nL, 1); nL += __shfl_xor(nL, 2); nL += __shfl_xor(nL, 4);
    nL += __shfl_xor(nL, 8); nL += __shfl_xor(nL, 16); nL += __shfl_xor(nL, 32);
    nP += __shfl_xor(nP, 1); nP += __shfl_xor(nP, 2); nP += __shfl_xor(nP, 4);
    nP += __shfl_xor(nP, 8); nP += __shfl_xor(nP, 16); nP += __shfl_xor(nP, 32);
    if ((o & 63) == 0) { red[o >> 6] = nL; red[2 + (o >> 6)] = nP; }
    __syncthreads();
    {
        float nrmL = fmaxf(sqrtf(red[0] + red[1]), 1e-12f);
        float nrmP = fmaxf(sqrtf(red[2] + red[3]), 1e-12f);
        stf<BF>(out, (size_t)OUT_LZ + b * D_ + o, rL / nrmL);
        stf<BF>(out, (size_t)OUT_PZ + b * D_ + o, rP / nrmP);
    }
    if (o == 0) {
        const float den = fmaxf(cnt, 1.f);
        float sp = 0.f, en = 0.f;
        for (int k = 0; k < 8; k++) { sp += sharp_parts[k * 128 + b]; en += ent_parts[k * 128 + b]; }
        stf<BF>(out, (size_t)OUT_SHARP + b, sp / den);
        stf<BF>(out, (size_t)OUT_NEGENT + b, -(en / den));
    }
}

__global__ __launch_bounds__(128) void epilogue_k(
    const unsigned short* hLb, const void* l_mask, const int* flags,
    const void* retr_l, const void* retr_p,
    const float* ppart, const float* pcnt,
    const float* sharp_parts, const float* ent_parts, void* out)
{
    const int mm = flags[0];
    if (flags[1]) epilogue_body<1>(hLb, l_mask, mm, retr_l, retr_p, ppart, pcnt, sharp_parts, ent_parts, out);
    else          epilogue_body<0>(hLb, l_mask, mm, retr_l, retr_p, ppart, pcnt, sharp_parts, ent_parts, out);
}

extern "C" void kernel_launch(void* const* d_in, const int* in_sizes, int n_in,
                              void* d_out, int out_size, void* d_ws, size_t ws_size,
                              hipStream_t stream)
{
    const void* l_x     = d_in[0];
    const void* l_typ   = d_in[1];
    const void* p_x     = d_in[2];
    const void* p_typ   = d_in[3];
    const void* p_score = d_in[4];
    const void* p_rad   = d_in[5];
    const void* l_mask  = d_in[6];
    const void* p_mask  = d_in[7];
    const void* lt_emb  = d_in[8];
    const void* lx_w1   = d_in[9];
    const void* lx_b1   = d_in[10];
    const void* lx_w2   = d_in[11];
    const void* lx_b2   = d_in[12];
    const void* l_ln_g  = d_in[13];
    const void* l_ln_b  = d_in[14];
    const void* pt_emb  = d_in[15];
    const void* px_w1   = d_in[16];
    const void* px_b1   = d_in[17];
    const void* px_w2   = d_in[18];
    const void* px_b2   = d_in[19];
    const void* ps_w1   = d_in[20];
    const void* ps_b1   = d_in[21];
    const void* ps_w2   = d_in[22];
    const void* ps_b2   = d_in[23];
    const void* p_ln_g  = d_in[24];
    const void* p_ln_b  = d_in[25];
    const void* proj_l  = d_in[26];
    const void* proj_p  = d_in[27];
    const void* dustv   = d_in[28];
    const void* sg_w1   = d_in[29];
    const void* sg_b1   = d_in[30];
    const void* sg_w2   = d_in[31];
    const void* sg_b2   = d_in[32];
    const void* retr_l  = d_in[33];
    const void* retr_p  = d_in[34];

    float* ws     = (float*)d_ws;
    __hip_bfloat16* hLb = (__hip_bfloat16*)(ws + WS_HLB);
    __hip_bfloat16* hPb = (__hip_bfloat16*)(ws + WS_HPB);
    float* dust   = ws + WS_DUST;
    float* sharpp = ws + WS_SHARPP;
    float* entp   = ws + WS_ENTP;
    int*   flags  = (int*)(ws + WS_FLAG);
    __hip_bfloat16* wt = (__hip_bfloat16*)(ws + WS_WT);
    float* ppart  = ws + WS_PPART;
    float* pcnt   = ws + WS_PCNT;

    detect_k<<<1, 64, 0, stream>>>((const unsigned int*)p_x, (const unsigned int*)p_mask,
                                   (const unsigned int*)p_typ, flags);
    wt_prep_k<<<64, 256, 0, stream>>>(px_w1, px_w2, ps_w2, proj_p, sg_w1, wt, flags);
    enc_l_k<<<(B_ * L_) / RL, 128, 0, stream>>>(l_x, l_typ, lx_w1, lx_b1, lx_w2, lx_b2,
                                                l_ln_g, l_ln_b, lt_emb, proj_l, dustv,
                                                hLb, dust, flags);
    enc_p_k<<<B_ * (P_ / ROWS), 256, ENC_P_SMEM, stream>>>(
        p_x, p_typ, p_score, p_rad,
        px_b1, px_b2, ps_b2, ps_w1, ps_b1,
        p_ln_g, p_ln_b, pt_emb,
        sg_b1, sg_w2, sg_b2,
        (const unsigned short*)wt, p_mask, flags,
        d_out, hPb, ppart, pcnt);
    logits_sm_k<<<B_ * 8, 256, 0, stream>>>((const unsigned short*)hLb, (const unsigned short*)hPb,
                                            dust, l_mask, p_mask, flags, d_out, sharpp, entp);
    epilogue_k<<<B_, 128, 0, stream>>>((const unsigned short*)hLb, l_mask, flags,
                                       retr_l, retr_p, ppart, pcnt, sharpp, entp, d_out);
}